// Round 1
// baseline (2888.504 us; speedup 1.0000x reference)
//
#include <hip/hip_runtime.h>

#define SQ     2048
#define DMODEL 2048
#define NHEAD  16
#define NKV    4
#define HDIM   128
#define FFDIM  5632
#define VOCAB  32000
#define NLAYER 2
#define EPSV   1e-5f

typedef __bf16 bf16;
typedef __bf16 bf16x4 __attribute__((ext_vector_type(4)));
typedef __bf16 bf16x8 __attribute__((ext_vector_type(8)));
typedef float  f32x4  __attribute__((ext_vector_type(4)));

enum { EP_STORE = 0, EP_SCALEMASK = 1, EP_ADD = 2, EP_SILUMUL = 3 };

#define BM   128
#define BN   128
#define BKK  64
#define LDSP 72   // padded K-stride in LDS elems (144B rows: 16B aligned, ~2-way banks on frag reads)

// C = A(MxK) * B + epilogue.  BLAY=0: B is KxN row-major. BLAY=1: B is NxK row-major (B^T).
// Batch z: A += z*sA (or Aalt for z>=zsplitA), B += (z/bdiv)*sB, C += z*sC (or Calt for z>=zsplitC).
template<int BLAY, int EPI>
__global__ __launch_bounds__(256, 2)
void gemm_bf16(const float* A, const float* B, float* C, const float* Cin,
               const float* Aalt, float* Calt,
               int N, int K, int lda, int ldb, int ldc,
               long sA, long sB, long sC, int bdiv, int zsplitA, int zsplitC,
               float scale)
{
  __shared__ bf16 As[BM][LDSP];
  __shared__ bf16 Bs[BN][LDSP];   // stored as [n][k] for both layouts

  const int tid  = (int)threadIdx.x;
  const int lane = tid & 63;
  const int wm   = (tid >> 6) >> 1;
  const int wn   = (tid >> 6) & 1;
  const int z    = (int)blockIdx.z;
  const int m0   = (int)blockIdx.y * BM;
  const int n0   = (int)blockIdx.x * BN;

  const float* Ap = (z < zsplitA) ? (A + (long)z * sA) : (Aalt + (long)(z - zsplitA) * sA);
  const float* Bp = B + (long)(z / bdiv) * sB;
  float*       Cp = (z < zsplitC) ? (C + (long)z * sC) : (Calt + (long)(z - zsplitC) * sC);

  f32x4 acc[4][4] = {};

  for (int kt = 0; kt < K; kt += BKK) {
    // ---- stage A tile (BM x BKK), fp32 -> bf16
    #pragma unroll
    for (int p = 0; p < 8; ++p) {
      const int row = p * 16 + (tid >> 4);
      const int col = (tid & 15) * 4;
      f32x4 v = *(const f32x4*)(Ap + (long)(m0 + row) * lda + (kt + col));
      bf16x4 b = { (bf16)v[0], (bf16)v[1], (bf16)v[2], (bf16)v[3] };
      *(bf16x4*)(&As[row][col]) = b;
    }
    if (BLAY == 1) {
      // B is N x K: rows are K-contiguous, same staging pattern as A
      #pragma unroll
      for (int p = 0; p < 8; ++p) {
        const int row = p * 16 + (tid >> 4);
        const int col = (tid & 15) * 4;
        f32x4 v = *(const f32x4*)(Bp + (long)(n0 + row) * ldb + (kt + col));
        bf16x4 b = { (bf16)v[0], (bf16)v[1], (bf16)v[2], (bf16)v[3] };
        *(bf16x4*)(&Bs[row][col]) = b;
      }
    } else {
      // B is K x N: transpose-stage into Bs[n][k] (4 k-rows packed per b64 write)
      #pragma unroll
      for (int p = 0; p < 2; ++p) {
        const int kq = p * 8 + (tid >> 5);   // k-quad index 0..15 -> k = 4*kq
        const int n  = (tid & 31) * 4;
        const float* bsrc = Bp + (long)(kt + kq * 4) * ldb + (n0 + n);
        f32x4 w0 = *(const f32x4*)(bsrc);
        f32x4 w1 = *(const f32x4*)(bsrc + (long)ldb);
        f32x4 w2 = *(const f32x4*)(bsrc + 2 * (long)ldb);
        f32x4 w3 = *(const f32x4*)(bsrc + 3 * (long)ldb);
        #pragma unroll
        for (int i = 0; i < 4; ++i) {
          bf16x4 b = { (bf16)w0[i], (bf16)w1[i], (bf16)w2[i], (bf16)w3[i] };
          *(bf16x4*)(&Bs[n + i][kq * 4]) = b;
        }
      }
    }
    __syncthreads();

    #pragma unroll
    for (int kk = 0; kk < 2; ++kk) {
      const int kb = kk * 32 + (lane >> 4) * 8;
      bf16x8 af[4], bfv[4];
      #pragma unroll
      for (int m = 0; m < 4; ++m)
        af[m] = *(const bf16x8*)(&As[wm * 64 + m * 16 + (lane & 15)][kb]);
      #pragma unroll
      for (int n = 0; n < 4; ++n)
        bfv[n] = *(const bf16x8*)(&Bs[wn * 64 + n * 16 + (lane & 15)][kb]);
      #pragma unroll
      for (int m = 0; m < 4; ++m)
        #pragma unroll
        for (int n = 0; n < 4; ++n)
          acc[m][n] = __builtin_amdgcn_mfma_f32_16x16x32_bf16(af[m], bfv[n], acc[m][n], 0, 0, 0);
    }
    __syncthreads();
  }

  // ---- epilogue.  C/D frag: col = lane&15, row = (lane>>4)*4 + reg
  #pragma unroll
  for (int m = 0; m < 4; ++m) {
    const int gr0 = m0 + wm * 64 + m * 16 + (lane >> 4) * 4;
    #pragma unroll
    for (int n = 0; n < 4; ++n) {
      const int gc = n0 + wn * 64 + n * 16 + (lane & 15);
      #pragma unroll
      for (int r = 0; r < 4; ++r) {
        const int gr = gr0 + r;
        const long off = (long)gr * ldc + gc;
        float v = acc[m][n][r];
        if (EPI == EP_STORE) {
          Cp[off] = v;
        } else if (EPI == EP_SCALEMASK) {
          // reference: scores * scale * tril-mask -> masked entries are EXACTLY 0 (not -inf)
          Cp[off] = (gc > gr) ? 0.0f : v * scale;
        } else if (EPI == EP_ADD) {
          Cp[off] = Cin[off] + v;
        } else { // EP_SILUMUL: out = silu(up) * gate
          const float g = Cin[off];
          Cp[off] = (v / (1.0f + __expf(-v))) * g;
        }
      }
    }
  }
}

__global__ __launch_bounds__(256)
void rmsnorm_kernel(float* out, const float* in, const float* g)
{
  const int row = (int)blockIdx.x;
  const float* x = in + (long)row * DMODEL;
  float* o = out + (long)row * DMODEL;
  const int tid = (int)threadIdx.x;
  f32x4 v0 = *(const f32x4*)(x + tid * 4);
  f32x4 v1 = *(const f32x4*)(x + tid * 4 + 1024);
  float ss = v0[0]*v0[0] + v0[1]*v0[1] + v0[2]*v0[2] + v0[3]*v0[3]
           + v1[0]*v1[0] + v1[1]*v1[1] + v1[2]*v1[2] + v1[3]*v1[3];
  #pragma unroll
  for (int o_ = 32; o_; o_ >>= 1) ss += __shfl_xor(ss, o_);
  __shared__ float sm[4];
  if ((tid & 63) == 0) sm[tid >> 6] = ss;
  __syncthreads();
  ss = sm[0] + sm[1] + sm[2] + sm[3];
  const float r = 1.0f / sqrtf(ss * (1.0f / DMODEL) + EPSV);
  f32x4 g0 = *(const f32x4*)(g + tid * 4);
  f32x4 g1 = *(const f32x4*)(g + tid * 4 + 1024);
  f32x4 o0, o1;
  #pragma unroll
  for (int j = 0; j < 4; ++j) { o0[j] = v0[j] * r * g0[j]; o1[j] = v1[j] * r * g1[j]; }
  *(f32x4*)(o + tid * 4) = o0;
  *(f32x4*)(o + tid * 4 + 1024) = o1;
}

__global__ __launch_bounds__(256)
void softmax_kernel(float* base, float* alt, int zsplit)
{
  const int row = (int)blockIdx.x;
  const int z   = (int)blockIdx.y;
  const long SSL = (long)SQ * SQ;
  float* p = ((z < zsplit) ? (base + (long)z * SSL) : (alt + (long)(z - zsplit) * SSL))
             + (long)row * SQ;
  const int tid = (int)threadIdx.x;
  f32x4 v0 = *(f32x4*)(p + tid * 4);
  f32x4 v1 = *(f32x4*)(p + tid * 4 + 1024);
  float mx = fmaxf(fmaxf(fmaxf(v0[0], v0[1]), fmaxf(v0[2], v0[3])),
                   fmaxf(fmaxf(v1[0], v1[1]), fmaxf(v1[2], v1[3])));
  #pragma unroll
  for (int o = 32; o; o >>= 1) mx = fmaxf(mx, __shfl_xor(mx, o));
  __shared__ float sm[4], sv[4];
  if ((tid & 63) == 0) sm[tid >> 6] = mx;
  __syncthreads();
  mx = fmaxf(fmaxf(sm[0], sm[1]), fmaxf(sm[2], sm[3]));
  float s = 0.f;
  #pragma unroll
  for (int j = 0; j < 4; ++j) { v0[j] = __expf(v0[j] - mx); s += v0[j]; }
  #pragma unroll
  for (int j = 0; j < 4; ++j) { v1[j] = __expf(v1[j] - mx); s += v1[j]; }
  #pragma unroll
  for (int o = 32; o; o >>= 1) s += __shfl_xor(s, o);
  if ((tid & 63) == 0) sv[tid >> 6] = s;
  __syncthreads();
  s = sv[0] + sv[1] + sv[2] + sv[3];
  const float inv = 1.0f / s;
  #pragma unroll
  for (int j = 0; j < 4; ++j) { v0[j] *= inv; v1[j] *= inv; }
  *(f32x4*)(p + tid * 4) = v0;
  *(f32x4*)(p + tid * 4 + 1024) = v1;
}

__global__ void rope_tables(float* cosT, float* sinT)
{
  const int s = (int)blockIdx.x;
  const int i = (int)threadIdx.x;   // 0..63
  const double inv = pow(10000.0, -(double)i / 64.0);
  const double f = (double)s * inv;
  cosT[s * 64 + i] = (float)cos(f);
  sinT[s * 64 + i] = (float)sin(f);
}

__global__ __launch_bounds__(256)
void rope_apply(float* buf, const float* cosT, const float* sinT, int nh, int stride)
{
  const int t = (int)(blockIdx.x * blockDim.x + threadIdx.x);
  const int per = nh * 64;
  const int s = t / per;
  const int r = t - s * per;
  const int h = r >> 6;
  const int i = r & 63;
  float* b = buf + (long)s * stride + h * HDIM;
  const float c  = cosT[s * 64 + i];
  const float sn = sinT[s * 64 + i];
  const float x1 = b[i];
  const float x2 = b[64 + i];
  b[i]      = x1 * c - x2 * sn;
  b[64 + i] = x2 * c + x1 * sn;
}

__global__ __launch_bounds__(256)
void embed_gather(f32x4* x, const f32x4* embed, const int* idx)
{
  const int t = (int)(blockIdx.x * 256 + threadIdx.x);
  const int s = t >> 9;      // 512 f32x4 per row
  const int c = t & 511;
  x[t] = embed[(long)idx[s] * 512 + c];
}

extern "C" void kernel_launch(void* const* d_in, const int* in_sizes, int n_in,
                              void* d_out, int out_size, void* d_ws, size_t ws_size,
                              hipStream_t stream)
{
  (void)in_sizes; (void)n_in; (void)out_size; (void)ws_size;
  const int*   idx   = (const int*)  d_in[0];
  const float* embed = (const float*)d_in[1];
  const float* wq    = (const float*)d_in[2];
  const float* wk    = (const float*)d_in[3];
  const float* wv    = (const float*)d_in[4];
  const float* wo    = (const float*)d_in[5];
  const float* ln1g  = (const float*)d_in[6];
  const float* ln2g  = (const float*)d_in[7];
  const float* wgate = (const float*)d_in[8];
  const float* wup   = (const float*)d_in[9];
  const float* wdown = (const float*)d_in[10];
  const float* fing  = (const float*)d_in[11];
  const float* lmh   = (const float*)d_in[12];
  float* out = (float*)d_out;

  // workspace layout (all fp32): ~101 MB
  float* ws  = (float*)d_ws;
  const long MD = (long)SQ * DMODEL;           // 4 Mi elems
  float* x    = ws;
  float* h    = x  + MD;
  float* qb   = h  + MD;
  float* kb   = qb + MD;
  float* vb   = kb + (long)SQ * 512;
  float* ffb  = vb + (long)SQ * 512;           // FF buffer (also head-15 scores: disjoint phases)
  float* cosT = ffb + (long)SQ * FFDIM;
  float* sinT = cosT + SQ * 64;
  float* yb   = qb;                            // attn-out aliases q (q dead after QK^T)
  float* sc15 = ffb;                           // head-15 scores (d_out only fits 15 heads)

  const long SSL = (long)SQ * SQ;
  const int  BIG = 1 << 30;
  const float scale = 0.08838834764831845f;    // 1/sqrt(128)

  rope_tables<<<SQ, 64, 0, stream>>>(cosT, sinT);
  embed_gather<<<(SQ * 512) / 256, 256, 0, stream>>>((f32x4*)x, (const f32x4*)embed, idx);

  for (int l = 0; l < NLAYER; ++l) {
    const float* lwq = wq    + (long)l * DMODEL * DMODEL;
    const float* lwk = wk    + (long)l * DMODEL * (NKV * HDIM);
    const float* lwv = wv    + (long)l * DMODEL * (NKV * HDIM);
    const float* lwo = wo    + (long)l * DMODEL * DMODEL;
    const float* lwg = wgate + (long)l * DMODEL * FFDIM;
    const float* lwu = wup   + (long)l * DMODEL * FFDIM;
    const float* lwd = wdown + (long)l * FFDIM * DMODEL;

    rmsnorm_kernel<<<SQ, 256, 0, stream>>>(h, x, ln1g + l * DMODEL);

    gemm_bf16<0, EP_STORE><<<dim3(16, 16, 1), 256, 0, stream>>>(
        h, lwq, qb, nullptr, nullptr, nullptr,
        DMODEL, DMODEL, DMODEL, DMODEL, DMODEL, 0, 0, 0, 1, BIG, BIG, 0.f);
    gemm_bf16<0, EP_STORE><<<dim3(4, 16, 1), 256, 0, stream>>>(
        h, lwk, kb, nullptr, nullptr, nullptr,
        512, DMODEL, DMODEL, 512, 512, 0, 0, 0, 1, BIG, BIG, 0.f);
    gemm_bf16<0, EP_STORE><<<dim3(4, 16, 1), 256, 0, stream>>>(
        h, lwv, vb, nullptr, nullptr, nullptr,
        512, DMODEL, DMODEL, 512, 512, 0, 0, 0, 1, BIG, BIG, 0.f);

    rope_apply<<<(SQ * NHEAD * 64) / 256, 256, 0, stream>>>(qb, cosT, sinT, NHEAD, DMODEL);
    rope_apply<<<(SQ * NKV * 64) / 256, 256, 0, stream>>>(kb, cosT, sinT, NKV, NKV * HDIM);

    // scores[h] = (Q_h K_h^T) * scale, masked (exact 0 above diagonal). heads 0..14 -> d_out, 15 -> ws
    gemm_bf16<1, EP_SCALEMASK><<<dim3(16, 16, NHEAD), 256, 0, stream>>>(
        qb, kb, out, nullptr, nullptr, sc15,
        SQ, HDIM, DMODEL, NKV * HDIM, SQ, (long)HDIM, (long)HDIM, SSL, 4, BIG, 15, scale);

    softmax_kernel<<<dim3(SQ, NHEAD), 256, 0, stream>>>(out, sc15, 15);

    // y[:, h*128:+128] = attn_h @ V_h
    gemm_bf16<0, EP_STORE><<<dim3(1, 16, NHEAD), 256, 0, stream>>>(
        out, vb, yb, nullptr, sc15, nullptr,
        HDIM, SQ, SQ, NKV * HDIM, DMODEL, SSL, (long)HDIM, (long)HDIM, 4, 15, BIG, 0.f);

    // x += y @ wo
    gemm_bf16<0, EP_ADD><<<dim3(16, 16, 1), 256, 0, stream>>>(
        yb, lwo, x, x, nullptr, nullptr,
        DMODEL, DMODEL, DMODEL, DMODEL, DMODEL, 0, 0, 0, 1, BIG, BIG, 0.f);

    rmsnorm_kernel<<<SQ, 256, 0, stream>>>(h, x, ln2g + l * DMODEL);

    // ffb = h @ w_gate ; ffb = silu(h @ w_up) * ffb ; x += ffb @ w_down
    gemm_bf16<0, EP_STORE><<<dim3(44, 16, 1), 256, 0, stream>>>(
        h, lwg, ffb, nullptr, nullptr, nullptr,
        FFDIM, DMODEL, DMODEL, FFDIM, FFDIM, 0, 0, 0, 1, BIG, BIG, 0.f);
    gemm_bf16<0, EP_SILUMUL><<<dim3(44, 16, 1), 256, 0, stream>>>(
        h, lwu, ffb, ffb, nullptr, nullptr,
        FFDIM, DMODEL, DMODEL, FFDIM, FFDIM, 0, 0, 0, 1, BIG, BIG, 0.f);
    gemm_bf16<0, EP_ADD><<<dim3(16, 16, 1), 256, 0, stream>>>(
        ffb, lwd, x, x, nullptr, nullptr,
        DMODEL, FFDIM, FFDIM, DMODEL, DMODEL, 0, 0, 0, 1, BIG, BIG, 0.f);
  }

  rmsnorm_kernel<<<SQ, 256, 0, stream>>>(h, x, fing);

  // logits = h @ lm_head^T
  gemm_bf16<1, EP_STORE><<<dim3(VOCAB / BN, 16, 1), 256, 0, stream>>>(
      h, lmh, out, nullptr, nullptr, nullptr,
      VOCAB, DMODEL, DMODEL, DMODEL, VOCAB, 0, 0, 0, 1, BIG, BIG, 0.f);
}

// Round 2
// 1797.288 us; speedup vs baseline: 1.6071x; 1.6071x over previous
//
#include <hip/hip_runtime.h>

#define SQ     2048
#define DMODEL 2048
#define NHEAD  16
#define NKV    4
#define HDIM   128
#define FFDIM  5632
#define VOCAB  32000
#define NLAYER 2
#define EPSV   1e-5f

typedef __bf16 bf16;
typedef __bf16 bf16x4 __attribute__((ext_vector_type(4)));
typedef __bf16 bf16x8 __attribute__((ext_vector_type(8)));
typedef float  f32x4  __attribute__((ext_vector_type(4)));

enum { EP_STOREF = 0, EP_SCALEMASK = 1, EP_ADD = 2, EP_STOREB = 3, EP_STOREB_T = 4, EP_SILUMUL = 5 };

#define BM 128
#define BN 128
#define BK 64

// global -> LDS direct DMA, 16B per lane; dest = wave-uniform base + lane*16
#define GLD(gp, lp) __builtin_amdgcn_global_load_lds( \
    (const __attribute__((address_space(1))) void*)(gp), \
    (__attribute__((address_space(3))) void*)(lp), 16, 0, 0)

// C = A(2048 x K, bf16 row-major) * B(N x K, bf16 row-major = B^T).
// Grid: x = m-tile (fast), y = n-tile, z = batch. XCD-bijective swizzle + m-fastest decode.
template<int EPI, int CAUSAL>
__global__ __launch_bounds__(256, 2)
void gemm_bf16(const bf16* __restrict__ A, const bf16* __restrict__ B,
               void* __restrict__ C, const void* __restrict__ Cin,
               const bf16* __restrict__ Aalt, void* __restrict__ Calt,
               int K, int lda, int ldb, int ldc,
               long sA, long sB, long sC, int kvShift, int zsplitA, int zsplitC,
               float scale)
{
  __shared__ bf16 As[BM * BK];
  __shared__ bf16 Bs[BN * BK];

  const int tid  = (int)threadIdx.x;
  const int lane = tid & 63;
  const int wave = tid >> 6;
  const int wm   = wave >> 1, wn = wave & 1;
  const int z    = (int)blockIdx.z;

  // bijective XCD swizzle (m204), then m-fastest decode
  const int GM  = (int)gridDim.x;
  const int nwg = GM * (int)gridDim.y;
  const int bid = (int)blockIdx.y * GM + (int)blockIdx.x;
  const int q8  = nwg >> 3, r8 = nwg & 7;
  const int xcd = bid & 7, rnk = bid >> 3;
  const int swz = ((xcd < r8) ? xcd * (q8 + 1) : r8 * (q8 + 1) + (xcd - r8) * q8) + rnk;
  const int m0  = (swz % GM) * BM;
  const int n0  = (swz / GM) * BN;

  void* Cb = (z < zsplitC) ? C : Calt;
  const long zc = (z < zsplitC) ? (long)z : (long)(z - zsplitC);

  const int colr = (lane >> 4) * 4;  // frag row base (within 16)
  const int colc = lane & 15;        // frag col

  if (CAUSAL && n0 >= m0 + BM) {     // fully-masked QK^T tile: output is exactly 0
    float* Cf = (float*)Cb + zc * sC;
    #pragma unroll
    for (int m = 0; m < 4; ++m) {
      const int gr0 = m0 + wm * 64 + m * 16 + colr;
      #pragma unroll
      for (int n = 0; n < 4; ++n) {
        const int gc = n0 + wn * 64 + n * 16 + colc;
        #pragma unroll
        for (int r = 0; r < 4; ++r) Cf[(long)(gr0 + r) * ldc + gc] = 0.0f;
      }
    }
    return;
  }

  const bf16* Ap = (z < zsplitA) ? (A + (long)z * sA) : (Aalt + (long)(z - zsplitA) * sA);
  const bf16* Bp = B + (long)(z >> kvShift) * sB;

  const int srow = lane >> 3;        // staging row within 8-row chunk
  const int scol = (lane & 7) * 8;   // staging col (elems)

  f32x4 acc[4][4] = {};

  for (int kt = 0; kt < K; kt += BK) {
    #pragma unroll
    for (int c = 0; c < 4; ++c) {
      const int chunk = wave * 4 + c;          // 16 chunks of 8 rows x 64 cols
      const int row   = chunk * 8 + srow;
      GLD(Ap + (long)(m0 + row) * lda + kt + scol, As + chunk * 512);
      GLD(Bp + (long)(n0 + row) * ldb + kt + scol, Bs + chunk * 512);
    }
    __syncthreads();
    #pragma unroll
    for (int kk = 0; kk < 2; ++kk) {
      const int ko = kk * 32 + (lane >> 4) * 8;
      bf16x8 af[4], bv[4];
      #pragma unroll
      for (int m = 0; m < 4; ++m)
        af[m] = *(const bf16x8*)(As + (wm * 64 + m * 16 + colc) * BK + ko);
      #pragma unroll
      for (int n = 0; n < 4; ++n)
        bv[n] = *(const bf16x8*)(Bs + (wn * 64 + n * 16 + colc) * BK + ko);
      #pragma unroll
      for (int m = 0; m < 4; ++m)
        #pragma unroll
        for (int n = 0; n < 4; ++n)
          acc[m][n] = __builtin_amdgcn_mfma_f32_16x16x32_bf16(af[m], bv[n], acc[m][n], 0, 0, 0);
    }
    __syncthreads();
  }

  // epilogue. C/D frag: col = lane&15, row = (lane>>4)*4 + reg
  #pragma unroll
  for (int m = 0; m < 4; ++m) {
    const int gr0 = m0 + wm * 64 + m * 16 + colr;
    #pragma unroll
    for (int n = 0; n < 4; ++n) {
      const int gc = n0 + wn * 64 + n * 16 + colc;
      if (EPI == EP_STOREB_T) {
        bf16* Cp = (bf16*)Cb + zc * sC;
        bf16x4 pk = { (bf16)acc[m][n][0], (bf16)acc[m][n][1],
                      (bf16)acc[m][n][2], (bf16)acc[m][n][3] };
        *(bf16x4*)(Cp + (long)gc * ldc + gr0) = pk;
      } else {
        #pragma unroll
        for (int r = 0; r < 4; ++r) {
          const int  gr  = gr0 + r;
          const long off = (long)gr * ldc + gc;
          float v = acc[m][n][r];
          if (EPI == EP_STOREF) {
            ((float*)Cb + zc * sC)[off] = v;
          } else if (EPI == EP_SCALEMASK) {
            ((float*)Cb + zc * sC)[off] = (gc > gr) ? 0.0f : v * scale;
          } else if (EPI == EP_ADD) {
            float* Cf = (float*)Cb + zc * sC;
            Cf[off] = ((const float*)Cin)[off] + v;
          } else if (EPI == EP_STOREB) {
            ((bf16*)Cb + zc * sC)[off] = (bf16)v;
          } else { // EP_SILUMUL: out = silu(up) * gate
            bf16* Cf = (bf16*)Cb + zc * sC;
            const float g = (float)((const bf16*)Cin)[off];
            Cf[off] = (bf16)((v / (1.0f + __expf(-v))) * g);
          }
        }
      }
    }
  }
}

// fp32 [K][N] -> bf16 [N][K] transpose+convert, 32x32 LDS tiles
__global__ __launch_bounds__(256)
void transpose_cvt(const float* __restrict__ in, bf16* __restrict__ out, int K, int N)
{
  __shared__ float t[32][33];
  const int n0 = (int)blockIdx.x * 32, k0 = (int)blockIdx.y * 32;
  const int tr = (int)threadIdx.x >> 3;
  const int tc = ((int)threadIdx.x & 7) * 4;
  f32x4 v = *(const f32x4*)(in + (long)(k0 + tr) * N + n0 + tc);
  t[tr][tc] = v[0]; t[tr][tc + 1] = v[1]; t[tr][tc + 2] = v[2]; t[tr][tc + 3] = v[3];
  __syncthreads();
  bf16x4 b = { (bf16)t[tc][tr], (bf16)t[tc + 1][tr], (bf16)t[tc + 2][tr], (bf16)t[tc + 3][tr] };
  *(bf16x4*)(out + (long)(n0 + tr) * K + k0 + tc) = b;
}

__global__ __launch_bounds__(256)
void cvt_bf16_kernel(const float* __restrict__ in, bf16* __restrict__ out, int nvec)
{
  const int i = (int)(blockIdx.x * 256 + threadIdx.x);
  if (i < nvec) {
    f32x4 v = ((const f32x4*)in)[i];
    bf16x4 b = { (bf16)v[0], (bf16)v[1], (bf16)v[2], (bf16)v[3] };
    ((bf16x4*)out)[i] = b;
  }
}

__global__ __launch_bounds__(256)
void rmsnorm_kernel(bf16* __restrict__ out, const float* __restrict__ in, const float* __restrict__ g)
{
  const int row = (int)blockIdx.x;
  const float* x = in + (long)row * DMODEL;
  bf16* o = out + (long)row * DMODEL;
  const int tid = (int)threadIdx.x;
  f32x4 v0 = *(const f32x4*)(x + tid * 4);
  f32x4 v1 = *(const f32x4*)(x + tid * 4 + 1024);
  float ss = v0[0]*v0[0] + v0[1]*v0[1] + v0[2]*v0[2] + v0[3]*v0[3]
           + v1[0]*v1[0] + v1[1]*v1[1] + v1[2]*v1[2] + v1[3]*v1[3];
  #pragma unroll
  for (int o_ = 32; o_; o_ >>= 1) ss += __shfl_xor(ss, o_);
  __shared__ float sm[4];
  if ((tid & 63) == 0) sm[tid >> 6] = ss;
  __syncthreads();
  ss = sm[0] + sm[1] + sm[2] + sm[3];
  const float r = 1.0f / sqrtf(ss * (1.0f / DMODEL) + EPSV);
  f32x4 g0 = *(const f32x4*)(g + tid * 4);
  f32x4 g1 = *(const f32x4*)(g + tid * 4 + 1024);
  bf16x4 o0, o1;
  #pragma unroll
  for (int j = 0; j < 4; ++j) { o0[j] = (bf16)(v0[j] * r * g0[j]); o1[j] = (bf16)(v1[j] * r * g1[j]); }
  *(bf16x4*)(o + tid * 4) = o0;
  *(bf16x4*)(o + tid * 4 + 1024) = o1;
}

// full-row softmax over fp32 scores; writes bf16 probs IN-PLACE (packed in first half of each 8KB row)
__global__ __launch_bounds__(256)
void softmax_kernel(float* base, float* alt, int zsplit)
{
  const int row = (int)blockIdx.x;
  const int z   = (int)blockIdx.y;
  const long SSL = (long)SQ * SQ;
  float* p = ((z < zsplit) ? (base + (long)z * SSL) : (alt + (long)(z - zsplit) * SSL))
             + (long)row * SQ;
  const int tid = (int)threadIdx.x;
  f32x4 v0 = *(f32x4*)(p + tid * 4);
  f32x4 v1 = *(f32x4*)(p + tid * 4 + 1024);
  float mx = fmaxf(fmaxf(fmaxf(v0[0], v0[1]), fmaxf(v0[2], v0[3])),
                   fmaxf(fmaxf(v1[0], v1[1]), fmaxf(v1[2], v1[3])));
  #pragma unroll
  for (int o = 32; o; o >>= 1) mx = fmaxf(mx, __shfl_xor(mx, o));
  __shared__ float sm[4], sv[4];
  if ((tid & 63) == 0) sm[tid >> 6] = mx;
  __syncthreads();
  mx = fmaxf(fmaxf(sm[0], sm[1]), fmaxf(sm[2], sm[3]));
  float s = 0.f;
  #pragma unroll
  for (int j = 0; j < 4; ++j) { v0[j] = __expf(v0[j] - mx); s += v0[j]; }
  #pragma unroll
  for (int j = 0; j < 4; ++j) { v1[j] = __expf(v1[j] - mx); s += v1[j]; }
  #pragma unroll
  for (int o = 32; o; o >>= 1) s += __shfl_xor(s, o);
  if ((tid & 63) == 0) sv[tid >> 6] = s;
  __syncthreads();
  s = sv[0] + sv[1] + sv[2] + sv[3];
  const float inv = 1.0f / s;
  bf16* ob = (bf16*)p;
  bf16x4 b0, b1;
  #pragma unroll
  for (int j = 0; j < 4; ++j) { b0[j] = (bf16)(v0[j] * inv); b1[j] = (bf16)(v1[j] * inv); }
  *(bf16x4*)(ob + tid * 4) = b0;
  *(bf16x4*)(ob + tid * 4 + 1024) = b1;
}

__global__ void rope_tables(float* cosT, float* sinT)
{
  const int s = (int)blockIdx.x;
  const int i = (int)threadIdx.x;   // 0..63
  const double inv = pow(10000.0, -(double)i / 64.0);
  const double f = (double)s * inv;
  cosT[s * 64 + i] = (float)cos(f);
  sinT[s * 64 + i] = (float)sin(f);
}

__global__ __launch_bounds__(256)
void rope_apply(bf16* buf, const float* cosT, const float* sinT, int nh, int stride)
{
  const int t = (int)(blockIdx.x * blockDim.x + threadIdx.x);
  const int per = nh * 64;
  const int s = t / per;
  const int r = t - s * per;
  const int h = r >> 6;
  const int i = r & 63;
  bf16* b = buf + (long)s * stride + h * HDIM;
  const float c  = cosT[s * 64 + i];
  const float sn = sinT[s * 64 + i];
  const float x1 = (float)b[i];
  const float x2 = (float)b[64 + i];
  b[i]      = (bf16)(x1 * c - x2 * sn);
  b[64 + i] = (bf16)(x2 * c + x1 * sn);
}

__global__ __launch_bounds__(256)
void embed_gather(f32x4* x, const f32x4* embed, const int* idx)
{
  const int t = (int)(blockIdx.x * 256 + threadIdx.x);
  const int s = t >> 9;      // 512 f32x4 per row
  const int c = t & 511;
  x[t] = embed[(long)idx[s] * 512 + c];
}

extern "C" void kernel_launch(void* const* d_in, const int* in_sizes, int n_in,
                              void* d_out, int out_size, void* d_ws, size_t ws_size,
                              hipStream_t stream)
{
  (void)in_sizes; (void)n_in; (void)out_size;
  const int*   idx   = (const int*)  d_in[0];
  const float* embed = (const float*)d_in[1];
  const float* wq    = (const float*)d_in[2];
  const float* wk    = (const float*)d_in[3];
  const float* wv    = (const float*)d_in[4];
  const float* wo    = (const float*)d_in[5];
  const float* ln1g  = (const float*)d_in[6];
  const float* ln2g  = (const float*)d_in[7];
  const float* wgate = (const float*)d_in[8];
  const float* wup   = (const float*)d_in[9];
  const float* wdown = (const float*)d_in[10];
  const float* fing  = (const float*)d_in[11];
  const float* lmh   = (const float*)d_in[12];
  float* out = (float*)d_out;

  // ---- workspace layout (~59MB fixed + weight scratch)
  char* wp = (char*)d_ws;
  auto alloc = [&](size_t bytes) { char* p = wp; wp += (bytes + 255) & ~(size_t)255; return p; };
  float* cosT = (float*)alloc((size_t)SQ * 64 * 4);
  float* sinT = (float*)alloc((size_t)SQ * 64 * 4);
  float* x    = (float*)alloc((size_t)SQ * DMODEL * 4);
  bf16*  h    = (bf16*) alloc((size_t)SQ * DMODEL * 2);
  bf16*  qb   = (bf16*) alloc((size_t)SQ * DMODEL * 2);
  bf16*  kb   = (bf16*) alloc((size_t)SQ * 512 * 2);
  bf16*  vT   = (bf16*) alloc((size_t)512 * SQ * 2);
  char*  fscr = alloc((size_t)SQ * FFDIM * 2);    // ffb (bf16, MLP) / sc15 (fp32, attn) — disjoint phases
  bf16*  ffb  = (bf16*) fscr;
  float* sc15 = (float*)fscr;
  size_t used  = (size_t)(wp - (char*)d_ws);
  bf16*  wbuf  = (bf16*)wp;                        // per-GEMM weight scratch (max 22MB) / lm_head chunks
  size_t avail = ws_size - used;

  bf16* yb = qb;                                   // attn-out aliases q (q dead after QK^T)
  const long SSL = (long)SQ * SQ;
  const int  BIG = 1 << 30;
  const float scale = 0.08838834764831845f;        // 1/sqrt(128)

  rope_tables<<<SQ, 64, 0, stream>>>(cosT, sinT);
  embed_gather<<<(SQ * 512) / 256, 256, 0, stream>>>((f32x4*)x, (const f32x4*)embed, idx);

  for (int l = 0; l < NLAYER; ++l) {
    const float* lwq = wq    + (long)l * DMODEL * DMODEL;
    const float* lwk = wk    + (long)l * DMODEL * 512;
    const float* lwv = wv    + (long)l * DMODEL * 512;
    const float* lwo = wo    + (long)l * DMODEL * DMODEL;
    const float* lwg = wgate + (long)l * DMODEL * FFDIM;
    const float* lwu = wup   + (long)l * DMODEL * FFDIM;
    const float* lwd = wdown + (long)l * FFDIM * DMODEL;

    rmsnorm_kernel<<<SQ, 256, 0, stream>>>(h, x, ln1g + l * DMODEL);

    transpose_cvt<<<dim3(DMODEL / 32, DMODEL / 32), 256, 0, stream>>>(lwq, wbuf, DMODEL, DMODEL);
    gemm_bf16<EP_STOREB, 0><<<dim3(16, 16, 1), 256, 0, stream>>>(
        h, wbuf, qb, nullptr, nullptr, nullptr,
        DMODEL, DMODEL, DMODEL, DMODEL, 0, 0, 0, 0, BIG, BIG, 0.f);

    transpose_cvt<<<dim3(512 / 32, DMODEL / 32), 256, 0, stream>>>(lwk, wbuf, DMODEL, 512);
    gemm_bf16<EP_STOREB, 0><<<dim3(16, 4, 1), 256, 0, stream>>>(
        h, wbuf, kb, nullptr, nullptr, nullptr,
        DMODEL, DMODEL, DMODEL, 512, 0, 0, 0, 0, BIG, BIG, 0.f);

    transpose_cvt<<<dim3(512 / 32, DMODEL / 32), 256, 0, stream>>>(lwv, wbuf, DMODEL, 512);
    gemm_bf16<EP_STOREB_T, 0><<<dim3(16, 4, 1), 256, 0, stream>>>(   // v -> vT[c][s]
        h, wbuf, vT, nullptr, nullptr, nullptr,
        DMODEL, DMODEL, DMODEL, SQ, 0, 0, 0, 0, BIG, BIG, 0.f);

    rope_apply<<<(SQ * NHEAD * 64) / 256, 256, 0, stream>>>(qb, cosT, sinT, NHEAD, DMODEL);
    rope_apply<<<(SQ * NKV * 64) / 256, 256, 0, stream>>>(kb, cosT, sinT, NKV, 512);

    // scores[h] = (Q_h K_h^T)*scale, masked to exact 0 above diagonal; heads 0..14 -> d_out, 15 -> sc15
    gemm_bf16<EP_SCALEMASK, 1><<<dim3(16, 16, NHEAD), 256, 0, stream>>>(
        qb, kb, out, nullptr, nullptr, sc15,
        HDIM, DMODEL, 512, SQ, 128, 128, SSL, 2, BIG, 15, scale);

    softmax_kernel<<<dim3(SQ, NHEAD), 256, 0, stream>>>(out, sc15, 15);

    // y[:, h*128:+128] = P_h @ V_h  (P bf16 in-place, lda=4096; full K — masked probs are NOT zero)
    gemm_bf16<EP_STOREB, 0><<<dim3(16, 1, NHEAD), 256, 0, stream>>>(
        (const bf16*)out, vT, yb, nullptr, (const bf16*)sc15, nullptr,
        SQ, 2 * SQ, SQ, DMODEL, 2L * SQ * SQ, (long)HDIM * SQ, HDIM, 2, 15, BIG, 0.f);

    transpose_cvt<<<dim3(DMODEL / 32, DMODEL / 32), 256, 0, stream>>>(lwo, wbuf, DMODEL, DMODEL);
    gemm_bf16<EP_ADD, 0><<<dim3(16, 16, 1), 256, 0, stream>>>(
        yb, wbuf, x, x, nullptr, nullptr,
        DMODEL, DMODEL, DMODEL, DMODEL, 0, 0, 0, 0, BIG, BIG, 0.f);

    rmsnorm_kernel<<<SQ, 256, 0, stream>>>(h, x, ln2g + l * DMODEL);

    transpose_cvt<<<dim3(FFDIM / 32, DMODEL / 32), 256, 0, stream>>>(lwg, wbuf, DMODEL, FFDIM);
    gemm_bf16<EP_STOREB, 0><<<dim3(16, 44, 1), 256, 0, stream>>>(
        h, wbuf, ffb, nullptr, nullptr, nullptr,
        DMODEL, DMODEL, DMODEL, FFDIM, 0, 0, 0, 0, BIG, BIG, 0.f);

    transpose_cvt<<<dim3(FFDIM / 32, DMODEL / 32), 256, 0, stream>>>(lwu, wbuf, DMODEL, FFDIM);
    gemm_bf16<EP_SILUMUL, 0><<<dim3(16, 44, 1), 256, 0, stream>>>(
        h, wbuf, ffb, ffb, nullptr, nullptr,
        DMODEL, DMODEL, DMODEL, FFDIM, 0, 0, 0, 0, BIG, BIG, 0.f);

    transpose_cvt<<<dim3(DMODEL / 32, FFDIM / 32), 256, 0, stream>>>(lwd, wbuf, FFDIM, DMODEL);
    gemm_bf16<EP_ADD, 0><<<dim3(16, 16, 1), 256, 0, stream>>>(
        ffb, wbuf, x, x, nullptr, nullptr,
        FFDIM, FFDIM, FFDIM, DMODEL, 0, 0, 0, 0, BIG, BIG, 0.f);
  }

  rmsnorm_kernel<<<SQ, 256, 0, stream>>>(h, x, fing);

  // logits = h @ lm_head^T, lm_head converted to bf16 in ws-sized chunks (already N x K layout)
  long chunkRows = (long)(avail / ((size_t)DMODEL * 2)) & ~127L;
  if (chunkRows > VOCAB) chunkRows = VOCAB;
  for (long c0 = 0; c0 < VOCAB; c0 += chunkRows) {
    const long rows = (VOCAB - c0 < chunkRows) ? (VOCAB - c0) : chunkRows;
    const int  nvec = (int)(rows * DMODEL / 4);
    cvt_bf16_kernel<<<(nvec + 255) / 256, 256, 0, stream>>>(lmh + c0 * DMODEL, wbuf, nvec);
    gemm_bf16<EP_STOREF, 0><<<dim3(16, (int)(rows / 128), 1), 256, 0, stream>>>(
        h, wbuf, out + c0, nullptr, nullptr, nullptr,
        DMODEL, DMODEL, DMODEL, VOCAB, 0, 0, 0, 0, BIG, BIG, 0.f);
  }
}

// Round 3
// 1690.032 us; speedup vs baseline: 1.7091x; 1.0635x over previous
//
#include <hip/hip_runtime.h>

#define SQ     2048
#define DMODEL 2048
#define NHEAD  16
#define NKV    4
#define HDIM   128
#define FFDIM  5632
#define VOCAB  32000
#define NLAYER 2
#define EPSV   1e-5f

typedef __bf16 bf16;
typedef __bf16 bf16x4 __attribute__((ext_vector_type(4)));
typedef __bf16 bf16x8 __attribute__((ext_vector_type(8)));
typedef float  f32x4  __attribute__((ext_vector_type(4)));

enum { EP_STOREF = 0, EP_SCALEMASK = 1, EP_ADD = 2, EP_STOREB = 3, EP_STOREB_T = 4, EP_SILUMUL = 5 };

// global -> LDS direct DMA, 16B per lane; LDS dest = wave-uniform base + lane*16
#define GLD(gp, lp) __builtin_amdgcn_global_load_lds( \
    (const __attribute__((address_space(1))) void*)(gp), \
    (__attribute__((address_space(3))) void*)(lp), 16, 0, 0)

#define MFMA16(a, b, c) __builtin_amdgcn_mfma_f32_16x16x32_bf16(a, b, c, 0, 0, 0)

#define FENCE() __builtin_amdgcn_sched_barrier(0)
#define PH_BAR() do { FENCE(); __builtin_amdgcn_s_barrier(); FENCE(); } while (0)

// ============================================================================
// 256x256-tile, BK=64, 8-wave, 4-phase/K-tile pipelined GEMM (T2+T3+T4+T5).
// A: M x K bf16 row-major. B: N x K bf16 row-major (B^T). M = 256*gridDim.x.
// LDS: 2 buffers x 4 half-tile slots {A0,A1,B0,B1}, each [128][64] bf16,
// XOR-swizzled: phys 16B-slot = logical ^ (row&7), both on DMA-src and ds_read.
// Counted vmcnt(6) at phase d only (vmcnt(0) for last 2 tiles). Raw barriers.
// ============================================================================
template<int EPI>
__global__ __launch_bounds__(512, 2)
void gemm256(const bf16* __restrict__ A, const bf16* __restrict__ B,
             void* __restrict__ C, const void* __restrict__ Cin,
             int K, int lda, int ldb, int ldc)
{
  __shared__ bf16 smem[2][4][128 * 64];   // 128 KiB

  const int tid  = (int)threadIdx.x;
  const int lane = tid & 63;
  const int wave = tid >> 6;              // 0..7
  const int wm   = wave >> 2;             // 0..1  (M half)
  const int wn   = wave & 3;              // 0..3  (N quarter)

  // bijective XCD swizzle, m-fastest decode
  const int GM  = (int)gridDim.x;
  const int nwg = GM * (int)gridDim.y;
  const int bid = (int)blockIdx.y * GM + (int)blockIdx.x;
  const int q8  = nwg >> 3, r8 = nwg & 7;
  const int xcd = bid & 7, rnk = bid >> 3;
  const int swz = ((xcd < r8) ? xcd * (q8 + 1) : r8 * (q8 + 1) + (xcd - r8) * q8) + rnk;
  const int m0  = (swz % GM) * 256;
  const int n0  = (swz / GM) * 256;

  const int nkt  = K >> 6;                // K-tiles of 64
  const int srow = lane >> 3;             // DMA: row within 8-row chunk
  const long sxcol = (long)(((lane & 7) ^ (lane >> 3)) * 8);   // DMA src col (swizzled)
  const int frow = lane & 15;
  const int ph0  = ((     (lane >> 4)) ^ (lane & 7)) * 16;     // ds_read phys byte, kstep 0
  const int ph1  = ((4 + (lane >> 4)) ^ (lane & 7)) * 16;      // kstep 1

  auto stageA = [&](int tile, int half) {
    if (tile < nkt) {
      const long kc = (long)tile * 64 + sxcol;
      #pragma unroll
      for (int i = 0; i < 2; ++i)
        GLD(A + (long)(m0 + half * 128 + wave * 16 + i * 8 + srow) * lda + kc,
            smem[tile & 1][half] + (wave * 16 + i * 8) * 64);
    }
  };
  auto stageB = [&](int tile, int half) {
    if (tile < nkt) {
      const long kc = (long)tile * 64 + sxcol;
      #pragma unroll
      for (int i = 0; i < 2; ++i)
        GLD(B + (long)(n0 + half * 128 + wave * 16 + i * 8 + srow) * ldb + kc,
            smem[tile & 1][2 + half] + (wave * 16 + i * 8) * 64);
    }
  };

  // ---- prologue: t0.{B0,B1,A0,A1}, vmcnt(4), t1.{B0,B1,A0}, vmcnt(6)
  stageB(0, 0); stageB(0, 1); stageA(0, 0); stageA(0, 1);
  asm volatile("s_waitcnt vmcnt(4)" ::: "memory");
  stageB(1, 0); stageB(1, 1); stageA(1, 0);
  asm volatile("s_waitcnt vmcnt(6)" ::: "memory");
  PH_BAR();

  f32x4 acc[8][4] = {};

  for (int t = 0; t < nkt; ++t) {
    const int bsel = t & 1;
    const char* Asl = (const char*)smem[bsel][wm];
    const char* Bsl = (const char*)smem[bsel][2 + (wn >> 1)];
    const int brow = (wn & 1) * 64;

    bf16x8 ar[4][2], b0f[2][2], b1f[2][2];

    // ---- phase a: read A mr0-3 + B nc0-1; stage (t+1).A1; MFMA quadrant (M0,N0)
    #pragma unroll
    for (int mr = 0; mr < 4; ++mr) {
      ar[mr][0] = *(const bf16x8*)(Asl + (mr * 16 + frow) * 128 + ph0);
      ar[mr][1] = *(const bf16x8*)(Asl + (mr * 16 + frow) * 128 + ph1);
    }
    #pragma unroll
    for (int nc = 0; nc < 2; ++nc) {
      b0f[nc][0] = *(const bf16x8*)(Bsl + (brow + nc * 16 + frow) * 128 + ph0);
      b0f[nc][1] = *(const bf16x8*)(Bsl + (brow + nc * 16 + frow) * 128 + ph1);
    }
    stageA(t + 1, 1);
    PH_BAR();
    __builtin_amdgcn_s_setprio(1);
    #pragma unroll
    for (int mr = 0; mr < 4; ++mr)
      #pragma unroll
      for (int nc = 0; nc < 2; ++nc) {
        acc[mr][nc] = MFMA16(ar[mr][0], b0f[nc][0], acc[mr][nc]);
        acc[mr][nc] = MFMA16(ar[mr][1], b0f[nc][1], acc[mr][nc]);
      }
    __builtin_amdgcn_s_setprio(0);
    PH_BAR();

    // ---- phase b: read B nc2-3; MFMA (M0,N1)
    #pragma unroll
    for (int nc = 0; nc < 2; ++nc) {
      b1f[nc][0] = *(const bf16x8*)(Bsl + (brow + (2 + nc) * 16 + frow) * 128 + ph0);
      b1f[nc][1] = *(const bf16x8*)(Bsl + (brow + (2 + nc) * 16 + frow) * 128 + ph1);
    }
    PH_BAR();
    __builtin_amdgcn_s_setprio(1);
    #pragma unroll
    for (int mr = 0; mr < 4; ++mr)
      #pragma unroll
      for (int nc = 0; nc < 2; ++nc) {
        acc[mr][2 + nc] = MFMA16(ar[mr][0], b1f[nc][0], acc[mr][2 + nc]);
        acc[mr][2 + nc] = MFMA16(ar[mr][1], b1f[nc][1], acc[mr][2 + nc]);
      }
    __builtin_amdgcn_s_setprio(0);
    PH_BAR();

    // ---- phase c: read A mr4-7 (overwrite ar); stage (t+2).B0,B1; MFMA (M1,N0)
    #pragma unroll
    for (int mr = 0; mr < 4; ++mr) {
      ar[mr][0] = *(const bf16x8*)(Asl + ((4 + mr) * 16 + frow) * 128 + ph0);
      ar[mr][1] = *(const bf16x8*)(Asl + ((4 + mr) * 16 + frow) * 128 + ph1);
    }
    stageB(t + 2, 0); stageB(t + 2, 1);
    PH_BAR();
    __builtin_amdgcn_s_setprio(1);
    #pragma unroll
    for (int mr = 0; mr < 4; ++mr)
      #pragma unroll
      for (int nc = 0; nc < 2; ++nc) {
        acc[4 + mr][nc] = MFMA16(ar[mr][0], b0f[nc][0], acc[4 + mr][nc]);
        acc[4 + mr][nc] = MFMA16(ar[mr][1], b0f[nc][1], acc[4 + mr][nc]);
      }
    __builtin_amdgcn_s_setprio(0);
    PH_BAR();

    // ---- phase d: stage (t+2).A0; MFMA (M1,N1); counted vmcnt; close
    stageA(t + 2, 0);
    PH_BAR();
    __builtin_amdgcn_s_setprio(1);
    #pragma unroll
    for (int mr = 0; mr < 4; ++mr)
      #pragma unroll
      for (int nc = 0; nc < 2; ++nc) {
        acc[4 + mr][2 + nc] = MFMA16(ar[mr][0], b1f[nc][0], acc[4 + mr][2 + nc]);
        acc[4 + mr][2 + nc] = MFMA16(ar[mr][1], b1f[nc][1], acc[4 + mr][2 + nc]);
      }
    __builtin_amdgcn_s_setprio(0);
    FENCE();
    if (t + 2 < nkt) asm volatile("s_waitcnt vmcnt(6)" ::: "memory");
    else             asm volatile("s_waitcnt vmcnt(0)" ::: "memory");
    PH_BAR();
  }

  // ---- epilogue. C/D frag: col = lane&15, row = (lane>>4)*4 + reg
  #pragma unroll
  for (int mr = 0; mr < 8; ++mr) {
    const int gr0 = m0 + wm * 128 + mr * 16 + (lane >> 4) * 4;
    #pragma unroll
    for (int nc = 0; nc < 4; ++nc) {
      const int gc = n0 + wn * 64 + nc * 16 + (lane & 15);
      #pragma unroll
      for (int r = 0; r < 4; ++r) {
        const long off = (long)(gr0 + r) * ldc + gc;
        const float v = acc[mr][nc][r];
        if (EPI == EP_STOREF) {
          ((float*)C)[off] = v;
        } else if (EPI == EP_STOREB) {
          ((bf16*)C)[off] = (bf16)v;
        } else if (EPI == EP_SILUMUL) {
          const float g = (float)((const bf16*)Cin)[off];
          ((bf16*)C)[off] = (bf16)((v / (1.0f + __expf(-v))) * g);
        }
      }
    }
  }
}

// ============================================================================
// 128x128-tile m97-structure GEMM (kept for small/odd-shaped GEMMs)
// ============================================================================
#define BM 128
#define BN 128
#define BK 64

template<int EPI, int CAUSAL>
__global__ __launch_bounds__(256, 2)
void gemm_bf16(const bf16* __restrict__ A, const bf16* __restrict__ B,
               void* __restrict__ C, const void* __restrict__ Cin,
               const bf16* __restrict__ Aalt, void* __restrict__ Calt,
               int K, int lda, int ldb, int ldc,
               long sA, long sB, long sC, int kvShift, int zsplitA, int zsplitC,
               float scale)
{
  __shared__ bf16 As[BM * BK];
  __shared__ bf16 Bs[BN * BK];

  const int tid  = (int)threadIdx.x;
  const int lane = tid & 63;
  const int wave = tid >> 6;
  const int wm   = wave >> 1, wn = wave & 1;
  const int z    = (int)blockIdx.z;

  const int GM  = (int)gridDim.x;
  const int nwg = GM * (int)gridDim.y;
  const int bid = (int)blockIdx.y * GM + (int)blockIdx.x;
  const int q8  = nwg >> 3, r8 = nwg & 7;
  const int xcd = bid & 7, rnk = bid >> 3;
  const int swz = ((xcd < r8) ? xcd * (q8 + 1) : r8 * (q8 + 1) + (xcd - r8) * q8) + rnk;
  const int m0  = (swz % GM) * BM;
  const int n0  = (swz / GM) * BN;

  void* Cb = (z < zsplitC) ? C : Calt;
  const long zc = (z < zsplitC) ? (long)z : (long)(z - zsplitC);

  const int colr = (lane >> 4) * 4;
  const int colc = lane & 15;

  if (CAUSAL && n0 >= m0 + BM) {     // fully-masked QK^T tile: output exactly 0
    float* Cf = (float*)Cb + zc * sC;
    #pragma unroll
    for (int m = 0; m < 4; ++m) {
      const int gr0 = m0 + wm * 64 + m * 16 + colr;
      #pragma unroll
      for (int n = 0; n < 4; ++n) {
        const int gc = n0 + wn * 64 + n * 16 + colc;
        #pragma unroll
        for (int r = 0; r < 4; ++r) Cf[(long)(gr0 + r) * ldc + gc] = 0.0f;
      }
    }
    return;
  }

  const bf16* Ap = (z < zsplitA) ? (A + (long)z * sA) : (Aalt + (long)(z - zsplitA) * sA);
  const bf16* Bp = B + (long)(z >> kvShift) * sB;

  const int srow = lane >> 3;
  const int scol = (lane & 7) * 8;

  f32x4 acc[4][4] = {};

  for (int kt = 0; kt < K; kt += BK) {
    #pragma unroll
    for (int c = 0; c < 4; ++c) {
      const int chunk = wave * 4 + c;
      const int row   = chunk * 8 + srow;
      GLD(Ap + (long)(m0 + row) * lda + kt + scol, As + chunk * 512);
      GLD(Bp + (long)(n0 + row) * ldb + kt + scol, Bs + chunk * 512);
    }
    __syncthreads();
    #pragma unroll
    for (int kk = 0; kk < 2; ++kk) {
      const int ko = kk * 32 + (lane >> 4) * 8;
      bf16x8 af[4], bv[4];
      #pragma unroll
      for (int m = 0; m < 4; ++m)
        af[m] = *(const bf16x8*)(As + (wm * 64 + m * 16 + colc) * BK + ko);
      #pragma unroll
      for (int n = 0; n < 4; ++n)
        bv[n] = *(const bf16x8*)(Bs + (wn * 64 + n * 16 + colc) * BK + ko);
      #pragma unroll
      for (int m = 0; m < 4; ++m)
        #pragma unroll
        for (int n = 0; n < 4; ++n)
          acc[m][n] = MFMA16(af[m], bv[n], acc[m][n]);
    }
    __syncthreads();
  }

  #pragma unroll
  for (int m = 0; m < 4; ++m) {
    const int gr0 = m0 + wm * 64 + m * 16 + colr;
    #pragma unroll
    for (int n = 0; n < 4; ++n) {
      const int gc = n0 + wn * 64 + n * 16 + colc;
      if (EPI == EP_STOREB_T) {
        bf16* Cp = (bf16*)Cb + zc * sC;
        bf16x4 pk = { (bf16)acc[m][n][0], (bf16)acc[m][n][1],
                      (bf16)acc[m][n][2], (bf16)acc[m][n][3] };
        *(bf16x4*)(Cp + (long)gc * ldc + gr0) = pk;
      } else {
        #pragma unroll
        for (int r = 0; r < 4; ++r) {
          const int  gr  = gr0 + r;
          const long off = (long)gr * ldc + gc;
          float v = acc[m][n][r];
          if (EPI == EP_STOREF) {
            ((float*)Cb + zc * sC)[off] = v;
          } else if (EPI == EP_SCALEMASK) {
            ((float*)Cb + zc * sC)[off] = (gc > gr) ? 0.0f : v * scale;
          } else if (EPI == EP_ADD) {
            float* Cf = (float*)Cb + zc * sC;
            Cf[off] = ((const float*)Cin)[off] + v;
          } else if (EPI == EP_STOREB) {
            ((bf16*)Cb + zc * sC)[off] = (bf16)v;
          } else { // EP_SILUMUL
            bf16* Cf = (bf16*)Cb + zc * sC;
            const float g = (float)((const bf16*)Cin)[off];
            Cf[off] = (bf16)((v / (1.0f + __expf(-v))) * g);
          }
        }
      }
    }
  }
}

// fp32 [K][N] -> bf16 [N][K] transpose+convert
__global__ __launch_bounds__(256)
void transpose_cvt(const float* __restrict__ in, bf16* __restrict__ out, int K, int N)
{
  __shared__ float t[32][33];
  const int n0 = (int)blockIdx.x * 32, k0 = (int)blockIdx.y * 32;
  const int tr = (int)threadIdx.x >> 3;
  const int tc = ((int)threadIdx.x & 7) * 4;
  f32x4 v = *(const f32x4*)(in + (long)(k0 + tr) * N + n0 + tc);
  t[tr][tc] = v[0]; t[tr][tc + 1] = v[1]; t[tr][tc + 2] = v[2]; t[tr][tc + 3] = v[3];
  __syncthreads();
  bf16x4 b = { (bf16)t[tc][tr], (bf16)t[tc + 1][tr], (bf16)t[tc + 2][tr], (bf16)t[tc + 3][tr] };
  *(bf16x4*)(out + (long)(n0 + tr) * K + k0 + tc) = b;
}

__global__ __launch_bounds__(256)
void cvt_bf16_kernel(const float* __restrict__ in, bf16* __restrict__ out, int nvec)
{
  const int i = (int)(blockIdx.x * 256 + threadIdx.x);
  if (i < nvec) {
    f32x4 v = ((const f32x4*)in)[i];
    bf16x4 b = { (bf16)v[0], (bf16)v[1], (bf16)v[2], (bf16)v[3] };
    ((bf16x4*)out)[i] = b;
  }
}

__global__ __launch_bounds__(256)
void rmsnorm_kernel(bf16* __restrict__ out, const float* __restrict__ in, const float* __restrict__ g)
{
  const int row = (int)blockIdx.x;
  const float* x = in + (long)row * DMODEL;
  bf16* o = out + (long)row * DMODEL;
  const int tid = (int)threadIdx.x;
  f32x4 v0 = *(const f32x4*)(x + tid * 4);
  f32x4 v1 = *(const f32x4*)(x + tid * 4 + 1024);
  float ss = v0[0]*v0[0] + v0[1]*v0[1] + v0[2]*v0[2] + v0[3]*v0[3]
           + v1[0]*v1[0] + v1[1]*v1[1] + v1[2]*v1[2] + v1[3]*v1[3];
  #pragma unroll
  for (int o_ = 32; o_; o_ >>= 1) ss += __shfl_xor(ss, o_);
  __shared__ float sm[4];
  if ((tid & 63) == 0) sm[tid >> 6] = ss;
  __syncthreads();
  ss = sm[0] + sm[1] + sm[2] + sm[3];
  const float r = 1.0f / sqrtf(ss * (1.0f / DMODEL) + EPSV);
  f32x4 g0 = *(const f32x4*)(g + tid * 4);
  f32x4 g1 = *(const f32x4*)(g + tid * 4 + 1024);
  bf16x4 o0, o1;
  #pragma unroll
  for (int j = 0; j < 4; ++j) { o0[j] = (bf16)(v0[j] * r * g0[j]); o1[j] = (bf16)(v1[j] * r * g1[j]); }
  *(bf16x4*)(o + tid * 4) = o0;
  *(bf16x4*)(o + tid * 4 + 1024) = o1;
}

// full-row softmax over fp32 scores; writes bf16 probs IN-PLACE
__global__ __launch_bounds__(256)
void softmax_kernel(float* base, float* alt, int zsplit)
{
  const int row = (int)blockIdx.x;
  const int z   = (int)blockIdx.y;
  const long SSL = (long)SQ * SQ;
  float* p = ((z < zsplit) ? (base + (long)z * SSL) : (alt + (long)(z - zsplit) * SSL))
             + (long)row * SQ;
  const int tid = (int)threadIdx.x;
  f32x4 v0 = *(f32x4*)(p + tid * 4);
  f32x4 v1 = *(f32x4*)(p + tid * 4 + 1024);
  float mx = fmaxf(fmaxf(fmaxf(v0[0], v0[1]), fmaxf(v0[2], v0[3])),
                   fmaxf(fmaxf(v1[0], v1[1]), fmaxf(v1[2], v1[3])));
  #pragma unroll
  for (int o = 32; o; o >>= 1) mx = fmaxf(mx, __shfl_xor(mx, o));
  __shared__ float sm[4], sv[4];
  if ((tid & 63) == 0) sm[tid >> 6] = mx;
  __syncthreads();
  mx = fmaxf(fmaxf(sm[0], sm[1]), fmaxf(sm[2], sm[3]));
  float s = 0.f;
  #pragma unroll
  for (int j = 0; j < 4; ++j) { v0[j] = __expf(v0[j] - mx); s += v0[j]; }
  #pragma unroll
  for (int j = 0; j < 4; ++j) { v1[j] = __expf(v1[j] - mx); s += v1[j]; }
  #pragma unroll
  for (int o = 32; o; o >>= 1) s += __shfl_xor(s, o);
  if ((tid & 63) == 0) sv[tid >> 6] = s;
  __syncthreads();
  s = sv[0] + sv[1] + sv[2] + sv[3];
  const float inv = 1.0f / s;
  bf16* ob = (bf16*)p;
  bf16x4 b0, b1;
  #pragma unroll
  for (int j = 0; j < 4; ++j) { b0[j] = (bf16)(v0[j] * inv); b1[j] = (bf16)(v1[j] * inv); }
  *(bf16x4*)(ob + tid * 4) = b0;
  *(bf16x4*)(ob + tid * 4 + 1024) = b1;
}

__global__ void rope_tables(float* cosT, float* sinT)
{
  const int s = (int)blockIdx.x;
  const int i = (int)threadIdx.x;   // 0..63
  const double inv = pow(10000.0, -(double)i / 64.0);
  const double f = (double)s * inv;
  cosT[s * 64 + i] = (float)cos(f);
  sinT[s * 64 + i] = (float)sin(f);
}

__global__ __launch_bounds__(256)
void rope_apply(bf16* buf, const float* cosT, const float* sinT, int nh, int stride)
{
  const int t = (int)(blockIdx.x * blockDim.x + threadIdx.x);
  const int per = nh * 64;
  const int s = t / per;
  const int r = t - s * per;
  const int h = r >> 6;
  const int i = r & 63;
  bf16* b = buf + (long)s * stride + h * HDIM;
  const float c  = cosT[s * 64 + i];
  const float sn = sinT[s * 64 + i];
  const float x1 = (float)b[i];
  const float x2 = (float)b[64 + i];
  b[i]      = (bf16)(x1 * c - x2 * sn);
  b[64 + i] = (bf16)(x2 * c + x1 * sn);
}

__global__ __launch_bounds__(256)
void embed_gather(f32x4* x, const f32x4* embed, const int* idx)
{
  const int t = (int)(blockIdx.x * 256 + threadIdx.x);
  const int s = t >> 9;
  const int c = t & 511;
  x[t] = embed[(long)idx[s] * 512 + c];
}

extern "C" void kernel_launch(void* const* d_in, const int* in_sizes, int n_in,
                              void* d_out, int out_size, void* d_ws, size_t ws_size,
                              hipStream_t stream)
{
  (void)in_sizes; (void)n_in; (void)out_size;
  const int*   idx   = (const int*)  d_in[0];
  const float* embed = (const float*)d_in[1];
  const float* wq    = (const float*)d_in[2];
  const float* wk    = (const float*)d_in[3];
  const float* wv    = (const float*)d_in[4];
  const float* wo    = (const float*)d_in[5];
  const float* ln1g  = (const float*)d_in[6];
  const float* ln2g  = (const float*)d_in[7];
  const float* wgate = (const float*)d_in[8];
  const float* wup   = (const float*)d_in[9];
  const float* wdown = (const float*)d_in[10];
  const float* fing  = (const float*)d_in[11];
  const float* lmh   = (const float*)d_in[12];
  float* out = (float*)d_out;

  char* wp = (char*)d_ws;
  auto alloc = [&](size_t bytes) { char* p = wp; wp += (bytes + 255) & ~(size_t)255; return p; };
  float* cosT = (float*)alloc((size_t)SQ * 64 * 4);
  float* sinT = (float*)alloc((size_t)SQ * 64 * 4);
  float* x    = (float*)alloc((size_t)SQ * DMODEL * 4);
  bf16*  h    = (bf16*) alloc((size_t)SQ * DMODEL * 2);
  bf16*  qb   = (bf16*) alloc((size_t)SQ * DMODEL * 2);
  bf16*  kb   = (bf16*) alloc((size_t)SQ * 512 * 2);
  bf16*  vT   = (bf16*) alloc((size_t)512 * SQ * 2);
  char*  fscr = alloc((size_t)SQ * FFDIM * 2);
  bf16*  ffb  = (bf16*) fscr;
  float* sc15 = (float*)fscr;
  size_t used  = (size_t)(wp - (char*)d_ws);
  bf16*  wbuf  = (bf16*)wp;
  size_t avail = ws_size - used;

  bf16* yb = qb;
  const long SSL = (long)SQ * SQ;
  const int  BIG = 1 << 30;
  const float scale = 0.08838834764831845f;

  rope_tables<<<SQ, 64, 0, stream>>>(cosT, sinT);
  embed_gather<<<(SQ * 512) / 256, 256, 0, stream>>>((f32x4*)x, (const f32x4*)embed, idx);

  for (int l = 0; l < NLAYER; ++l) {
    const float* lwq = wq    + (long)l * DMODEL * DMODEL;
    const float* lwk = wk    + (long)l * DMODEL * 512;
    const float* lwv = wv    + (long)l * DMODEL * 512;
    const float* lwo = wo    + (long)l * DMODEL * DMODEL;
    const float* lwg = wgate + (long)l * DMODEL * FFDIM;
    const float* lwu = wup   + (long)l * DMODEL * FFDIM;
    const float* lwd = wdown + (long)l * FFDIM * DMODEL;

    rmsnorm_kernel<<<SQ, 256, 0, stream>>>(h, x, ln1g + l * DMODEL);

    transpose_cvt<<<dim3(DMODEL / 32, DMODEL / 32), 256, 0, stream>>>(lwq, wbuf, DMODEL, DMODEL);
    gemm_bf16<EP_STOREB, 0><<<dim3(16, 16, 1), 256, 0, stream>>>(
        h, wbuf, qb, nullptr, nullptr, nullptr,
        DMODEL, DMODEL, DMODEL, DMODEL, 0, 0, 0, 0, BIG, BIG, 0.f);

    transpose_cvt<<<dim3(512 / 32, DMODEL / 32), 256, 0, stream>>>(lwk, wbuf, DMODEL, 512);
    gemm_bf16<EP_STOREB, 0><<<dim3(16, 4, 1), 256, 0, stream>>>(
        h, wbuf, kb, nullptr, nullptr, nullptr,
        DMODEL, DMODEL, DMODEL, 512, 0, 0, 0, 0, BIG, BIG, 0.f);

    transpose_cvt<<<dim3(512 / 32, DMODEL / 32), 256, 0, stream>>>(lwv, wbuf, DMODEL, 512);
    gemm_bf16<EP_STOREB_T, 0><<<dim3(16, 4, 1), 256, 0, stream>>>(
        h, wbuf, vT, nullptr, nullptr, nullptr,
        DMODEL, DMODEL, DMODEL, SQ, 0, 0, 0, 0, BIG, BIG, 0.f);

    rope_apply<<<(SQ * NHEAD * 64) / 256, 256, 0, stream>>>(qb, cosT, sinT, NHEAD, DMODEL);
    rope_apply<<<(SQ * NKV * 64) / 256, 256, 0, stream>>>(kb, cosT, sinT, NKV, 512);

    gemm_bf16<EP_SCALEMASK, 1><<<dim3(16, 16, NHEAD), 256, 0, stream>>>(
        qb, kb, out, nullptr, nullptr, sc15,
        HDIM, DMODEL, 512, SQ, 128, 128, SSL, 2, BIG, 15, scale);

    softmax_kernel<<<dim3(SQ, NHEAD), 256, 0, stream>>>(out, sc15, 15);

    gemm_bf16<EP_STOREB, 0><<<dim3(16, 1, NHEAD), 256, 0, stream>>>(
        (const bf16*)out, vT, yb, nullptr, (const bf16*)sc15, nullptr,
        SQ, 2 * SQ, SQ, DMODEL, 2L * SQ * SQ, (long)HDIM * SQ, HDIM, 2, 15, BIG, 0.f);

    transpose_cvt<<<dim3(DMODEL / 32, DMODEL / 32), 256, 0, stream>>>(lwo, wbuf, DMODEL, DMODEL);
    gemm_bf16<EP_ADD, 0><<<dim3(16, 16, 1), 256, 0, stream>>>(
        yb, wbuf, x, x, nullptr, nullptr,
        DMODEL, DMODEL, DMODEL, DMODEL, 0, 0, 0, 0, BIG, BIG, 0.f);

    rmsnorm_kernel<<<SQ, 256, 0, stream>>>(h, x, ln2g + l * DMODEL);

    // gate/up on the 256^2 8-phase kernel (grid 8 x 22)
    transpose_cvt<<<dim3(FFDIM / 32, DMODEL / 32), 256, 0, stream>>>(lwg, wbuf, DMODEL, FFDIM);
    gemm256<EP_STOREB><<<dim3(8, FFDIM / 256, 1), 512, 0, stream>>>(
        h, wbuf, ffb, nullptr, DMODEL, DMODEL, DMODEL, FFDIM);

    transpose_cvt<<<dim3(FFDIM / 32, DMODEL / 32), 256, 0, stream>>>(lwu, wbuf, DMODEL, FFDIM);
    gemm256<EP_SILUMUL><<<dim3(8, FFDIM / 256, 1), 512, 0, stream>>>(
        h, wbuf, ffb, ffb, DMODEL, DMODEL, DMODEL, FFDIM);

    transpose_cvt<<<dim3(DMODEL / 32, FFDIM / 32), 256, 0, stream>>>(lwd, wbuf, FFDIM, DMODEL);
    gemm_bf16<EP_ADD, 0><<<dim3(16, 16, 1), 256, 0, stream>>>(
        ffb, wbuf, x, x, nullptr, nullptr,
        FFDIM, FFDIM, FFDIM, DMODEL, 0, 0, 0, 0, BIG, BIG, 0.f);
  }

  rmsnorm_kernel<<<SQ, 256, 0, stream>>>(h, x, fing);

  // logits = h @ lm_head^T on the 256^2 kernel (grid 8 x rows/256)
  long chunkRows = (long)(avail / ((size_t)DMODEL * 2)) & ~255L;
  if (chunkRows > VOCAB) chunkRows = VOCAB;
  for (long c0 = 0; c0 < VOCAB; c0 += chunkRows) {
    const long rows = (VOCAB - c0 < chunkRows) ? (VOCAB - c0) : chunkRows;
    const int  nvec = (int)(rows * DMODEL / 4);
    cvt_bf16_kernel<<<(nvec + 255) / 256, 256, 0, stream>>>(lmh + c0 * DMODEL, wbuf, nvec);
    gemm256<EP_STOREF><<<dim3(8, (int)(rows / 256), 1), 512, 0, stream>>>(
        h, wbuf, out + c0, nullptr, DMODEL, DMODEL, DMODEL, VOCAB);
  }
}

// Round 4
// 1552.269 us; speedup vs baseline: 1.8608x; 1.0887x over previous
//
#include <hip/hip_runtime.h>

#define SQ     2048
#define DMODEL 2048
#define NHEAD  16
#define NKV    4
#define HDIM   128
#define FFDIM  5632
#define VOCAB  32000
#define NLAYER 2
#define EPSV   1e-5f

typedef __bf16 bf16;
typedef __bf16 bf16x4 __attribute__((ext_vector_type(4)));
typedef __bf16 bf16x8 __attribute__((ext_vector_type(8)));
typedef float  f32x4  __attribute__((ext_vector_type(4)));

enum { EP_STOREF = 0, EP_ADD = 2, EP_STOREB = 3, EP_STOREB_T = 4, EP_SILUMUL = 5 };

// global -> LDS direct DMA, 16B per lane; LDS dest = wave-uniform base + lane*16
#define GLD(gp, lp) __builtin_amdgcn_global_load_lds( \
    (const __attribute__((address_space(1))) void*)(gp), \
    (__attribute__((address_space(3))) void*)(lp), 16, 0, 0)

#define MFMA16(a, b, c) __builtin_amdgcn_mfma_f32_16x16x32_bf16(a, b, c, 0, 0, 0)

#define FENCE() __builtin_amdgcn_sched_barrier(0)
#define PH_BAR() do { FENCE(); __builtin_amdgcn_s_barrier(); FENCE(); } while (0)

// ============================================================================
// Fused flash-style attention with mask-before-softmax semantics.
// Reference: P = softmax(scores*scale*tril) where masked scores are EXACTLY 0.
// Fixed-shift (M=0) closed form:
//   y_q = (sum_{k<=q} e^{s_qk} V_k + T_q) / (sum_{k<=q} e^{s_qk} + (S-1-q))
// with T_q = suffix sums of V. Fully-masked 128-chunks folded into precomputed
// chunk sums (suffPc); diagonal-tile masked entries get P=1.0 inside the MFMA.
// Grid: (16 qtiles, 16 heads), 256 thr. Wave w owns q-rows qt*128+w*32..+31.
// ============================================================================
__global__ __launch_bounds__(256, 1)
void flash_attn(const bf16* __restrict__ qb, const bf16* __restrict__ kb,
                const bf16* __restrict__ vT, const float* __restrict__ suffPc,
                bf16* __restrict__ yb, float scale)
{
  __shared__ bf16 Ks[128 * 128];   // [kv][d], xor-swizzled 16B slots
  __shared__ bf16 Vs[128 * 128];   // [d][kv], xor-swizzled
  __shared__ bf16 Ps[128 * 136];   // [q][kv], +8 pad

  const int tid  = (int)threadIdx.x;
  const int lane = tid & 63;
  const int w    = tid >> 6;            // 0..3
  const int qt   = (int)blockIdx.x;
  const int h    = (int)blockIdx.y;
  const int kvh  = h >> 2;

  const int l15 = lane & 15;
  const int g4  = lane >> 4;            // 0..3

  // ---- Q fragments to registers: rows qt*128 + w*32 + m*16 + l15
  bf16x8 qf[2][4];
  #pragma unroll
  for (int m = 0; m < 2; ++m)
    #pragma unroll
    for (int ks = 0; ks < 4; ++ks)
      qf[m][ks] = *(const bf16x8*)(qb + (long)(qt * 128 + w * 32 + m * 16 + l15) * DMODEL
                                   + h * HDIM + ks * 32 + g4 * 8);

  f32x4 acc_o[2][8] = {};
  float den[2][4] = {};

  const bf16* Kg = kb + (long)kvh * HDIM;           // row stride 512
  const bf16* Vg = vT + (long)(kvh * HDIM) * SQ;    // row stride 2048

  for (int j = 0; j <= qt; ++j) {
    const bool diag = (j == qt);
    PH_BAR();                                        // prev PV reads done

    // ---- stage K tile [128 kv][128 d] and V^T tile [128 d][128 kv]
    #pragma unroll
    for (int i = 0; i < 8; ++i) {
      const int rb = w * 32 + i * 4;
      const int r  = rb + g4;
      GLD(Kg + (long)(j * 128 + r) * 512 + ((l15 ^ (r & 7)) * 8), Ks + rb * 128);
    }
    #pragma unroll
    for (int i = 0; i < 8; ++i) {
      const int rb = w * 32 + i * 4;
      const int r  = rb + g4;
      GLD(Vg + (long)r * SQ + j * 128 + ((l15 ^ (r & 7)) * 8), Vs + rb * 128);
    }
    asm volatile("s_waitcnt vmcnt(8)" ::: "memory");  // this wave's K landed
    PH_BAR();                                         // all waves' K landed (V in flight)

    // ---- QK^T: acc_s[m][n] over K=128
    f32x4 acc_s[2][8] = {};
    #pragma unroll
    for (int ks = 0; ks < 4; ++ks) {
      bf16x8 kf[8];
      #pragma unroll
      for (int n = 0; n < 8; ++n) {
        const int kr = n * 16 + l15;
        kf[n] = *(const bf16x8*)((const char*)Ks + kr * 256 + (((ks * 4 + g4) ^ (kr & 7)) * 16));
      }
      #pragma unroll
      for (int m = 0; m < 2; ++m)
        #pragma unroll
        for (int n = 0; n < 8; ++n)
          acc_s[m][n] = MFMA16(qf[m][ks], kf[n], acc_s[m][n]);
    }

    // ---- P = e^{s*scale} (masked -> 1.0 on diagonal tile); write Ps; den rowsums
    float rs[2][4] = {};
    #pragma unroll
    for (int m = 0; m < 2; ++m)
      #pragma unroll
      for (int n = 0; n < 8; ++n) {
        const int kc = n * 16 + l15;
        #pragma unroll
        for (int r = 0; r < 4; ++r) {
          const int qlr = w * 32 + m * 16 + g4 * 4 + r;
          float p = __expf(acc_s[m][n][r] * scale);
          if (diag && kc > qlr) p = 1.0f;
          rs[m][r] += p;
          Ps[(w * 32 + m * 16 + g4 * 4 + r) * 136 + kc] = (bf16)p;
        }
      }
    #pragma unroll
    for (int m = 0; m < 2; ++m)
      #pragma unroll
      for (int r = 0; r < 4; ++r) {
        float v = rs[m][r];
        v += __shfl_xor(v, 1); v += __shfl_xor(v, 2);
        v += __shfl_xor(v, 4); v += __shfl_xor(v, 8);
        den[m][r] += v;
      }

    asm volatile("s_waitcnt vmcnt(0) lgkmcnt(0)" ::: "memory");  // V + Ps visible
    PH_BAR();

    // ---- PV: acc_o[m][n] += P[m] * V^T[n] over K=128 kv
    #pragma unroll
    for (int ks = 0; ks < 4; ++ks) {
      bf16x8 pa[2], vf[8];
      #pragma unroll
      for (int m = 0; m < 2; ++m)
        pa[m] = *(const bf16x8*)((const char*)Ps + (w * 32 + m * 16 + l15) * 272
                                 + ks * 64 + g4 * 16);
      #pragma unroll
      for (int n = 0; n < 8; ++n) {
        const int dr = n * 16 + l15;
        vf[n] = *(const bf16x8*)((const char*)Vs + dr * 256 + (((ks * 4 + g4) ^ (dr & 7)) * 16));
      }
      #pragma unroll
      for (int m = 0; m < 2; ++m)
        #pragma unroll
        for (int n = 0; n < 8; ++n)
          acc_o[m][n] = MFMA16(pa[m], vf[n], acc_o[m][n]);
    }
  }

  // ---- epilogue: add masked-tail, divide, store
  float denf[2][4];
  #pragma unroll
  for (int m = 0; m < 2; ++m)
    #pragma unroll
    for (int r = 0; r < 4; ++r)
      denf[m][r] = den[m][r] + 128.0f * (15 - qt);

  #pragma unroll
  for (int n = 0; n < 8; ++n) {
    const float t = suffPc[((kvh << 4) + qt) * 128 + n * 16 + l15];
    #pragma unroll
    for (int m = 0; m < 2; ++m)
      #pragma unroll
      for (int r = 0; r < 4; ++r) {
        const float y = (acc_o[m][n][r] + t) / denf[m][r];
        yb[(long)(qt * 128 + w * 32 + m * 16 + g4 * 4 + r) * DMODEL
           + h * HDIM + n * 16 + l15] = (bf16)y;
      }
  }
}

// per (kvh): suffPc[kvh][c][d] = sum over chunks c' > c of column-sums of V
__global__ __launch_bounds__(128)
void vsuffix(const bf16* __restrict__ vT, float* __restrict__ suffPc)
{
  const int kvh = (int)blockIdx.x;
  const int d   = (int)threadIdx.x;
  const bf16* row = vT + (long)(kvh * HDIM + d) * SQ;
  float a = 0.f;
  for (int c = 15; c >= 0; --c) {
    suffPc[(kvh * 16 + c) * 128 + d] = a;
    float s = 0.f;
    #pragma unroll
    for (int r = 0; r < 16; ++r) {
      bf16x8 v = *(const bf16x8*)(row + c * 128 + r * 8);
      #pragma unroll
      for (int e = 0; e < 8; ++e) s += (float)v[e];
    }
    a += s;
  }
}

// ============================================================================
// 256x256-tile, BK=64, 8-wave, 4-phase/K-tile pipelined GEMM (T2+T3+T4+T5).
// ============================================================================
template<int EPI>
__global__ __launch_bounds__(512, 2)
void gemm256(const bf16* __restrict__ A, const bf16* __restrict__ B,
             void* __restrict__ C, const void* __restrict__ Cin,
             int K, int lda, int ldb, int ldc)
{
  __shared__ bf16 smem[2][4][128 * 64];   // 128 KiB

  const int tid  = (int)threadIdx.x;
  const int lane = tid & 63;
  const int wave = tid >> 6;
  const int wm   = wave >> 2;
  const int wn   = wave & 3;

  const int GM  = (int)gridDim.x;
  const int nwg = GM * (int)gridDim.y;
  const int bid = (int)blockIdx.y * GM + (int)blockIdx.x;
  const int q8  = nwg >> 3, r8 = nwg & 7;
  const int xcd = bid & 7, rnk = bid >> 3;
  const int swz = ((xcd < r8) ? xcd * (q8 + 1) : r8 * (q8 + 1) + (xcd - r8) * q8) + rnk;
  const int m0  = (swz % GM) * 256;
  const int n0  = (swz / GM) * 256;

  const int nkt  = K >> 6;
  const int srow = lane >> 3;
  const long sxcol = (long)(((lane & 7) ^ (lane >> 3)) * 8);
  const int frow = lane & 15;
  const int ph0  = ((     (lane >> 4)) ^ (lane & 7)) * 16;
  const int ph1  = ((4 + (lane >> 4)) ^ (lane & 7)) * 16;

  auto stageA = [&](int tile, int half) {
    if (tile < nkt) {
      const long kc = (long)tile * 64 + sxcol;
      #pragma unroll
      for (int i = 0; i < 2; ++i)
        GLD(A + (long)(m0 + half * 128 + wave * 16 + i * 8 + srow) * lda + kc,
            smem[tile & 1][half] + (wave * 16 + i * 8) * 64);
    }
  };
  auto stageB = [&](int tile, int half) {
    if (tile < nkt) {
      const long kc = (long)tile * 64 + sxcol;
      #pragma unroll
      for (int i = 0; i < 2; ++i)
        GLD(B + (long)(n0 + half * 128 + wave * 16 + i * 8 + srow) * ldb + kc,
            smem[tile & 1][2 + half] + (wave * 16 + i * 8) * 64);
    }
  };

  stageB(0, 0); stageB(0, 1); stageA(0, 0); stageA(0, 1);
  asm volatile("s_waitcnt vmcnt(4)" ::: "memory");
  stageB(1, 0); stageB(1, 1); stageA(1, 0);
  asm volatile("s_waitcnt vmcnt(6)" ::: "memory");
  PH_BAR();

  f32x4 acc[8][4] = {};

  for (int t = 0; t < nkt; ++t) {
    const int bsel = t & 1;
    const char* Asl = (const char*)smem[bsel][wm];
    const char* Bsl = (const char*)smem[bsel][2 + (wn >> 1)];
    const int brow = (wn & 1) * 64;

    bf16x8 ar[4][2], b0f[2][2], b1f[2][2];

    #pragma unroll
    for (int mr = 0; mr < 4; ++mr) {
      ar[mr][0] = *(const bf16x8*)(Asl + (mr * 16 + frow) * 128 + ph0);
      ar[mr][1] = *(const bf16x8*)(Asl + (mr * 16 + frow) * 128 + ph1);
    }
    #pragma unroll
    for (int nc = 0; nc < 2; ++nc) {
      b0f[nc][0] = *(const bf16x8*)(Bsl + (brow + nc * 16 + frow) * 128 + ph0);
      b0f[nc][1] = *(const bf16x8*)(Bsl + (brow + nc * 16 + frow) * 128 + ph1);
    }
    stageA(t + 1, 1);
    PH_BAR();
    __builtin_amdgcn_s_setprio(1);
    #pragma unroll
    for (int mr = 0; mr < 4; ++mr)
      #pragma unroll
      for (int nc = 0; nc < 2; ++nc) {
        acc[mr][nc] = MFMA16(ar[mr][0], b0f[nc][0], acc[mr][nc]);
        acc[mr][nc] = MFMA16(ar[mr][1], b0f[nc][1], acc[mr][nc]);
      }
    __builtin_amdgcn_s_setprio(0);
    PH_BAR();

    #pragma unroll
    for (int nc = 0; nc < 2; ++nc) {
      b1f[nc][0] = *(const bf16x8*)(Bsl + (brow + (2 + nc) * 16 + frow) * 128 + ph0);
      b1f[nc][1] = *(const bf16x8*)(Bsl + (brow + (2 + nc) * 16 + frow) * 128 + ph1);
    }
    PH_BAR();
    __builtin_amdgcn_s_setprio(1);
    #pragma unroll
    for (int mr = 0; mr < 4; ++mr)
      #pragma unroll
      for (int nc = 0; nc < 2; ++nc) {
        acc[mr][2 + nc] = MFMA16(ar[mr][0], b1f[nc][0], acc[mr][2 + nc]);
        acc[mr][2 + nc] = MFMA16(ar[mr][1], b1f[nc][1], acc[mr][2 + nc]);
      }
    __builtin_amdgcn_s_setprio(0);
    PH_BAR();

    #pragma unroll
    for (int mr = 0; mr < 4; ++mr) {
      ar[mr][0] = *(const bf16x8*)(Asl + ((4 + mr) * 16 + frow) * 128 + ph0);
      ar[mr][1] = *(const bf16x8*)(Asl + ((4 + mr) * 16 + frow) * 128 + ph1);
    }
    stageB(t + 2, 0); stageB(t + 2, 1);
    PH_BAR();
    __builtin_amdgcn_s_setprio(1);
    #pragma unroll
    for (int mr = 0; mr < 4; ++mr)
      #pragma unroll
      for (int nc = 0; nc < 2; ++nc) {
        acc[4 + mr][nc] = MFMA16(ar[mr][0], b0f[nc][0], acc[4 + mr][nc]);
        acc[4 + mr][nc] = MFMA16(ar[mr][1], b0f[nc][1], acc[4 + mr][nc]);
      }
    __builtin_amdgcn_s_setprio(0);
    PH_BAR();

    stageA(t + 2, 0);
    PH_BAR();
    __builtin_amdgcn_s_setprio(1);
    #pragma unroll
    for (int mr = 0; mr < 4; ++mr)
      #pragma unroll
      for (int nc = 0; nc < 2; ++nc) {
        acc[4 + mr][2 + nc] = MFMA16(ar[mr][0], b1f[nc][0], acc[4 + mr][2 + nc]);
        acc[4 + mr][2 + nc] = MFMA16(ar[mr][1], b1f[nc][1], acc[4 + mr][2 + nc]);
      }
    __builtin_amdgcn_s_setprio(0);
    FENCE();
    if (t + 2 < nkt) asm volatile("s_waitcnt vmcnt(6)" ::: "memory");
    else             asm volatile("s_waitcnt vmcnt(0)" ::: "memory");
    PH_BAR();
  }

  #pragma unroll
  for (int mr = 0; mr < 8; ++mr) {
    const int gr0 = m0 + wm * 128 + mr * 16 + (lane >> 4) * 4;
    #pragma unroll
    for (int nc = 0; nc < 4; ++nc) {
      const int gc = n0 + wn * 64 + nc * 16 + (lane & 15);
      #pragma unroll
      for (int r = 0; r < 4; ++r) {
        const long off = (long)(gr0 + r) * ldc + gc;
        const float v = acc[mr][nc][r];
        if (EPI == EP_STOREF) {
          ((float*)C)[off] = v;
        } else if (EPI == EP_STOREB) {
          ((bf16*)C)[off] = (bf16)v;
        } else if (EPI == EP_SILUMUL) {
          const float g = (float)((const bf16*)Cin)[off];
          ((bf16*)C)[off] = (bf16)((v / (1.0f + __expf(-v))) * g);
        }
      }
    }
  }
}

// ============================================================================
// 128x128-tile m97-structure GEMM (small/odd-shaped GEMMs)
// ============================================================================
#define BM 128
#define BN 128
#define BK 64

template<int EPI>
__global__ __launch_bounds__(256, 2)
void gemm_bf16(const bf16* __restrict__ A, const bf16* __restrict__ B,
               void* __restrict__ C, const void* __restrict__ Cin,
               int K, int lda, int ldb, int ldc)
{
  __shared__ bf16 As[BM * BK];
  __shared__ bf16 Bs[BN * BK];

  const int tid  = (int)threadIdx.x;
  const int lane = tid & 63;
  const int wave = tid >> 6;
  const int wm   = wave >> 1, wn = wave & 1;

  const int GM  = (int)gridDim.x;
  const int nwg = GM * (int)gridDim.y;
  const int bid = (int)blockIdx.y * GM + (int)blockIdx.x;
  const int q8  = nwg >> 3, r8 = nwg & 7;
  const int xcd = bid & 7, rnk = bid >> 3;
  const int swz = ((xcd < r8) ? xcd * (q8 + 1) : r8 * (q8 + 1) + (xcd - r8) * q8) + rnk;
  const int m0  = (swz % GM) * BM;
  const int n0  = (swz / GM) * BN;

  const int colr = (lane >> 4) * 4;
  const int colc = lane & 15;
  const int srow = lane >> 3;
  const int scol = (lane & 7) * 8;

  f32x4 acc[4][4] = {};

  for (int kt = 0; kt < K; kt += BK) {
    #pragma unroll
    for (int c = 0; c < 4; ++c) {
      const int chunk = wave * 4 + c;
      const int row   = chunk * 8 + srow;
      GLD(A + (long)(m0 + row) * lda + kt + scol, As + chunk * 512);
      GLD(B + (long)(n0 + row) * ldb + kt + scol, Bs + chunk * 512);
    }
    __syncthreads();
    #pragma unroll
    for (int kk = 0; kk < 2; ++kk) {
      const int ko = kk * 32 + (lane >> 4) * 8;
      bf16x8 af[4], bv[4];
      #pragma unroll
      for (int m = 0; m < 4; ++m)
        af[m] = *(const bf16x8*)(As + (wm * 64 + m * 16 + colc) * BK + ko);
      #pragma unroll
      for (int n = 0; n < 4; ++n)
        bv[n] = *(const bf16x8*)(Bs + (wn * 64 + n * 16 + colc) * BK + ko);
      #pragma unroll
      for (int m = 0; m < 4; ++m)
        #pragma unroll
        for (int n = 0; n < 4; ++n)
          acc[m][n] = MFMA16(af[m], bv[n], acc[m][n]);
    }
    __syncthreads();
  }

  #pragma unroll
  for (int m = 0; m < 4; ++m) {
    const int gr0 = m0 + wm * 64 + m * 16 + colr;
    #pragma unroll
    for (int n = 0; n < 4; ++n) {
      const int gc = n0 + wn * 64 + n * 16 + colc;
      if (EPI == EP_STOREB_T) {
        bf16x4 pk = { (bf16)acc[m][n][0], (bf16)acc[m][n][1],
                      (bf16)acc[m][n][2], (bf16)acc[m][n][3] };
        *(bf16x4*)((bf16*)C + (long)gc * ldc + gr0) = pk;
      } else {
        #pragma unroll
        for (int r = 0; r < 4; ++r) {
          const int  gr  = gr0 + r;
          const long off = (long)gr * ldc + gc;
          float v = acc[m][n][r];
          if (EPI == EP_STOREF) {
            ((float*)C)[off] = v;
          } else if (EPI == EP_ADD) {
            ((float*)C)[off] = ((const float*)Cin)[off] + v;
          } else if (EPI == EP_STOREB) {
            ((bf16*)C)[off] = (bf16)v;
          } else if (EPI == EP_SILUMUL) {
            const float g = (float)((const bf16*)Cin)[off];
            ((bf16*)C)[off] = (bf16)((v / (1.0f + __expf(-v))) * g);
          }
        }
      }
    }
  }
}

// fp32 [K][N] -> bf16 [N][K] transpose+convert
__global__ __launch_bounds__(256)
void transpose_cvt(const float* __restrict__ in, bf16* __restrict__ out, int K, int N)
{
  __shared__ float t[32][33];
  const int n0 = (int)blockIdx.x * 32, k0 = (int)blockIdx.y * 32;
  const int tr = (int)threadIdx.x >> 3;
  const int tc = ((int)threadIdx.x & 7) * 4;
  f32x4 v = *(const f32x4*)(in + (long)(k0 + tr) * N + n0 + tc);
  t[tr][tc] = v[0]; t[tr][tc + 1] = v[1]; t[tr][tc + 2] = v[2]; t[tr][tc + 3] = v[3];
  __syncthreads();
  bf16x4 b = { (bf16)t[tc][tr], (bf16)t[tc + 1][tr], (bf16)t[tc + 2][tr], (bf16)t[tc + 3][tr] };
  *(bf16x4*)(out + (long)(n0 + tr) * K + k0 + tc) = b;
}

__global__ __launch_bounds__(256)
void cvt_bf16_kernel(const float* __restrict__ in, bf16* __restrict__ out, int nvec)
{
  const int i = (int)(blockIdx.x * 256 + threadIdx.x);
  if (i < nvec) {
    f32x4 v = ((const f32x4*)in)[i];
    bf16x4 b = { (bf16)v[0], (bf16)v[1], (bf16)v[2], (bf16)v[3] };
    ((bf16x4*)out)[i] = b;
  }
}

__global__ __launch_bounds__(256)
void rmsnorm_kernel(bf16* __restrict__ out, const float* __restrict__ in, const float* __restrict__ g)
{
  const int row = (int)blockIdx.x;
  const float* x = in + (long)row * DMODEL;
  bf16* o = out + (long)row * DMODEL;
  const int tid = (int)threadIdx.x;
  f32x4 v0 = *(const f32x4*)(x + tid * 4);
  f32x4 v1 = *(const f32x4*)(x + tid * 4 + 1024);
  float ss = v0[0]*v0[0] + v0[1]*v0[1] + v0[2]*v0[2] + v0[3]*v0[3]
           + v1[0]*v1[0] + v1[1]*v1[1] + v1[2]*v1[2] + v1[3]*v1[3];
  #pragma unroll
  for (int o_ = 32; o_; o_ >>= 1) ss += __shfl_xor(ss, o_);
  __shared__ float sm[4];
  if ((tid & 63) == 0) sm[tid >> 6] = ss;
  __syncthreads();
  ss = sm[0] + sm[1] + sm[2] + sm[3];
  const float r = 1.0f / sqrtf(ss * (1.0f / DMODEL) + EPSV);
  f32x4 g0 = *(const f32x4*)(g + tid * 4);
  f32x4 g1 = *(const f32x4*)(g + tid * 4 + 1024);
  bf16x4 o0, o1;
  #pragma unroll
  for (int j = 0; j < 4; ++j) { o0[j] = (bf16)(v0[j] * r * g0[j]); o1[j] = (bf16)(v1[j] * r * g1[j]); }
  *(bf16x4*)(o + tid * 4) = o0;
  *(bf16x4*)(o + tid * 4 + 1024) = o1;
}

__global__ void rope_tables(float* cosT, float* sinT)
{
  const int s = (int)blockIdx.x;
  const int i = (int)threadIdx.x;
  const double inv = pow(10000.0, -(double)i / 64.0);
  const double f = (double)s * inv;
  cosT[s * 64 + i] = (float)cos(f);
  sinT[s * 64 + i] = (float)sin(f);
}

__global__ __launch_bounds__(256)
void rope_apply(bf16* buf, const float* cosT, const float* sinT, int nh, int stride)
{
  const int t = (int)(blockIdx.x * blockDim.x + threadIdx.x);
  const int per = nh * 64;
  const int s = t / per;
  const int r = t - s * per;
  const int h = r >> 6;
  const int i = r & 63;
  bf16* b = buf + (long)s * stride + h * HDIM;
  const float c  = cosT[s * 64 + i];
  const float sn = sinT[s * 64 + i];
  const float x1 = (float)b[i];
  const float x2 = (float)b[64 + i];
  b[i]      = (bf16)(x1 * c - x2 * sn);
  b[64 + i] = (bf16)(x2 * c + x1 * sn);
}

__global__ __launch_bounds__(256)
void embed_gather(f32x4* x, const f32x4* embed, const int* idx)
{
  const int t = (int)(blockIdx.x * 256 + threadIdx.x);
  const int s = t >> 9;
  const int c = t & 511;
  x[t] = embed[(long)idx[s] * 512 + c];
}

extern "C" void kernel_launch(void* const* d_in, const int* in_sizes, int n_in,
                              void* d_out, int out_size, void* d_ws, size_t ws_size,
                              hipStream_t stream)
{
  (void)in_sizes; (void)n_in; (void)out_size;
  const int*   idx   = (const int*)  d_in[0];
  const float* embed = (const float*)d_in[1];
  const float* wq    = (const float*)d_in[2];
  const float* wk    = (const float*)d_in[3];
  const float* wv    = (const float*)d_in[4];
  const float* wo    = (const float*)d_in[5];
  const float* ln1g  = (const float*)d_in[6];
  const float* ln2g  = (const float*)d_in[7];
  const float* wgate = (const float*)d_in[8];
  const float* wup   = (const float*)d_in[9];
  const float* wdown = (const float*)d_in[10];
  const float* fing  = (const float*)d_in[11];
  const float* lmh   = (const float*)d_in[12];
  float* out = (float*)d_out;

  char* wp = (char*)d_ws;
  auto alloc = [&](size_t bytes) { char* p = wp; wp += (bytes + 255) & ~(size_t)255; return p; };
  float* cosT   = (float*)alloc((size_t)SQ * 64 * 4);
  float* sinT   = (float*)alloc((size_t)SQ * 64 * 4);
  float* suffPc = (float*)alloc((size_t)NKV * 16 * 128 * 4);
  float* x      = (float*)alloc((size_t)SQ * DMODEL * 4);
  bf16*  h      = (bf16*) alloc((size_t)SQ * DMODEL * 2);
  bf16*  qb     = (bf16*) alloc((size_t)SQ * DMODEL * 2);
  bf16*  kb     = (bf16*) alloc((size_t)SQ * 512 * 2);
  bf16*  vT     = (bf16*) alloc((size_t)512 * SQ * 2);
  bf16*  ffb    = (bf16*) alloc((size_t)SQ * FFDIM * 2);
  size_t used  = (size_t)(wp - (char*)d_ws);
  bf16*  wbuf  = (bf16*)wp;
  size_t avail = ws_size - used;

  bf16* yb = qb;   // flash writes y into the q slot it just consumed (same rows/cols per block)
  const float scale = 0.08838834764831845f;

  rope_tables<<<SQ, 64, 0, stream>>>(cosT, sinT);
  embed_gather<<<(SQ * 512) / 256, 256, 0, stream>>>((f32x4*)x, (const f32x4*)embed, idx);

  for (int l = 0; l < NLAYER; ++l) {
    const float* lwq = wq    + (long)l * DMODEL * DMODEL;
    const float* lwk = wk    + (long)l * DMODEL * 512;
    const float* lwv = wv    + (long)l * DMODEL * 512;
    const float* lwo = wo    + (long)l * DMODEL * DMODEL;
    const float* lwg = wgate + (long)l * DMODEL * FFDIM;
    const float* lwu = wup   + (long)l * DMODEL * FFDIM;
    const float* lwd = wdown + (long)l * FFDIM * DMODEL;

    rmsnorm_kernel<<<SQ, 256, 0, stream>>>(h, x, ln1g + l * DMODEL);

    transpose_cvt<<<dim3(DMODEL / 32, DMODEL / 32), 256, 0, stream>>>(lwq, wbuf, DMODEL, DMODEL);
    gemm_bf16<EP_STOREB><<<dim3(16, 16, 1), 256, 0, stream>>>(
        h, wbuf, qb, nullptr, DMODEL, DMODEL, DMODEL, DMODEL);

    transpose_cvt<<<dim3(512 / 32, DMODEL / 32), 256, 0, stream>>>(lwk, wbuf, DMODEL, 512);
    gemm_bf16<EP_STOREB><<<dim3(16, 4, 1), 256, 0, stream>>>(
        h, wbuf, kb, nullptr, DMODEL, DMODEL, DMODEL, 512);

    transpose_cvt<<<dim3(512 / 32, DMODEL / 32), 256, 0, stream>>>(lwv, wbuf, DMODEL, 512);
    gemm_bf16<EP_STOREB_T><<<dim3(16, 4, 1), 256, 0, stream>>>(
        h, wbuf, vT, nullptr, DMODEL, DMODEL, DMODEL, SQ);

    vsuffix<<<NKV, 128, 0, stream>>>(vT, suffPc);
    rope_apply<<<(SQ * NHEAD * 64) / 256, 256, 0, stream>>>(qb, cosT, sinT, NHEAD, DMODEL);
    rope_apply<<<(SQ * NKV * 64) / 256, 256, 0, stream>>>(kb, cosT, sinT, NKV, 512);

    flash_attn<<<dim3(16, NHEAD), 256, 0, stream>>>(qb, kb, vT, suffPc, yb, scale);

    transpose_cvt<<<dim3(DMODEL / 32, DMODEL / 32), 256, 0, stream>>>(lwo, wbuf, DMODEL, DMODEL);
    gemm_bf16<EP_ADD><<<dim3(16, 16, 1), 256, 0, stream>>>(
        yb, wbuf, x, x, DMODEL, DMODEL, DMODEL, DMODEL);

    rmsnorm_kernel<<<SQ, 256, 0, stream>>>(h, x, ln2g + l * DMODEL);

    transpose_cvt<<<dim3(FFDIM / 32, DMODEL / 32), 256, 0, stream>>>(lwg, wbuf, DMODEL, FFDIM);
    gemm256<EP_STOREB><<<dim3(8, FFDIM / 256, 1), 512, 0, stream>>>(
        h, wbuf, ffb, nullptr, DMODEL, DMODEL, DMODEL, FFDIM);

    transpose_cvt<<<dim3(FFDIM / 32, DMODEL / 32), 256, 0, stream>>>(lwu, wbuf, DMODEL, FFDIM);
    gemm256<EP_SILUMUL><<<dim3(8, FFDIM / 256, 1), 512, 0, stream>>>(
        h, wbuf, ffb, ffb, DMODEL, DMODEL, DMODEL, FFDIM);

    transpose_cvt<<<dim3(DMODEL / 32, FFDIM / 32), 256, 0, stream>>>(lwd, wbuf, FFDIM, DMODEL);
    gemm_bf16<EP_ADD><<<dim3(16, 16, 1), 256, 0, stream>>>(
        ffb, wbuf, x, x, FFDIM, FFDIM, FFDIM, DMODEL);
  }

  rmsnorm_kernel<<<SQ, 256, 0, stream>>>(h, x, fing);

  long chunkRows = (long)(avail / ((size_t)DMODEL * 2)) & ~255L;
  if (chunkRows > VOCAB) chunkRows = VOCAB;
  for (long c0 = 0; c0 < VOCAB; c0 += chunkRows) {
    const long rows = (VOCAB - c0 < chunkRows) ? (VOCAB - c0) : chunkRows;
    const int  nvec = (int)(rows * DMODEL / 4);
    cvt_bf16_kernel<<<(nvec + 255) / 256, 256, 0, stream>>>(lmh + c0 * DMODEL, wbuf, nvec);
    gemm256<EP_STOREF><<<dim3(8, (int)(rows / 256), 1), 512, 0, stream>>>(
        h, wbuf, out + c0, nullptr, DMODEL, DMODEL, DMODEL, VOCAB);
  }
}

// Round 5
// 1333.971 us; speedup vs baseline: 2.1653x; 1.1636x over previous
//
#include <hip/hip_runtime.h>

#define SQ     2048
#define DMODEL 2048
#define NHEAD  16
#define NKV    4
#define HDIM   128
#define FFDIM  5632
#define VOCAB  32000
#define NLAYER 2
#define EPSV   1e-5f

typedef __bf16 bf16;
typedef __bf16 bf16x4 __attribute__((ext_vector_type(4)));
typedef __bf16 bf16x8 __attribute__((ext_vector_type(8)));
typedef float  f32x4  __attribute__((ext_vector_type(4)));

enum { EP_STOREF = 0, EP_ADD = 2, EP_STOREB = 3, EP_QKV = 6 };

// global -> LDS direct DMA, 16B per lane; LDS dest = wave-uniform base + lane*16
#define GLD(gp, lp) __builtin_amdgcn_global_load_lds( \
    (const __attribute__((address_space(1))) void*)(gp), \
    (__attribute__((address_space(3))) void*)(lp), 16, 0, 0)

#define MFMA16(a, b, c) __builtin_amdgcn_mfma_f32_16x16x32_bf16(a, b, c, 0, 0, 0)

#define FENCE() __builtin_amdgcn_sched_barrier(0)
#define PH_BAR() do { FENCE(); __builtin_amdgcn_s_barrier(); FENCE(); } while (0)

// XCD-bijective swizzle + m-fastest decode (m204)
#define XCD_SWZ(TM)                                                        \
  const int GM  = (int)gridDim.x;                                          \
  const int nwg = GM * (int)gridDim.y;                                     \
  const int bid = (int)blockIdx.y * GM + (int)blockIdx.x;                  \
  const int q8  = nwg >> 3, r8 = nwg & 7;                                  \
  const int xcd = bid & 7, rnk = bid >> 3;                                 \
  const int swz = ((xcd < r8) ? xcd * (q8 + 1)                             \
                              : r8 * (q8 + 1) + (xcd - r8) * q8) + rnk;    \
  const int m0  = (swz % GM) * (TM);                                       \
  const int n0  = (swz / GM) * (TM == 256 ? 256 : 128);

// ============================================================================
// 128x128-tile, BK=64, 4-wave, prefetching 2-phase GEMM (double-buffered,
// counted vmcnt(8), both-sides XOR swizzle).  A: MxK bf16 rm.  B: NxK bf16 rm.
// EP_QKV splits output columns: [0,2048)->C(qb), [2048,2560)->C2(kb),
// [2560,3072)->C3(vT, transposed store).
// ============================================================================
template<int EPI>
__global__ __launch_bounds__(256, 2)
void gemm128(const bf16* __restrict__ A, const bf16* __restrict__ B,
             void* __restrict__ C, const void* __restrict__ Cin,
             bf16* __restrict__ C2, bf16* __restrict__ C3,
             int K, int lda, int ldb, int ldc)
{
  __shared__ bf16 As[2][128 * 64];
  __shared__ bf16 Bs[2][128 * 64];

  const int tid  = (int)threadIdx.x;
  const int lane = tid & 63;
  const int wave = tid >> 6;
  const int wm   = wave >> 1, wn = wave & 1;

  XCD_SWZ(128)

  const int nkt  = K >> 6;
  const int srow = lane >> 3;
  const long sxcol = (long)(((lane & 7) ^ (lane >> 3)) * 8);
  const int colc = lane & 15;
  const int g4   = lane >> 4;

  auto stage = [&](int t) {
    if (t < nkt) {
      const long kc = (long)t * 64 + sxcol;
      bf16* dA = As[t & 1];
      bf16* dB = Bs[t & 1];
      #pragma unroll
      for (int c = 0; c < 4; ++c) {
        const int chunk = wave * 4 + c;       // 16 chunks of 8 rows x 64 cols
        const int row   = chunk * 8 + srow;
        GLD(A + (long)(m0 + row) * lda + kc, dA + chunk * 512);
        GLD(B + (long)(n0 + row) * ldb + kc, dB + chunk * 512);
      }
    }
  };

  stage(0);
  f32x4 acc[4][4] = {};

  for (int t = 0; t < nkt; ++t) {
    stage(t + 1);                             // overlap next-tile loads w/ compute
    FENCE();
    if (t + 1 < nkt) asm volatile("s_waitcnt vmcnt(8)" ::: "memory");
    else             asm volatile("s_waitcnt vmcnt(0)" ::: "memory");
    PH_BAR();
    const char* Ab = (const char*)As[t & 1];
    const char* Bb = (const char*)Bs[t & 1];
    #pragma unroll
    for (int kk = 0; kk < 2; ++kk) {
      bf16x8 af[4], bv[4];
      #pragma unroll
      for (int m = 0; m < 4; ++m) {
        const int r = wm * 64 + m * 16 + colc;
        af[m] = *(const bf16x8*)(Ab + r * 128 + (((kk * 4 + g4) ^ (r & 7)) * 16));
      }
      #pragma unroll
      for (int n = 0; n < 4; ++n) {
        const int r = wn * 64 + n * 16 + colc;
        bv[n] = *(const bf16x8*)(Bb + r * 128 + (((kk * 4 + g4) ^ (r & 7)) * 16));
      }
      #pragma unroll
      for (int m = 0; m < 4; ++m)
        #pragma unroll
        for (int n = 0; n < 4; ++n)
          acc[m][n] = MFMA16(af[m], bv[n], acc[m][n]);
    }
    PH_BAR();                                 // all reads of buf[t&1] done
  }

  // epilogue. C/D frag: col = lane&15, row = (lane>>4)*4 + reg
  #pragma unroll
  for (int m = 0; m < 4; ++m) {
    const int gr0 = m0 + wm * 64 + m * 16 + g4 * 4;
    #pragma unroll
    for (int n = 0; n < 4; ++n) {
      const int gc = n0 + wn * 64 + n * 16 + colc;
      if (EPI == EP_QKV) {
        if (n0 < 2048) {
          #pragma unroll
          for (int r = 0; r < 4; ++r)
            ((bf16*)C)[(long)(gr0 + r) * DMODEL + gc] = (bf16)acc[m][n][r];
        } else if (n0 < 2560) {
          #pragma unroll
          for (int r = 0; r < 4; ++r)
            C2[(long)(gr0 + r) * 512 + (gc - 2048)] = (bf16)acc[m][n][r];
        } else {
          bf16x4 pk = { (bf16)acc[m][n][0], (bf16)acc[m][n][1],
                        (bf16)acc[m][n][2], (bf16)acc[m][n][3] };
          *(bf16x4*)(C3 + (long)(gc - 2560) * SQ + gr0) = pk;
        }
      } else {
        #pragma unroll
        for (int r = 0; r < 4; ++r) {
          const long off = (long)(gr0 + r) * ldc + gc;
          const float v = acc[m][n][r];
          if (EPI == EP_STOREF)      ((float*)C)[off] = v;
          else if (EPI == EP_ADD)    ((float*)C)[off] = ((const float*)Cin)[off] + v;
          else if (EPI == EP_STOREB) ((bf16*)C)[off] = (bf16)v;
        }
      }
    }
  }
}

// ============================================================================
// 256x256-tile, BK=64, 8-wave, 4-phase/K-tile pipelined GEMM (T2+T3+T4+T5).
// ============================================================================
template<int EPI>
__global__ __launch_bounds__(512, 2)
void gemm256(const bf16* __restrict__ A, const bf16* __restrict__ B,
             void* __restrict__ C, const void* __restrict__ Cin,
             int K, int lda, int ldb, int ldc)
{
  __shared__ bf16 smem[2][4][128 * 64];   // 128 KiB

  const int tid  = (int)threadIdx.x;
  const int lane = tid & 63;
  const int wave = tid >> 6;
  const int wm   = wave >> 2;
  const int wn   = wave & 3;

  XCD_SWZ(256)

  const int nkt  = K >> 6;
  const int srow = lane >> 3;
  const long sxcol = (long)(((lane & 7) ^ (lane >> 3)) * 8);
  const int frow = lane & 15;
  const int ph0  = ((     (lane >> 4)) ^ (lane & 7)) * 16;
  const int ph1  = ((4 + (lane >> 4)) ^ (lane & 7)) * 16;

  auto stageA = [&](int tile, int half) {
    if (tile < nkt) {
      const long kc = (long)tile * 64 + sxcol;
      #pragma unroll
      for (int i = 0; i < 2; ++i)
        GLD(A + (long)(m0 + half * 128 + wave * 16 + i * 8 + srow) * lda + kc,
            smem[tile & 1][half] + (wave * 16 + i * 8) * 64);
    }
  };
  auto stageB = [&](int tile, int half) {
    if (tile < nkt) {
      const long kc = (long)tile * 64 + sxcol;
      #pragma unroll
      for (int i = 0; i < 2; ++i)
        GLD(B + (long)(n0 + half * 128 + wave * 16 + i * 8 + srow) * ldb + kc,
            smem[tile & 1][2 + half] + (wave * 16 + i * 8) * 64);
    }
  };

  stageB(0, 0); stageB(0, 1); stageA(0, 0); stageA(0, 1);
  asm volatile("s_waitcnt vmcnt(4)" ::: "memory");
  stageB(1, 0); stageB(1, 1); stageA(1, 0);
  asm volatile("s_waitcnt vmcnt(6)" ::: "memory");
  PH_BAR();

  f32x4 acc[8][4] = {};

  for (int t = 0; t < nkt; ++t) {
    const int bsel = t & 1;
    const char* Asl = (const char*)smem[bsel][wm];
    const char* Bsl = (const char*)smem[bsel][2 + (wn >> 1)];
    const int brow = (wn & 1) * 64;

    bf16x8 ar[4][2], b0f[2][2], b1f[2][2];

    #pragma unroll
    for (int mr = 0; mr < 4; ++mr) {
      ar[mr][0] = *(const bf16x8*)(Asl + (mr * 16 + frow) * 128 + ph0);
      ar[mr][1] = *(const bf16x8*)(Asl + (mr * 16 + frow) * 128 + ph1);
    }
    #pragma unroll
    for (int nc = 0; nc < 2; ++nc) {
      b0f[nc][0] = *(const bf16x8*)(Bsl + (brow + nc * 16 + frow) * 128 + ph0);
      b0f[nc][1] = *(const bf16x8*)(Bsl + (brow + nc * 16 + frow) * 128 + ph1);
    }
    stageA(t + 1, 1);
    PH_BAR();
    __builtin_amdgcn_s_setprio(1);
    #pragma unroll
    for (int mr = 0; mr < 4; ++mr)
      #pragma unroll
      for (int nc = 0; nc < 2; ++nc) {
        acc[mr][nc] = MFMA16(ar[mr][0], b0f[nc][0], acc[mr][nc]);
        acc[mr][nc] = MFMA16(ar[mr][1], b0f[nc][1], acc[mr][nc]);
      }
    __builtin_amdgcn_s_setprio(0);
    PH_BAR();

    #pragma unroll
    for (int nc = 0; nc < 2; ++nc) {
      b1f[nc][0] = *(const bf16x8*)(Bsl + (brow + (2 + nc) * 16 + frow) * 128 + ph0);
      b1f[nc][1] = *(const bf16x8*)(Bsl + (brow + (2 + nc) * 16 + frow) * 128 + ph1);
    }
    PH_BAR();
    __builtin_amdgcn_s_setprio(1);
    #pragma unroll
    for (int mr = 0; mr < 4; ++mr)
      #pragma unroll
      for (int nc = 0; nc < 2; ++nc) {
        acc[mr][2 + nc] = MFMA16(ar[mr][0], b1f[nc][0], acc[mr][2 + nc]);
        acc[mr][2 + nc] = MFMA16(ar[mr][1], b1f[nc][1], acc[mr][2 + nc]);
      }
    __builtin_amdgcn_s_setprio(0);
    PH_BAR();

    #pragma unroll
    for (int mr = 0; mr < 4; ++mr) {
      ar[mr][0] = *(const bf16x8*)(Asl + ((4 + mr) * 16 + frow) * 128 + ph0);
      ar[mr][1] = *(const bf16x8*)(Asl + ((4 + mr) * 16 + frow) * 128 + ph1);
    }
    stageB(t + 2, 0); stageB(t + 2, 1);
    PH_BAR();
    __builtin_amdgcn_s_setprio(1);
    #pragma unroll
    for (int mr = 0; mr < 4; ++mr)
      #pragma unroll
      for (int nc = 0; nc < 2; ++nc) {
        acc[4 + mr][nc] = MFMA16(ar[mr][0], b0f[nc][0], acc[4 + mr][nc]);
        acc[4 + mr][nc] = MFMA16(ar[mr][1], b0f[nc][1], acc[4 + mr][nc]);
      }
    __builtin_amdgcn_s_setprio(0);
    PH_BAR();

    stageA(t + 2, 0);
    PH_BAR();
    __builtin_amdgcn_s_setprio(1);
    #pragma unroll
    for (int mr = 0; mr < 4; ++mr)
      #pragma unroll
      for (int nc = 0; nc < 2; ++nc) {
        acc[4 + mr][2 + nc] = MFMA16(ar[mr][0], b1f[nc][0], acc[4 + mr][2 + nc]);
        acc[4 + mr][2 + nc] = MFMA16(ar[mr][1], b1f[nc][1], acc[4 + mr][2 + nc]);
      }
    __builtin_amdgcn_s_setprio(0);
    FENCE();
    if (t + 2 < nkt) asm volatile("s_waitcnt vmcnt(6)" ::: "memory");
    else             asm volatile("s_waitcnt vmcnt(0)" ::: "memory");
    PH_BAR();
  }

  #pragma unroll
  for (int mr = 0; mr < 8; ++mr) {
    const int gr0 = m0 + wm * 128 + mr * 16 + (lane >> 4) * 4;
    #pragma unroll
    for (int nc = 0; nc < 4; ++nc) {
      const int gc = n0 + wn * 64 + nc * 16 + (lane & 15);
      #pragma unroll
      for (int r = 0; r < 4; ++r) {
        const long off = (long)(gr0 + r) * ldc + gc;
        const float v = acc[mr][nc][r];
        if (EPI == EP_STOREF)      ((float*)C)[off] = v;
        else if (EPI == EP_STOREB) ((bf16*)C)[off] = (bf16)v;
      }
    }
  }
}

// ============================================================================
// Fused flash-style attention (mask-before-softmax, fixed-shift M=0 algebra)
// ============================================================================
__global__ __launch_bounds__(256, 1)
void flash_attn(const bf16* __restrict__ qb, const bf16* __restrict__ kb,
                const bf16* __restrict__ vT, const float* __restrict__ suffPc,
                bf16* __restrict__ yb, float scale)
{
  __shared__ bf16 Ks[128 * 128];
  __shared__ bf16 Vs[128 * 128];
  __shared__ bf16 Ps[128 * 136];

  const int tid  = (int)threadIdx.x;
  const int lane = tid & 63;
  const int w    = tid >> 6;
  const int qt   = (int)blockIdx.x;
  const int h    = (int)blockIdx.y;
  const int kvh  = h >> 2;

  const int l15 = lane & 15;
  const int g4  = lane >> 4;

  bf16x8 qf[2][4];
  #pragma unroll
  for (int m = 0; m < 2; ++m)
    #pragma unroll
    for (int ks = 0; ks < 4; ++ks)
      qf[m][ks] = *(const bf16x8*)(qb + (long)(qt * 128 + w * 32 + m * 16 + l15) * DMODEL
                                   + h * HDIM + ks * 32 + g4 * 8);

  f32x4 acc_o[2][8] = {};
  float den[2][4] = {};

  const bf16* Kg = kb + (long)kvh * HDIM;
  const bf16* Vg = vT + (long)(kvh * HDIM) * SQ;

  for (int j = 0; j <= qt; ++j) {
    const bool diag = (j == qt);
    PH_BAR();

    #pragma unroll
    for (int i = 0; i < 8; ++i) {
      const int rb = w * 32 + i * 4;
      const int r  = rb + g4;
      GLD(Kg + (long)(j * 128 + r) * 512 + ((l15 ^ (r & 7)) * 8), Ks + rb * 128);
    }
    #pragma unroll
    for (int i = 0; i < 8; ++i) {
      const int rb = w * 32 + i * 4;
      const int r  = rb + g4;
      GLD(Vg + (long)r * SQ + j * 128 + ((l15 ^ (r & 7)) * 8), Vs + rb * 128);
    }
    asm volatile("s_waitcnt vmcnt(8)" ::: "memory");
    PH_BAR();

    f32x4 acc_s[2][8] = {};
    #pragma unroll
    for (int ks = 0; ks < 4; ++ks) {
      bf16x8 kf[8];
      #pragma unroll
      for (int n = 0; n < 8; ++n) {
        const int kr = n * 16 + l15;
        kf[n] = *(const bf16x8*)((const char*)Ks + kr * 256 + (((ks * 4 + g4) ^ (kr & 7)) * 16));
      }
      #pragma unroll
      for (int m = 0; m < 2; ++m)
        #pragma unroll
        for (int n = 0; n < 8; ++n)
          acc_s[m][n] = MFMA16(qf[m][ks], kf[n], acc_s[m][n]);
    }

    float rs[2][4] = {};
    #pragma unroll
    for (int m = 0; m < 2; ++m)
      #pragma unroll
      for (int n = 0; n < 8; ++n) {
        const int kc = n * 16 + l15;
        #pragma unroll
        for (int r = 0; r < 4; ++r) {
          const int qlr = w * 32 + m * 16 + g4 * 4 + r;
          float p = __expf(acc_s[m][n][r] * scale);
          if (diag && kc > qlr) p = 1.0f;
          rs[m][r] += p;
          Ps[(w * 32 + m * 16 + g4 * 4 + r) * 136 + kc] = (bf16)p;
        }
      }
    #pragma unroll
    for (int m = 0; m < 2; ++m)
      #pragma unroll
      for (int r = 0; r < 4; ++r) {
        float v = rs[m][r];
        v += __shfl_xor(v, 1); v += __shfl_xor(v, 2);
        v += __shfl_xor(v, 4); v += __shfl_xor(v, 8);
        den[m][r] += v;
      }

    asm volatile("s_waitcnt vmcnt(0) lgkmcnt(0)" ::: "memory");
    PH_BAR();

    #pragma unroll
    for (int ks = 0; ks < 4; ++ks) {
      bf16x8 pa[2], vf[8];
      #pragma unroll
      for (int m = 0; m < 2; ++m)
        pa[m] = *(const bf16x8*)((const char*)Ps + (w * 32 + m * 16 + l15) * 272
                                 + ks * 64 + g4 * 16);
      #pragma unroll
      for (int n = 0; n < 8; ++n) {
        const int dr = n * 16 + l15;
        vf[n] = *(const bf16x8*)((const char*)Vs + dr * 256 + (((ks * 4 + g4) ^ (dr & 7)) * 16));
      }
      #pragma unroll
      for (int m = 0; m < 2; ++m)
        #pragma unroll
        for (int n = 0; n < 8; ++n)
          acc_o[m][n] = MFMA16(pa[m], vf[n], acc_o[m][n]);
    }
  }

  float denf[2][4];
  #pragma unroll
  for (int m = 0; m < 2; ++m)
    #pragma unroll
    for (int r = 0; r < 4; ++r)
      denf[m][r] = den[m][r] + 128.0f * (15 - qt);

  #pragma unroll
  for (int n = 0; n < 8; ++n) {
    const float t = suffPc[((kvh << 4) + qt) * 128 + n * 16 + l15];
    #pragma unroll
    for (int m = 0; m < 2; ++m)
      #pragma unroll
      for (int r = 0; r < 4; ++r) {
        const float y = (acc_o[m][n][r] + t) / denf[m][r];
        yb[(long)(qt * 128 + w * 32 + m * 16 + g4 * 4 + r) * DMODEL
           + h * HDIM + n * 16 + l15] = (bf16)y;
      }
  }
}

__global__ __launch_bounds__(128)
void vsuffix(const bf16* __restrict__ vT, float* __restrict__ suffPc)
{
  const int kvh = (int)blockIdx.x;
  const int d   = (int)threadIdx.x;
  const bf16* row = vT + (long)(kvh * HDIM + d) * SQ;
  float a = 0.f;
  for (int c = 15; c >= 0; --c) {
    suffPc[(kvh * 16 + c) * 128 + d] = a;
    float s = 0.f;
    #pragma unroll
    for (int r = 0; r < 16; ++r) {
      bf16x8 v = *(const bf16x8*)(row + c * 128 + r * 8);
      #pragma unroll
      for (int e = 0; e < 8; ++e) s += (float)v[e];
    }
    a += s;
  }
}

// silu(up)*gate in place over the gate half of gz[2048][11264]
__global__ __launch_bounds__(256)
void silumul(bf16* __restrict__ gz)
{
  const long t  = (long)blockIdx.x * 256 + threadIdx.x;   // 2048*704 threads
  const int row = (int)(t / 704);
  const int c8  = (int)(t % 704);
  bf16* g = gz + (long)row * (2 * FFDIM) + c8 * 8;
  bf16x8 gv = *(bf16x8*)g;
  bf16x8 uv = *(bf16x8*)(g + FFDIM);
  bf16x8 o;
  #pragma unroll
  for (int j = 0; j < 8; ++j) {
    const float u = (float)uv[j];
    o[j] = (bf16)((u / (1.0f + __expf(-u))) * (float)gv[j]);
  }
  *(bf16x8*)g = o;
}

// fp32 [K][N] -> bf16 [N][K] transpose+convert
__global__ __launch_bounds__(256)
void transpose_cvt(const float* __restrict__ in, bf16* __restrict__ out, int K, int N)
{
  __shared__ float t[32][33];
  const int n0 = (int)blockIdx.x * 32, k0 = (int)blockIdx.y * 32;
  const int tr = (int)threadIdx.x >> 3;
  const int tc = ((int)threadIdx.x & 7) * 4;
  f32x4 v = *(const f32x4*)(in + (long)(k0 + tr) * N + n0 + tc);
  t[tr][tc] = v[0]; t[tr][tc + 1] = v[1]; t[tr][tc + 2] = v[2]; t[tr][tc + 3] = v[3];
  __syncthreads();
  bf16x4 b = { (bf16)t[tc][tr], (bf16)t[tc + 1][tr], (bf16)t[tc + 2][tr], (bf16)t[tc + 3][tr] };
  *(bf16x4*)(out + (long)(n0 + tr) * K + k0 + tc) = b;
}

__global__ __launch_bounds__(256)
void cvt_bf16_kernel(const float* __restrict__ in, bf16* __restrict__ out, int nvec)
{
  const int i = (int)(blockIdx.x * 256 + threadIdx.x);
  if (i < nvec) {
    f32x4 v = ((const f32x4*)in)[i];
    bf16x4 b = { (bf16)v[0], (bf16)v[1], (bf16)v[2], (bf16)v[3] };
    ((bf16x4*)out)[i] = b;
  }
}

__global__ __launch_bounds__(256)
void rmsnorm_kernel(bf16* __restrict__ out, const float* __restrict__ in, const float* __restrict__ g)
{
  const int row = (int)blockIdx.x;
  const float* x = in + (long)row * DMODEL;
  bf16* o = out + (long)row * DMODEL;
  const int tid = (int)threadIdx.x;
  f32x4 v0 = *(const f32x4*)(x + tid * 4);
  f32x4 v1 = *(const f32x4*)(x + tid * 4 + 1024);
  float ss = v0[0]*v0[0] + v0[1]*v0[1] + v0[2]*v0[2] + v0[3]*v0[3]
           + v1[0]*v1[0] + v1[1]*v1[1] + v1[2]*v1[2] + v1[3]*v1[3];
  #pragma unroll
  for (int o_ = 32; o_; o_ >>= 1) ss += __shfl_xor(ss, o_);
  __shared__ float sm[4];
  if ((tid & 63) == 0) sm[tid >> 6] = ss;
  __syncthreads();
  ss = sm[0] + sm[1] + sm[2] + sm[3];
  const float r = 1.0f / sqrtf(ss * (1.0f / DMODEL) + EPSV);
  f32x4 g0 = *(const f32x4*)(g + tid * 4);
  f32x4 g1 = *(const f32x4*)(g + tid * 4 + 1024);
  bf16x4 o0, o1;
  #pragma unroll
  for (int j = 0; j < 4; ++j) { o0[j] = (bf16)(v0[j] * r * g0[j]); o1[j] = (bf16)(v1[j] * r * g1[j]); }
  *(bf16x4*)(o + tid * 4) = o0;
  *(bf16x4*)(o + tid * 4 + 1024) = o1;
}

__global__ void rope_tables(float* cosT, float* sinT)
{
  const int s = (int)blockIdx.x;
  const int i = (int)threadIdx.x;
  const double inv = pow(10000.0, -(double)i / 64.0);
  const double f = (double)s * inv;
  cosT[s * 64 + i] = (float)cos(f);
  sinT[s * 64 + i] = (float)sin(f);
}

__global__ __launch_bounds__(256)
void rope_apply(bf16* buf, const float* cosT, const float* sinT, int nh, int stride)
{
  const int t = (int)(blockIdx.x * blockDim.x + threadIdx.x);
  const int per = nh * 64;
  const int s = t / per;
  const int r = t - s * per;
  const int h = r >> 6;
  const int i = r & 63;
  bf16* b = buf + (long)s * stride + h * HDIM;
  const float c  = cosT[s * 64 + i];
  const float sn = sinT[s * 64 + i];
  const float x1 = (float)b[i];
  const float x2 = (float)b[64 + i];
  b[i]      = (bf16)(x1 * c - x2 * sn);
  b[64 + i] = (bf16)(x2 * c + x1 * sn);
}

__global__ __launch_bounds__(256)
void embed_gather(f32x4* x, const f32x4* embed, const int* idx)
{
  const int t = (int)(blockIdx.x * 256 + threadIdx.x);
  const int s = t >> 9;
  const int c = t & 511;
  x[t] = embed[(long)idx[s] * 512 + c];
}

extern "C" void kernel_launch(void* const* d_in, const int* in_sizes, int n_in,
                              void* d_out, int out_size, void* d_ws, size_t ws_size,
                              hipStream_t stream)
{
  (void)in_sizes; (void)n_in; (void)out_size;
  const int*   idx   = (const int*)  d_in[0];
  const float* embed = (const float*)d_in[1];
  const float* wq    = (const float*)d_in[2];
  const float* wk    = (const float*)d_in[3];
  const float* wv    = (const float*)d_in[4];
  const float* wo    = (const float*)d_in[5];
  const float* ln1g  = (const float*)d_in[6];
  const float* ln2g  = (const float*)d_in[7];
  const float* wgate = (const float*)d_in[8];
  const float* wup   = (const float*)d_in[9];
  const float* wdown = (const float*)d_in[10];
  const float* fing  = (const float*)d_in[11];
  const float* lmh   = (const float*)d_in[12];
  float* out = (float*)d_out;

  char* wp = (char*)d_ws;
  auto alloc = [&](size_t bytes) { char* p = wp; wp += (bytes + 255) & ~(size_t)255; return p; };
  float* cosT   = (float*)alloc((size_t)SQ * 64 * 4);
  float* sinT   = (float*)alloc((size_t)SQ * 64 * 4);
  float* suffPc = (float*)alloc((size_t)NKV * 16 * 128 * 4);
  float* x      = (float*)alloc((size_t)SQ * DMODEL * 4);
  bf16*  h      = (bf16*) alloc((size_t)SQ * DMODEL * 2);
  bf16*  qb     = (bf16*) alloc((size_t)SQ * DMODEL * 2);
  bf16*  kb     = (bf16*) alloc((size_t)SQ * 512 * 2);
  bf16*  vT     = (bf16*) alloc((size_t)512 * SQ * 2);
  size_t used  = (size_t)(wp - (char*)d_ws);
  bf16*  wbuf  = (bf16*)wp;                 // weight scratch (max gate+up: 46 MB)
  size_t avail = ws_size - used;

  bf16* yb = qb;                            // flash writes y over q (same rows per block)
  bf16* gz = (bf16*)d_out;                  // gate/up raw [2048][11264] — d_out dead until lm_head
  const float scale = 0.08838834764831845f;

  rope_tables<<<SQ, 64, 0, stream>>>(cosT, sinT);
  embed_gather<<<(SQ * 512) / 256, 256, 0, stream>>>((f32x4*)x, (const f32x4*)embed, idx);

  for (int l = 0; l < NLAYER; ++l) {
    const float* lwq = wq    + (long)l * DMODEL * DMODEL;
    const float* lwk = wk    + (long)l * DMODEL * 512;
    const float* lwv = wv    + (long)l * DMODEL * 512;
    const float* lwo = wo    + (long)l * DMODEL * DMODEL;
    const float* lwg = wgate + (long)l * DMODEL * FFDIM;
    const float* lwu = wup   + (long)l * DMODEL * FFDIM;
    const float* lwd = wdown + (long)l * FFDIM * DMODEL;

    rmsnorm_kernel<<<SQ, 256, 0, stream>>>(h, x, ln1g + l * DMODEL);

    // fused QKV: B = [wq^T | wk^T | wv^T] (3072 x 2048)
    transpose_cvt<<<dim3(64, 64), 256, 0, stream>>>(lwq, wbuf, DMODEL, DMODEL);
    transpose_cvt<<<dim3(16, 64), 256, 0, stream>>>(lwk, wbuf + (long)2048 * DMODEL, DMODEL, 512);
    transpose_cvt<<<dim3(16, 64), 256, 0, stream>>>(lwv, wbuf + (long)2560 * DMODEL, DMODEL, 512);
    gemm128<EP_QKV><<<dim3(16, 24), 256, 0, stream>>>(
        h, wbuf, qb, nullptr, kb, vT, DMODEL, DMODEL, DMODEL, 0);

    vsuffix<<<NKV, 128, 0, stream>>>(vT, suffPc);
    rope_apply<<<(SQ * NHEAD * 64) / 256, 256, 0, stream>>>(qb, cosT, sinT, NHEAD, DMODEL);
    rope_apply<<<(SQ * NKV * 64) / 256, 256, 0, stream>>>(kb, cosT, sinT, NKV, 512);

    flash_attn<<<dim3(16, NHEAD), 256, 0, stream>>>(qb, kb, vT, suffPc, yb, scale);

    transpose_cvt<<<dim3(64, 64), 256, 0, stream>>>(lwo, wbuf, DMODEL, DMODEL);
    gemm128<EP_ADD><<<dim3(16, 16), 256, 0, stream>>>(
        yb, wbuf, x, x, nullptr, nullptr, DMODEL, DMODEL, DMODEL, DMODEL);

    rmsnorm_kernel<<<SQ, 256, 0, stream>>>(h, x, ln2g + l * DMODEL);

    // fused gate+up: B = [wg^T | wu^T] (11264 x 2048) -> gz[2048][11264] in d_out
    transpose_cvt<<<dim3(176, 64), 256, 0, stream>>>(lwg, wbuf, DMODEL, FFDIM);
    transpose_cvt<<<dim3(176, 64), 256, 0, stream>>>(lwu, wbuf + (long)FFDIM * DMODEL, DMODEL, FFDIM);
    gemm256<EP_STOREB><<<dim3(8, 44), 512, 0, stream>>>(
        h, wbuf, gz, nullptr, DMODEL, DMODEL, DMODEL, 2 * FFDIM);

    silumul<<<(SQ * (FFDIM / 8)) / 256, 256, 0, stream>>>(gz);

    // down: A = gate half of gz (lda = 11264), K = 5632
    transpose_cvt<<<dim3(64, 176), 256, 0, stream>>>(lwd, wbuf, FFDIM, DMODEL);
    gemm128<EP_ADD><<<dim3(16, 16), 256, 0, stream>>>(
        gz, wbuf, x, x, nullptr, nullptr, FFDIM, 2 * FFDIM, FFDIM, DMODEL);
  }

  rmsnorm_kernel<<<SQ, 256, 0, stream>>>(h, x, fing);

  long chunkRows = (long)(avail / ((size_t)DMODEL * 2)) & ~255L;
  if (chunkRows > VOCAB) chunkRows = VOCAB;
  for (long c0 = 0; c0 < VOCAB; c0 += chunkRows) {
    const long rows = (VOCAB - c0 < chunkRows) ? (VOCAB - c0) : chunkRows;
    const int  nvec = (int)(rows * DMODEL / 4);
    cvt_bf16_kernel<<<(nvec + 255) / 256, 256, 0, stream>>>(lmh + c0 * DMODEL, wbuf, nvec);
    gemm256<EP_STOREF><<<dim3(8, (int)(rows / 256)), 512, 0, stream>>>(
        h, wbuf, out + c0, nullptr, DMODEL, DMODEL, DMODEL, VOCAB);
  }
}

// Round 7
// 1319.008 us; speedup vs baseline: 2.1899x; 1.0113x over previous
//
#include <hip/hip_runtime.h>

#define SQ     2048
#define DMODEL 2048
#define NHEAD  16
#define NKV    4
#define HDIM   128
#define FFDIM  5632
#define VOCAB  32000
#define NLAYER 2
#define EPSV   1e-5f

typedef __bf16 bf16;
typedef __bf16 bf16x4 __attribute__((ext_vector_type(4)));
typedef __bf16 bf16x8 __attribute__((ext_vector_type(8)));
typedef float  f32x4  __attribute__((ext_vector_type(4)));

enum { EP_STOREF = 0, EP_ADD = 2, EP_STOREB = 3, EP_QKV = 6, EP_GLU = 7 };

// global -> LDS direct DMA, 16B per lane; LDS dest = wave-uniform base + lane*16
#define GLD(gp, lp) __builtin_amdgcn_global_load_lds( \
    (const __attribute__((address_space(1))) void*)(gp), \
    (__attribute__((address_space(3))) void*)(lp), 16, 0, 0)

#define MFMA16(a, b, c) __builtin_amdgcn_mfma_f32_16x16x32_bf16(a, b, c, 0, 0, 0)

#define FENCE() __builtin_amdgcn_sched_barrier(0)
#define PH_BAR() do { FENCE(); __builtin_amdgcn_s_barrier(); FENCE(); } while (0)

// XCD-bijective swizzle + m-fastest decode (m204)
#define XCD_SWZ(TM)                                                        \
  const int GM  = (int)gridDim.x;                                          \
  const int nwg = GM * (int)gridDim.y;                                     \
  const int bid = (int)blockIdx.y * GM + (int)blockIdx.x;                  \
  const int q8  = nwg >> 3, r8 = nwg & 7;                                  \
  const int xcd = bid & 7, rnk = bid >> 3;                                 \
  const int swz = ((xcd < r8) ? xcd * (q8 + 1)                             \
                              : r8 * (q8 + 1) + (xcd - r8) * q8) + rnk;    \
  const int m0  = (swz % GM) * (TM);                                       \
  const int n0  = (swz / GM) * (TM == 256 ? 256 : 128);

// ============================================================================
// 128x128-tile, BK=64, 4-wave, prefetching pipelined GEMM.
// NBUF=2: 1-tile-deep prefetch, 64KB LDS, 2 blocks/CU (for grids > 256 blocks).
// NBUF=3: 2-tile-deep prefetch, 96KB LDS, 1 block/CU (for exactly-256-block
//         grids where the co-resident-block latency cover doesn't exist).
// vmcnt ledger (8 loads/wave/tile): NBUF=2 -> 8 steady; NBUF=3 -> 16 steady,
// 8 at t+2==nkt, 0 at last tile. Never drains mid-loop otherwise (T4).
// ============================================================================
template<int EPI, int NBUF>
__global__ __launch_bounds__(256, NBUF == 2 ? 2 : 1)
void gemm128(const bf16* __restrict__ A, const bf16* __restrict__ B,
             void* __restrict__ C, const void* __restrict__ Cin,
             bf16* __restrict__ C2, bf16* __restrict__ C3,
             int K, int lda, int ldb, int ldc)
{
  __shared__ bf16 As[NBUF][128 * 64];
  __shared__ bf16 Bs[NBUF][128 * 64];

  const int tid  = (int)threadIdx.x;
  const int lane = tid & 63;
  const int wave = tid >> 6;
  const int wm   = wave >> 1, wn = wave & 1;

  XCD_SWZ(128)

  const int nkt  = K >> 6;
  const int srow = lane >> 3;
  const long sxcol = (long)(((lane & 7) ^ (lane >> 3)) * 8);
  const int colc = lane & 15;
  const int g4   = lane >> 4;

  auto stage = [&](int t, int buf) {
    if (t < nkt) {
      const long kc = (long)t * 64 + sxcol;
      bf16* dA = As[buf];
      bf16* dB = Bs[buf];
      #pragma unroll
      for (int c = 0; c < 4; ++c) {
        const int chunk = wave * 4 + c;       // 16 chunks of 8 rows x 64 cols
        const int row   = chunk * 8 + srow;
        GLD(A + (long)(m0 + row) * lda + kc, dA + chunk * 512);
        GLD(B + (long)(n0 + row) * ldb + kc, dB + chunk * 512);
      }
    }
  };

  stage(0, 0);
  if (NBUF == 3) stage(1, 1);

  f32x4 acc[4][4] = {};
  int wb = (NBUF == 3) ? 2 : 1;               // buffer for next stage
  int rb = 0;                                 // buffer being read

  for (int t = 0; t < nkt; ++t) {
    if (NBUF == 2) {
      stage(t + 1, wb);
      wb ^= 1;
      FENCE();
      if (t + 1 < nkt) asm volatile("s_waitcnt vmcnt(8)" ::: "memory");
      else             asm volatile("s_waitcnt vmcnt(0)" ::: "memory");
    } else {
      stage(t + 2, wb);
      wb = (wb == 2) ? 0 : wb + 1;
      FENCE();
      if (t + 2 < nkt)      asm volatile("s_waitcnt vmcnt(16)" ::: "memory");
      else if (t + 1 < nkt) asm volatile("s_waitcnt vmcnt(8)"  ::: "memory");
      else                  asm volatile("s_waitcnt vmcnt(0)"  ::: "memory");
    }
    PH_BAR();
    const char* Ab = (const char*)As[rb];
    const char* Bb = (const char*)Bs[rb];
    rb = (NBUF == 2) ? (rb ^ 1) : ((rb == 2) ? 0 : rb + 1);
    #pragma unroll
    for (int kk = 0; kk < 2; ++kk) {
      bf16x8 af[4], bv[4];
      #pragma unroll
      for (int m = 0; m < 4; ++m) {
        const int r = wm * 64 + m * 16 + colc;
        af[m] = *(const bf16x8*)(Ab + r * 128 + (((kk * 4 + g4) ^ (r & 7)) * 16));
      }
      #pragma unroll
      for (int n = 0; n < 4; ++n) {
        const int r = wn * 64 + n * 16 + colc;
        bv[n] = *(const bf16x8*)(Bb + r * 128 + (((kk * 4 + g4) ^ (r & 7)) * 16));
      }
      #pragma unroll
      for (int m = 0; m < 4; ++m)
        #pragma unroll
        for (int n = 0; n < 4; ++n)
          acc[m][n] = MFMA16(af[m], bv[n], acc[m][n]);
    }
    PH_BAR();
  }

  // epilogue. C/D frag: col = lane&15, row = (lane>>4)*4 + reg
  #pragma unroll
  for (int m = 0; m < 4; ++m) {
    const int gr0 = m0 + wm * 64 + m * 16 + g4 * 4;
    #pragma unroll
    for (int n = 0; n < 4; ++n) {
      const int gc = n0 + wn * 64 + n * 16 + colc;
      if (EPI == EP_QKV) {
        if (n0 < 2048) {
          #pragma unroll
          for (int r = 0; r < 4; ++r)
            ((bf16*)C)[(long)(gr0 + r) * DMODEL + gc] = (bf16)acc[m][n][r];
        } else if (n0 < 2560) {
          #pragma unroll
          for (int r = 0; r < 4; ++r)
            C2[(long)(gr0 + r) * 512 + (gc - 2048)] = (bf16)acc[m][n][r];
        } else {
          bf16x4 pk = { (bf16)acc[m][n][0], (bf16)acc[m][n][1],
                        (bf16)acc[m][n][2], (bf16)acc[m][n][3] };
          *(bf16x4*)(C3 + (long)(gc - 2560) * SQ + gr0) = pk;
        }
      } else {
        #pragma unroll
        for (int r = 0; r < 4; ++r) {
          const long off = (long)(gr0 + r) * ldc + gc;
          const float v = acc[m][n][r];
          if (EPI == EP_STOREF)      ((float*)C)[off] = v;
          else if (EPI == EP_ADD)    ((float*)C)[off] = ((const float*)Cin)[off] + v;
          else if (EPI == EP_STOREB) ((bf16*)C)[off] = (bf16)v;
        }
      }
    }
  }
}

// ============================================================================
// 256x256-tile, BK=64, 8-wave, 4-phase/K-tile pipelined GEMM (T2+T3+T4+T5).
// EP_GLU: B rows interleaved (even=gate, odd=up); epilogue pairs adjacent
// columns via shfl_xor(1); even lanes write silu(up)*gate bf16 at col gc/2.
// ============================================================================
template<int EPI>
__global__ __launch_bounds__(512, 2)
void gemm256(const bf16* __restrict__ A, const bf16* __restrict__ B,
             void* __restrict__ C, const void* __restrict__ Cin,
             int K, int lda, int ldb, int ldc)
{
  __shared__ bf16 smem[2][4][128 * 64];   // 128 KiB

  const int tid  = (int)threadIdx.x;
  const int lane = tid & 63;
  const int wave = tid >> 6;
  const int wm   = wave >> 2;
  const int wn   = wave & 3;

  XCD_SWZ(256)

  const int nkt  = K >> 6;
  const int srow = lane >> 3;
  const long sxcol = (long)(((lane & 7) ^ (lane >> 3)) * 8);
  const int frow = lane & 15;
  const int ph0  = ((     (lane >> 4)) ^ (lane & 7)) * 16;
  const int ph1  = ((4 + (lane >> 4)) ^ (lane & 7)) * 16;

  auto stageA = [&](int tile, int half) {
    if (tile < nkt) {
      const long kc = (long)tile * 64 + sxcol;
      #pragma unroll
      for (int i = 0; i < 2; ++i)
        GLD(A + (long)(m0 + half * 128 + wave * 16 + i * 8 + srow) * lda + kc,
            smem[tile & 1][half] + (wave * 16 + i * 8) * 64);
    }
  };
  auto stageB = [&](int tile, int half) {
    if (tile < nkt) {
      const long kc = (long)tile * 64 + sxcol;
      #pragma unroll
      for (int i = 0; i < 2; ++i)
        GLD(B + (long)(n0 + half * 128 + wave * 16 + i * 8 + srow) * ldb + kc,
            smem[tile & 1][2 + half] + (wave * 16 + i * 8) * 64);
    }
  };

  stageB(0, 0); stageB(0, 1); stageA(0, 0); stageA(0, 1);
  asm volatile("s_waitcnt vmcnt(4)" ::: "memory");
  stageB(1, 0); stageB(1, 1); stageA(1, 0);
  asm volatile("s_waitcnt vmcnt(6)" ::: "memory");
  PH_BAR();

  f32x4 acc[8][4] = {};

  for (int t = 0; t < nkt; ++t) {
    const int bsel = t & 1;
    const char* Asl = (const char*)smem[bsel][wm];
    const char* Bsl = (const char*)smem[bsel][2 + (wn >> 1)];
    const int brow = (wn & 1) * 64;

    bf16x8 ar[4][2], b0f[2][2], b1f[2][2];

    #pragma unroll
    for (int mr = 0; mr < 4; ++mr) {
      ar[mr][0] = *(const bf16x8*)(Asl + (mr * 16 + frow) * 128 + ph0);
      ar[mr][1] = *(const bf16x8*)(Asl + (mr * 16 + frow) * 128 + ph1);
    }
    #pragma unroll
    for (int nc = 0; nc < 2; ++nc) {
      b0f[nc][0] = *(const bf16x8*)(Bsl + (brow + nc * 16 + frow) * 128 + ph0);
      b0f[nc][1] = *(const bf16x8*)(Bsl + (brow + nc * 16 + frow) * 128 + ph1);
    }
    stageA(t + 1, 1);
    PH_BAR();
    __builtin_amdgcn_s_setprio(1);
    #pragma unroll
    for (int mr = 0; mr < 4; ++mr)
      #pragma unroll
      for (int nc = 0; nc < 2; ++nc) {
        acc[mr][nc] = MFMA16(ar[mr][0], b0f[nc][0], acc[mr][nc]);
        acc[mr][nc] = MFMA16(ar[mr][1], b0f[nc][1], acc[mr][nc]);
      }
    __builtin_amdgcn_s_setprio(0);
    PH_BAR();

    #pragma unroll
    for (int nc = 0; nc < 2; ++nc) {
      b1f[nc][0] = *(const bf16x8*)(Bsl + (brow + (2 + nc) * 16 + frow) * 128 + ph0);
      b1f[nc][1] = *(const bf16x8*)(Bsl + (brow + (2 + nc) * 16 + frow) * 128 + ph1);
    }
    PH_BAR();
    __builtin_amdgcn_s_setprio(1);
    #pragma unroll
    for (int mr = 0; mr < 4; ++mr)
      #pragma unroll
      for (int nc = 0; nc < 2; ++nc) {
        acc[mr][2 + nc] = MFMA16(ar[mr][0], b1f[nc][0], acc[mr][2 + nc]);
        acc[mr][2 + nc] = MFMA16(ar[mr][1], b1f[nc][1], acc[mr][2 + nc]);
      }
    __builtin_amdgcn_s_setprio(0);
    PH_BAR();

    #pragma unroll
    for (int mr = 0; mr < 4; ++mr) {
      ar[mr][0] = *(const bf16x8*)(Asl + ((4 + mr) * 16 + frow) * 128 + ph0);
      ar[mr][1] = *(const bf16x8*)(Asl + ((4 + mr) * 16 + frow) * 128 + ph1);
    }
    stageB(t + 2, 0); stageB(t + 2, 1);
    PH_BAR();
    __builtin_amdgcn_s_setprio(1);
    #pragma unroll
    for (int mr = 0; mr < 4; ++mr)
      #pragma unroll
      for (int nc = 0; nc < 2; ++nc) {
        acc[4 + mr][nc] = MFMA16(ar[mr][0], b0f[nc][0], acc[4 + mr][nc]);
        acc[4 + mr][nc] = MFMA16(ar[mr][1], b0f[nc][1], acc[4 + mr][nc]);
      }
    __builtin_amdgcn_s_setprio(0);
    PH_BAR();

    stageA(t + 2, 0);
    PH_BAR();
    __builtin_amdgcn_s_setprio(1);
    #pragma unroll
    for (int mr = 0; mr < 4; ++mr)
      #pragma unroll
      for (int nc = 0; nc < 2; ++nc) {
        acc[4 + mr][2 + nc] = MFMA16(ar[mr][0], b1f[nc][0], acc[4 + mr][2 + nc]);
        acc[4 + mr][2 + nc] = MFMA16(ar[mr][1], b1f[nc][1], acc[4 + mr][2 + nc]);
      }
    __builtin_amdgcn_s_setprio(0);
    FENCE();
    if (t + 2 < nkt) asm volatile("s_waitcnt vmcnt(6)" ::: "memory");
    else             asm volatile("s_waitcnt vmcnt(0)" ::: "memory");
    PH_BAR();
  }

  #pragma unroll
  for (int mr = 0; mr < 8; ++mr) {
    const int gr0 = m0 + wm * 128 + mr * 16 + (lane >> 4) * 4;
    #pragma unroll
    for (int nc = 0; nc < 4; ++nc) {
      const int gc = n0 + wn * 64 + nc * 16 + (lane & 15);
      #pragma unroll
      for (int r = 0; r < 4; ++r) {
        const float v = acc[mr][nc][r];
        if (EPI == EP_GLU) {
          const float o = __shfl_xor(v, 1);      // partner column's value
          if (((lane & 15) & 1) == 0) {          // even col lane: v=gate, o=up
            const float res = (o / (1.0f + __expf(-o))) * v;
            ((bf16*)C)[(long)(gr0 + r) * ldc + (gc >> 1)] = (bf16)res;
          }
        } else {
          const long off = (long)(gr0 + r) * ldc + gc;
          if (EPI == EP_STOREF)      ((float*)C)[off] = v;
          else if (EPI == EP_STOREB) ((bf16*)C)[off] = (bf16)v;
        }
      }
    }
  }
}

// ============================================================================
// Fused flash-style attention (mask-before-softmax, fixed-shift M=0 algebra)
// ============================================================================
__global__ __launch_bounds__(256, 1)
void flash_attn(const bf16* __restrict__ qb, const bf16* __restrict__ kb,
                const bf16* __restrict__ vT, const float* __restrict__ suffPc,
                bf16* __restrict__ yb, float scale)
{
  __shared__ bf16 Ks[128 * 128];
  __shared__ bf16 Vs[128 * 128];
  __shared__ bf16 Ps[128 * 136];

  const int tid  = (int)threadIdx.x;
  const int lane = tid & 63;
  const int w    = tid >> 6;
  const int qt   = (int)blockIdx.x;
  const int h    = (int)blockIdx.y;
  const int kvh  = h >> 2;

  const int l15 = lane & 15;
  const int g4  = lane >> 4;

  bf16x8 qf[2][4];
  #pragma unroll
  for (int m = 0; m < 2; ++m)
    #pragma unroll
    for (int ks = 0; ks < 4; ++ks)
      qf[m][ks] = *(const bf16x8*)(qb + (long)(qt * 128 + w * 32 + m * 16 + l15) * DMODEL
                                   + h * HDIM + ks * 32 + g4 * 8);

  f32x4 acc_o[2][8] = {};
  float den[2][4] = {};

  const bf16* Kg = kb + (long)kvh * HDIM;
  const bf16* Vg = vT + (long)(kvh * HDIM) * SQ;

  for (int j = 0; j <= qt; ++j) {
    const bool diag = (j == qt);
    PH_BAR();

    #pragma unroll
    for (int i = 0; i < 8; ++i) {
      const int rb = w * 32 + i * 4;
      const int r  = rb + g4;
      GLD(Kg + (long)(j * 128 + r) * 512 + ((l15 ^ (r & 7)) * 8), Ks + rb * 128);
    }
    #pragma unroll
    for (int i = 0; i < 8; ++i) {
      const int rb = w * 32 + i * 4;
      const int r  = rb + g4;
      GLD(Vg + (long)r * SQ + j * 128 + ((l15 ^ (r & 7)) * 8), Vs + rb * 128);
    }
    asm volatile("s_waitcnt vmcnt(8)" ::: "memory");
    PH_BAR();

    f32x4 acc_s[2][8] = {};
    #pragma unroll
    for (int ks = 0; ks < 4; ++ks) {
      bf16x8 kf[8];
      #pragma unroll
      for (int n = 0; n < 8; ++n) {
        const int kr = n * 16 + l15;
        kf[n] = *(const bf16x8*)((const char*)Ks + kr * 256 + (((ks * 4 + g4) ^ (kr & 7)) * 16));
      }
      #pragma unroll
      for (int m = 0; m < 2; ++m)
        #pragma unroll
        for (int n = 0; n < 8; ++n)
          acc_s[m][n] = MFMA16(qf[m][ks], kf[n], acc_s[m][n]);
    }

    float rs[2][4] = {};
    #pragma unroll
    for (int m = 0; m < 2; ++m)
      #pragma unroll
      for (int n = 0; n < 8; ++n) {
        const int kc = n * 16 + l15;
        #pragma unroll
        for (int r = 0; r < 4; ++r) {
          const int qlr = w * 32 + m * 16 + g4 * 4 + r;
          float p = __expf(acc_s[m][n][r] * scale);
          if (diag && kc > qlr) p = 1.0f;
          rs[m][r] += p;
          Ps[(w * 32 + m * 16 + g4 * 4 + r) * 136 + kc] = (bf16)p;
        }
      }
    #pragma unroll
    for (int m = 0; m < 2; ++m)
      #pragma unroll
      for (int r = 0; r < 4; ++r) {
        float v = rs[m][r];
        v += __shfl_xor(v, 1); v += __shfl_xor(v, 2);
        v += __shfl_xor(v, 4); v += __shfl_xor(v, 8);
        den[m][r] += v;
      }

    asm volatile("s_waitcnt vmcnt(0) lgkmcnt(0)" ::: "memory");
    PH_BAR();

    #pragma unroll
    for (int ks = 0; ks < 4; ++ks) {
      bf16x8 pa[2], vf[8];
      #pragma unroll
      for (int m = 0; m < 2; ++m)
        pa[m] = *(const bf16x8*)((const char*)Ps + (w * 32 + m * 16 + l15) * 272
                                 + ks * 64 + g4 * 16);
      #pragma unroll
      for (int n = 0; n < 8; ++n) {
        const int dr = n * 16 + l15;
        vf[n] = *(const bf16x8*)((const char*)Vs + dr * 256 + (((ks * 4 + g4) ^ (dr & 7)) * 16));
      }
      #pragma unroll
      for (int m = 0; m < 2; ++m)
        #pragma unroll
        for (int n = 0; n < 8; ++n)
          acc_o[m][n] = MFMA16(pa[m], vf[n], acc_o[m][n]);
    }
  }

  float denf[2][4];
  #pragma unroll
  for (int m = 0; m < 2; ++m)
    #pragma unroll
    for (int r = 0; r < 4; ++r)
      denf[m][r] = den[m][r] + 128.0f * (15 - qt);

  #pragma unroll
  for (int n = 0; n < 8; ++n) {
    const float t = suffPc[((kvh << 4) + qt) * 128 + n * 16 + l15];
    #pragma unroll
    for (int m = 0; m < 2; ++m)
      #pragma unroll
      for (int r = 0; r < 4; ++r) {
        const float y = (acc_o[m][n][r] + t) / denf[m][r];
        yb[(long)(qt * 128 + w * 32 + m * 16 + g4 * 4 + r) * DMODEL
           + h * HDIM + n * 16 + l15] = (bf16)y;
      }
  }
}

__global__ __launch_bounds__(128)
void vsuffix(const bf16* __restrict__ vT, float* __restrict__ suffPc)
{
  const int kvh = (int)blockIdx.x;
  const int d   = (int)threadIdx.x;
  const bf16* row = vT + (long)(kvh * HDIM + d) * SQ;
  float a = 0.f;
  for (int c = 15; c >= 0; --c) {
    suffPc[(kvh * 16 + c) * 128 + d] = a;
    float s = 0.f;
    #pragma unroll
    for (int r = 0; r < 16; ++r) {
      bf16x8 v = *(const bf16x8*)(row + c * 128 + r * 8);
      #pragma unroll
      for (int e = 0; e < 8; ++e) s += (float)v[e];
    }
    a += s;
  }
}

// fp32 [K][N] -> bf16 transpose+convert, up to 3 segments (z-indexed).
// Segment s: out row n at dst + n*ldout + k  (ldout enables row interleaving).
__global__ __launch_bounds__(256)
void transpose_cvt3(const float* __restrict__ s0, bf16* __restrict__ d0, int N0, int L0,
                    const float* __restrict__ s1, bf16* __restrict__ d1, int N1, int L1,
                    const float* __restrict__ s2, bf16* __restrict__ d2, int N2, int L2,
                    int K)
{
  const float* src; bf16* dst; int N, L;
  if (blockIdx.z == 0)      { src = s0; dst = d0; N = N0; L = L0; }
  else if (blockIdx.z == 1) { src = s1; dst = d1; N = N1; L = L1; }
  else                      { src = s2; dst = d2; N = N2; L = L2; }
  if (!src) return;
  const int n0 = (int)blockIdx.x * 32; if (n0 >= N) return;
  const int k0 = (int)blockIdx.y * 32;
  __shared__ float t[32][33];
  const int tr = (int)threadIdx.x >> 3;
  const int tc = ((int)threadIdx.x & 7) * 4;
  f32x4 v = *(const f32x4*)(src + (long)(k0 + tr) * N + n0 + tc);
  t[tr][tc] = v[0]; t[tr][tc + 1] = v[1]; t[tr][tc + 2] = v[2]; t[tr][tc + 3] = v[3];
  __syncthreads();
  bf16x4 b = { (bf16)t[tc][tr], (bf16)t[tc + 1][tr], (bf16)t[tc + 2][tr], (bf16)t[tc + 3][tr] };
  *(bf16x4*)(dst + (long)(n0 + tr) * L + k0 + tc) = b;
}

__global__ __launch_bounds__(256)
void cvt_bf16_kernel(const float* __restrict__ in, bf16* __restrict__ out, int nvec)
{
  const int i = (int)(blockIdx.x * 256 + threadIdx.x);
  if (i < nvec) {
    f32x4 v = ((const f32x4*)in)[i];
    bf16x4 b = { (bf16)v[0], (bf16)v[1], (bf16)v[2], (bf16)v[3] };
    ((bf16x4*)out)[i] = b;
  }
}

__global__ __launch_bounds__(256)
void rmsnorm_kernel(bf16* __restrict__ out, const float* __restrict__ in, const float* __restrict__ g)
{
  const int row = (int)blockIdx.x;
  const float* x = in + (long)row * DMODEL;
  bf16* o = out + (long)row * DMODEL;
  const int tid = (int)threadIdx.x;
  f32x4 v0 = *(const f32x4*)(x + tid * 4);
  f32x4 v1 = *(const f32x4*)(x + tid * 4 + 1024);
  float ss = v0[0]*v0[0] + v0[1]*v0[1] + v0[2]*v0[2] + v0[3]*v0[3]
           + v1[0]*v1[0] + v1[1]*v1[1] + v1[2]*v1[2] + v1[3]*v1[3];
  #pragma unroll
  for (int o_ = 32; o_; o_ >>= 1) ss += __shfl_xor(ss, o_);
  __shared__ float sm[4];
  if ((tid & 63) == 0) sm[tid >> 6] = ss;
  __syncthreads();
  ss = sm[0] + sm[1] + sm[2] + sm[3];
  const float r = 1.0f / sqrtf(ss * (1.0f / DMODEL) + EPSV);
  f32x4 g0 = *(const f32x4*)(g + tid * 4);
  f32x4 g1 = *(const f32x4*)(g + tid * 4 + 1024);
  bf16x4 o0, o1;
  #pragma unroll
  for (int j = 0; j < 4; ++j) { o0[j] = (bf16)(v0[j] * r * g0[j]); o1[j] = (bf16)(v1[j] * r * g1[j]); }
  *(bf16x4*)(o + tid * 4) = o0;
  *(bf16x4*)(o + tid * 4 + 1024) = o1;
}

__global__ void rope_tables(float* cosT, float* sinT)
{
  const int s = (int)blockIdx.x;
  const int i = (int)threadIdx.x;
  const double inv = pow(10000.0, -(double)i / 64.0);
  const double f = (double)s * inv;
  cosT[s * 64 + i] = (float)cos(f);
  sinT[s * 64 + i] = (float)sin(f);
}

// rope for q (blocks 0..8191) and k (blocks 8192..10239) in one dispatch.
// q needs SQ*NHEAD*64/256 = 8192 blocks; k needs SQ*NKV*64/256 = 2048.
__global__ __launch_bounds__(256)
void rope_both(bf16* __restrict__ qb, bf16* __restrict__ kb,
               const float* __restrict__ cosT, const float* __restrict__ sinT)
{
  const int blk = (int)blockIdx.x;
  bf16* buf; int nh, stride, t;
  if (blk < 8192) { buf = qb; nh = NHEAD; stride = DMODEL; t = blk * 256 + (int)threadIdx.x; }
  else            { buf = kb; nh = NKV;   stride = 512;    t = (blk - 8192) * 256 + (int)threadIdx.x; }
  const int per = nh * 64;
  const int s = t / per;
  const int r = t - s * per;
  const int h = r >> 6;
  const int i = r & 63;
  bf16* b = buf + (long)s * stride + h * HDIM;
  const float c  = cosT[s * 64 + i];
  const float sn = sinT[s * 64 + i];
  const float x1 = (float)b[i];
  const float x2 = (float)b[64 + i];
  b[i]      = (bf16)(x1 * c - x2 * sn);
  b[64 + i] = (bf16)(x2 * c + x1 * sn);
}

__global__ __launch_bounds__(256)
void embed_gather(f32x4* x, const f32x4* embed, const int* idx)
{
  const int t = (int)(blockIdx.x * 256 + threadIdx.x);
  const int s = t >> 9;
  const int c = t & 511;
  x[t] = embed[(long)idx[s] * 512 + c];
}

extern "C" void kernel_launch(void* const* d_in, const int* in_sizes, int n_in,
                              void* d_out, int out_size, void* d_ws, size_t ws_size,
                              hipStream_t stream)
{
  (void)in_sizes; (void)n_in; (void)out_size;
  const int*   idx   = (const int*)  d_in[0];
  const float* embed = (const float*)d_in[1];
  const float* wq    = (const float*)d_in[2];
  const float* wk    = (const float*)d_in[3];
  const float* wv    = (const float*)d_in[4];
  const float* wo    = (const float*)d_in[5];
  const float* ln1g  = (const float*)d_in[6];
  const float* ln2g  = (const float*)d_in[7];
  const float* wgate = (const float*)d_in[8];
  const float* wup   = (const float*)d_in[9];
  const float* wdown = (const float*)d_in[10];
  const float* fing  = (const float*)d_in[11];
  const float* lmh   = (const float*)d_in[12];
  float* out = (float*)d_out;

  char* wp = (char*)d_ws;
  auto alloc = [&](size_t bytes) { char* p = wp; wp += (bytes + 255) & ~(size_t)255; return p; };
  float* cosT   = (float*)alloc((size_t)SQ * 64 * 4);
  float* sinT   = (float*)alloc((size_t)SQ * 64 * 4);
  float* suffPc = (float*)alloc((size_t)NKV * 16 * 128 * 4);
  float* x      = (float*)alloc((size_t)SQ * DMODEL * 4);
  bf16*  h      = (bf16*) alloc((size_t)SQ * DMODEL * 2);
  bf16*  qb     = (bf16*) alloc((size_t)SQ * DMODEL * 2);
  bf16*  kb     = (bf16*) alloc((size_t)SQ * 512 * 2);
  bf16*  vT     = (bf16*) alloc((size_t)512 * SQ * 2);
  bf16*  ffb    = (bf16*) alloc((size_t)SQ * FFDIM * 2);
  size_t used  = (size_t)(wp - (char*)d_ws);
  bf16*  wbuf  = (bf16*)wp;                 // weight scratch (gate+up interleaved: 46 MB)
  size_t avail = ws_size - used;

  bf16* yb = qb;                            // flash writes y over q (same rows per block)
  const float scale = 0.08838834764831845f;

  rope_tables<<<SQ, 64, 0, stream>>>(cosT, sinT);
  embed_gather<<<(SQ * 512) / 256, 256, 0, stream>>>((f32x4*)x, (const f32x4*)embed, idx);

  for (int l = 0; l < NLAYER; ++l) {
    const float* lwq = wq    + (long)l * DMODEL * DMODEL;
    const float* lwk = wk    + (long)l * DMODEL * 512;
    const float* lwv = wv    + (long)l * DMODEL * 512;
    const float* lwo = wo    + (long)l * DMODEL * DMODEL;
    const float* lwg = wgate + (long)l * DMODEL * FFDIM;
    const float* lwu = wup   + (long)l * DMODEL * FFDIM;
    const float* lwd = wdown + (long)l * FFDIM * DMODEL;

    rmsnorm_kernel<<<SQ, 256, 0, stream>>>(h, x, ln1g + l * DMODEL);

    // fused QKV weight cvt: [wq^T | wk^T | wv^T] -> wbuf (3072 x 2048)
    transpose_cvt3<<<dim3(64, 64, 3), 256, 0, stream>>>(
        lwq, wbuf, DMODEL, DMODEL,
        lwk, wbuf + (long)2048 * DMODEL, 512, DMODEL,
        lwv, wbuf + (long)2560 * DMODEL, 512, DMODEL, DMODEL);
    gemm128<EP_QKV, 2><<<dim3(16, 24), 256, 0, stream>>>(
        h, wbuf, qb, nullptr, kb, vT, DMODEL, DMODEL, DMODEL, 0);

    vsuffix<<<NKV, 128, 0, stream>>>(vT, suffPc);
    rope_both<<<8192 + 2048, 256, 0, stream>>>(qb, kb, cosT, sinT);

    flash_attn<<<dim3(16, NHEAD), 256, 0, stream>>>(qb, kb, vT, suffPc, yb, scale);

    transpose_cvt3<<<dim3(64, 64, 1), 256, 0, stream>>>(
        lwo, wbuf, DMODEL, DMODEL,
        nullptr, nullptr, 0, 0, nullptr, nullptr, 0, 0, DMODEL);
    gemm128<EP_ADD, 3><<<dim3(16, 16), 256, 0, stream>>>(
        yb, wbuf, x, x, nullptr, nullptr, DMODEL, DMODEL, DMODEL, DMODEL);

    rmsnorm_kernel<<<SQ, 256, 0, stream>>>(h, x, ln2g + l * DMODEL);

    // gate+up interleaved: even rows = wg^T, odd rows = wu^T (11264 x 2048)
    transpose_cvt3<<<dim3(176, 64, 2), 256, 0, stream>>>(
        lwg, wbuf, FFDIM, 2 * DMODEL,
        lwu, wbuf + DMODEL, FFDIM, 2 * DMODEL,
        nullptr, nullptr, 0, 0, DMODEL);
    gemm256<EP_GLU><<<dim3(8, 44), 512, 0, stream>>>(
        h, wbuf, ffb, nullptr, DMODEL, DMODEL, DMODEL, FFDIM);

    // down: A = ffb [2048][5632]
    transpose_cvt3<<<dim3(64, 176, 1), 256, 0, stream>>>(
        lwd, wbuf, DMODEL, FFDIM,
        nullptr, nullptr, 0, 0, nullptr, nullptr, 0, 0, FFDIM);
    gemm128<EP_ADD, 3><<<dim3(16, 16), 256, 0, stream>>>(
        ffb, wbuf, x, x, nullptr, nullptr, FFDIM, FFDIM, FFDIM, DMODEL);
  }

  rmsnorm_kernel<<<SQ, 256, 0, stream>>>(h, x, fing);

  long chunkRows = (long)(avail / ((size_t)DMODEL * 2)) & ~255L;
  if (chunkRows > VOCAB) chunkRows = VOCAB;
  for (long c0 = 0; c0 < VOCAB; c0 += chunkRows) {
    const long rows = (VOCAB - c0 < chunkRows) ? (VOCAB - c0) : chunkRows;
    const int  nvec = (int)(rows * DMODEL / 4);
    cvt_bf16_kernel<<<(nvec + 255) / 256, 256, 0, stream>>>(lmh + c0 * DMODEL, wbuf, nvec);
    gemm256<EP_STOREF><<<dim3(8, (int)(rows / 256)), 512, 0, stream>>>(
        h, wbuf, out + c0, nullptr, DMODEL, DMODEL, DMODEL, VOCAB);
  }
}

// Round 8
// 1233.909 us; speedup vs baseline: 2.3409x; 1.0690x over previous
//
#include <hip/hip_runtime.h>

#define SQ     2048
#define DMODEL 2048
#define NHEAD  16
#define NKV    4
#define HDIM   128
#define FFDIM  5632
#define VOCAB  32000
#define NLAYER 2
#define EPSV   1e-5f

typedef __bf16 bf16;
typedef __bf16 bf16x4 __attribute__((ext_vector_type(4)));
typedef __bf16 bf16x8 __attribute__((ext_vector_type(8)));
typedef float  f32x4  __attribute__((ext_vector_type(4)));

enum { EP_STOREF = 0, EP_ADD = 2, EP_STOREB = 3, EP_QKV = 6, EP_GLU = 7 };

// global -> LDS direct DMA, 16B per lane; LDS dest = wave-uniform base + lane*16
#define GLD(gp, lp) __builtin_amdgcn_global_load_lds( \
    (const __attribute__((address_space(1))) void*)(gp), \
    (__attribute__((address_space(3))) void*)(lp), 16, 0, 0)

#define MFMA16(a, b, c) __builtin_amdgcn_mfma_f32_16x16x32_bf16(a, b, c, 0, 0, 0)

#define FENCE() __builtin_amdgcn_sched_barrier(0)
#define PH_BAR() do { FENCE(); __builtin_amdgcn_s_barrier(); FENCE(); } while (0)

// XCD-bijective swizzle + m-fastest decode (m204)
#define XCD_SWZ(TM)                                                        \
  const int GM  = (int)gridDim.x;                                          \
  const int nwg = GM * (int)gridDim.y;                                     \
  const int bid = (int)blockIdx.y * GM + (int)blockIdx.x;                  \
  const int q8  = nwg >> 3, r8 = nwg & 7;                                  \
  const int xcd = bid & 7, rnk = bid >> 3;                                 \
  const int swz = ((xcd < r8) ? xcd * (q8 + 1)                             \
                              : r8 * (q8 + 1) + (xcd - r8) * q8) + rnk;    \
  const int m0  = (swz % GM) * (TM);                                       \
  const int n0  = (swz / GM) * (TM == 256 ? 256 : 128);

// ============================================================================
// 128x128-tile, BK=64, 4-wave, prefetching pipelined GEMM.
// NBUF=2: 1-tile-deep prefetch, 64KB LDS, 2 blocks/CU (grids > 256 blocks).
// NBUF=3: 2-tile-deep prefetch, 96KB LDS (exactly-256-block grids).
// EP_GLU: B rows interleaved (even=gate, odd=up); epilogue pairs adjacent
// columns via shfl_xor(1); even lanes write silu(up)*gate bf16 at col gc/2.
// ============================================================================
template<int EPI, int NBUF>
__global__ __launch_bounds__(256, NBUF == 2 ? 2 : 1)
void gemm128(const bf16* __restrict__ A, const bf16* __restrict__ B,
             void* __restrict__ C, const void* __restrict__ Cin,
             bf16* __restrict__ C2, bf16* __restrict__ C3,
             int K, int lda, int ldb, int ldc)
{
  __shared__ bf16 As[NBUF][128 * 64];
  __shared__ bf16 Bs[NBUF][128 * 64];

  const int tid  = (int)threadIdx.x;
  const int lane = tid & 63;
  const int wave = tid >> 6;
  const int wm   = wave >> 1, wn = wave & 1;

  XCD_SWZ(128)

  const int nkt  = K >> 6;
  const int srow = lane >> 3;
  const long sxcol = (long)(((lane & 7) ^ (lane >> 3)) * 8);
  const int colc = lane & 15;
  const int g4   = lane >> 4;

  auto stage = [&](int t, int buf) {
    if (t < nkt) {
      const long kc = (long)t * 64 + sxcol;
      bf16* dA = As[buf];
      bf16* dB = Bs[buf];
      #pragma unroll
      for (int c = 0; c < 4; ++c) {
        const int chunk = wave * 4 + c;       // 16 chunks of 8 rows x 64 cols
        const int row   = chunk * 8 + srow;
        GLD(A + (long)(m0 + row) * lda + kc, dA + chunk * 512);
        GLD(B + (long)(n0 + row) * ldb + kc, dB + chunk * 512);
      }
    }
  };

  stage(0, 0);
  if (NBUF == 3) stage(1, 1);

  f32x4 acc[4][4] = {};
  int wb = (NBUF == 3) ? 2 : 1;               // buffer for next stage
  int rb = 0;                                 // buffer being read

  for (int t = 0; t < nkt; ++t) {
    if (NBUF == 2) {
      stage(t + 1, wb);
      wb ^= 1;
      FENCE();
      if (t + 1 < nkt) asm volatile("s_waitcnt vmcnt(8)" ::: "memory");
      else             asm volatile("s_waitcnt vmcnt(0)" ::: "memory");
    } else {
      stage(t + 2, wb);
      wb = (wb == 2) ? 0 : wb + 1;
      FENCE();
      if (t + 2 < nkt)      asm volatile("s_waitcnt vmcnt(16)" ::: "memory");
      else if (t + 1 < nkt) asm volatile("s_waitcnt vmcnt(8)"  ::: "memory");
      else                  asm volatile("s_waitcnt vmcnt(0)"  ::: "memory");
    }
    PH_BAR();
    const char* Ab = (const char*)As[rb];
    const char* Bb = (const char*)Bs[rb];
    rb = (NBUF == 2) ? (rb ^ 1) : ((rb == 2) ? 0 : rb + 1);
    #pragma unroll
    for (int kk = 0; kk < 2; ++kk) {
      bf16x8 af[4], bv[4];
      #pragma unroll
      for (int m = 0; m < 4; ++m) {
        const int r = wm * 64 + m * 16 + colc;
        af[m] = *(const bf16x8*)(Ab + r * 128 + (((kk * 4 + g4) ^ (r & 7)) * 16));
      }
      #pragma unroll
      for (int n = 0; n < 4; ++n) {
        const int r = wn * 64 + n * 16 + colc;
        bv[n] = *(const bf16x8*)(Bb + r * 128 + (((kk * 4 + g4) ^ (r & 7)) * 16));
      }
      #pragma unroll
      for (int m = 0; m < 4; ++m)
        #pragma unroll
        for (int n = 0; n < 4; ++n)
          acc[m][n] = MFMA16(af[m], bv[n], acc[m][n]);
    }
    PH_BAR();
  }

  // epilogue. C/D frag: col = lane&15, row = (lane>>4)*4 + reg
  #pragma unroll
  for (int m = 0; m < 4; ++m) {
    const int gr0 = m0 + wm * 64 + m * 16 + g4 * 4;
    #pragma unroll
    for (int n = 0; n < 4; ++n) {
      const int gc = n0 + wn * 64 + n * 16 + colc;
      if (EPI == EP_QKV) {
        if (n0 < 2048) {
          #pragma unroll
          for (int r = 0; r < 4; ++r)
            ((bf16*)C)[(long)(gr0 + r) * DMODEL + gc] = (bf16)acc[m][n][r];
        } else if (n0 < 2560) {
          #pragma unroll
          for (int r = 0; r < 4; ++r)
            C2[(long)(gr0 + r) * 512 + (gc - 2048)] = (bf16)acc[m][n][r];
        } else {
          bf16x4 pk = { (bf16)acc[m][n][0], (bf16)acc[m][n][1],
                        (bf16)acc[m][n][2], (bf16)acc[m][n][3] };
          *(bf16x4*)(C3 + (long)(gc - 2560) * SQ + gr0) = pk;
        }
      } else if (EPI == EP_GLU) {
        #pragma unroll
        for (int r = 0; r < 4; ++r) {
          const float v = acc[m][n][r];
          const float o = __shfl_xor(v, 1);    // partner column's value
          if ((colc & 1) == 0) {               // even col lane: v=gate, o=up
            const float res = (o / (1.0f + __expf(-o))) * v;
            ((bf16*)C)[(long)(gr0 + r) * ldc + (gc >> 1)] = (bf16)res;
          }
        }
      } else {
        #pragma unroll
        for (int r = 0; r < 4; ++r) {
          const long off = (long)(gr0 + r) * ldc + gc;
          const float v = acc[m][n][r];
          if (EPI == EP_STOREF)      ((float*)C)[off] = v;
          else if (EPI == EP_ADD)    ((float*)C)[off] = ((const float*)Cin)[off] + v;
          else if (EPI == EP_STOREB) ((bf16*)C)[off] = (bf16)v;
        }
      }
    }
  }
}

// ============================================================================
// 256x256-tile, BK=64, 8-wave, 4-phase/K-tile pipelined GEMM (T2+T3+T4+T5).
// ============================================================================
template<int EPI>
__global__ __launch_bounds__(512, 2)
void gemm256(const bf16* __restrict__ A, const bf16* __restrict__ B,
             void* __restrict__ C, const void* __restrict__ Cin,
             int K, int lda, int ldb, int ldc)
{
  __shared__ bf16 smem[2][4][128 * 64];   // 128 KiB

  const int tid  = (int)threadIdx.x;
  const int lane = tid & 63;
  const int wave = tid >> 6;
  const int wm   = wave >> 2;
  const int wn   = wave & 3;

  XCD_SWZ(256)

  const int nkt  = K >> 6;
  const int srow = lane >> 3;
  const long sxcol = (long)(((lane & 7) ^ (lane >> 3)) * 8);
  const int frow = lane & 15;
  const int ph0  = ((     (lane >> 4)) ^ (lane & 7)) * 16;
  const int ph1  = ((4 + (lane >> 4)) ^ (lane & 7)) * 16;

  auto stageA = [&](int tile, int half) {
    if (tile < nkt) {
      const long kc = (long)tile * 64 + sxcol;
      #pragma unroll
      for (int i = 0; i < 2; ++i)
        GLD(A + (long)(m0 + half * 128 + wave * 16 + i * 8 + srow) * lda + kc,
            smem[tile & 1][half] + (wave * 16 + i * 8) * 64);
    }
  };
  auto stageB = [&](int tile, int half) {
    if (tile < nkt) {
      const long kc = (long)tile * 64 + sxcol;
      #pragma unroll
      for (int i = 0; i < 2; ++i)
        GLD(B + (long)(n0 + half * 128 + wave * 16 + i * 8 + srow) * ldb + kc,
            smem[tile & 1][2 + half] + (wave * 16 + i * 8) * 64);
    }
  };

  stageB(0, 0); stageB(0, 1); stageA(0, 0); stageA(0, 1);
  asm volatile("s_waitcnt vmcnt(4)" ::: "memory");
  stageB(1, 0); stageB(1, 1); stageA(1, 0);
  asm volatile("s_waitcnt vmcnt(6)" ::: "memory");
  PH_BAR();

  f32x4 acc[8][4] = {};

  for (int t = 0; t < nkt; ++t) {
    const int bsel = t & 1;
    const char* Asl = (const char*)smem[bsel][wm];
    const char* Bsl = (const char*)smem[bsel][2 + (wn >> 1)];
    const int brow = (wn & 1) * 64;

    bf16x8 ar[4][2], b0f[2][2], b1f[2][2];

    #pragma unroll
    for (int mr = 0; mr < 4; ++mr) {
      ar[mr][0] = *(const bf16x8*)(Asl + (mr * 16 + frow) * 128 + ph0);
      ar[mr][1] = *(const bf16x8*)(Asl + (mr * 16 + frow) * 128 + ph1);
    }
    #pragma unroll
    for (int nc = 0; nc < 2; ++nc) {
      b0f[nc][0] = *(const bf16x8*)(Bsl + (brow + nc * 16 + frow) * 128 + ph0);
      b0f[nc][1] = *(const bf16x8*)(Bsl + (brow + nc * 16 + frow) * 128 + ph1);
    }
    stageA(t + 1, 1);
    PH_BAR();
    __builtin_amdgcn_s_setprio(1);
    #pragma unroll
    for (int mr = 0; mr < 4; ++mr)
      #pragma unroll
      for (int nc = 0; nc < 2; ++nc) {
        acc[mr][nc] = MFMA16(ar[mr][0], b0f[nc][0], acc[mr][nc]);
        acc[mr][nc] = MFMA16(ar[mr][1], b0f[nc][1], acc[mr][nc]);
      }
    __builtin_amdgcn_s_setprio(0);
    PH_BAR();

    #pragma unroll
    for (int nc = 0; nc < 2; ++nc) {
      b1f[nc][0] = *(const bf16x8*)(Bsl + (brow + (2 + nc) * 16 + frow) * 128 + ph0);
      b1f[nc][1] = *(const bf16x8*)(Bsl + (brow + (2 + nc) * 16 + frow) * 128 + ph1);
    }
    PH_BAR();
    __builtin_amdgcn_s_setprio(1);
    #pragma unroll
    for (int mr = 0; mr < 4; ++mr)
      #pragma unroll
      for (int nc = 0; nc < 2; ++nc) {
        acc[mr][2 + nc] = MFMA16(ar[mr][0], b1f[nc][0], acc[mr][2 + nc]);
        acc[mr][2 + nc] = MFMA16(ar[mr][1], b1f[nc][1], acc[mr][2 + nc]);
      }
    __builtin_amdgcn_s_setprio(0);
    PH_BAR();

    #pragma unroll
    for (int mr = 0; mr < 4; ++mr) {
      ar[mr][0] = *(const bf16x8*)(Asl + ((4 + mr) * 16 + frow) * 128 + ph0);
      ar[mr][1] = *(const bf16x8*)(Asl + ((4 + mr) * 16 + frow) * 128 + ph1);
    }
    stageB(t + 2, 0); stageB(t + 2, 1);
    PH_BAR();
    __builtin_amdgcn_s_setprio(1);
    #pragma unroll
    for (int mr = 0; mr < 4; ++mr)
      #pragma unroll
      for (int nc = 0; nc < 2; ++nc) {
        acc[4 + mr][nc] = MFMA16(ar[mr][0], b0f[nc][0], acc[4 + mr][nc]);
        acc[4 + mr][nc] = MFMA16(ar[mr][1], b0f[nc][1], acc[4 + mr][nc]);
      }
    __builtin_amdgcn_s_setprio(0);
    PH_BAR();

    stageA(t + 2, 0);
    PH_BAR();
    __builtin_amdgcn_s_setprio(1);
    #pragma unroll
    for (int mr = 0; mr < 4; ++mr)
      #pragma unroll
      for (int nc = 0; nc < 2; ++nc) {
        acc[4 + mr][2 + nc] = MFMA16(ar[mr][0], b1f[nc][0], acc[4 + mr][2 + nc]);
        acc[4 + mr][2 + nc] = MFMA16(ar[mr][1], b1f[nc][1], acc[4 + mr][2 + nc]);
      }
    __builtin_amdgcn_s_setprio(0);
    FENCE();
    if (t + 2 < nkt) asm volatile("s_waitcnt vmcnt(6)" ::: "memory");
    else             asm volatile("s_waitcnt vmcnt(0)" ::: "memory");
    PH_BAR();
  }

  #pragma unroll
  for (int mr = 0; mr < 8; ++mr) {
    const int gr0 = m0 + wm * 128 + mr * 16 + (lane >> 4) * 4;
    #pragma unroll
    for (int nc = 0; nc < 4; ++nc) {
      const int gc = n0 + wn * 64 + nc * 16 + (lane & 15);
      #pragma unroll
      for (int r = 0; r < 4; ++r) {
        const long off = (long)(gr0 + r) * ldc + gc;
        const float v = acc[mr][nc][r];
        if (EPI == EP_STOREF)      ((float*)C)[off] = v;
        else if (EPI == EP_STOREB) ((bf16*)C)[off] = (bf16)v;
      }
    }
  }
}

// ============================================================================
// Fused flash-style attention (mask-before-softmax, fixed-shift M=0 algebra)
// ============================================================================
__global__ __launch_bounds__(256, 1)
void flash_attn(const bf16* __restrict__ qb, const bf16* __restrict__ kb,
                const bf16* __restrict__ vT, const float* __restrict__ suffPc,
                bf16* __restrict__ yb, float scale)
{
  __shared__ bf16 Ks[128 * 128];
  __shared__ bf16 Vs[128 * 128];
  __shared__ bf16 Ps[128 * 136];

  const int tid  = (int)threadIdx.x;
  const int lane = tid & 63;
  const int w    = tid >> 6;
  const int qt   = (int)blockIdx.x;
  const int h    = (int)blockIdx.y;
  const int kvh  = h >> 2;

  const int l15 = lane & 15;
  const int g4  = lane >> 4;

  bf16x8 qf[2][4];
  #pragma unroll
  for (int m = 0; m < 2; ++m)
    #pragma unroll
    for (int ks = 0; ks < 4; ++ks)
      qf[m][ks] = *(const bf16x8*)(qb + (long)(qt * 128 + w * 32 + m * 16 + l15) * DMODEL
                                   + h * HDIM + ks * 32 + g4 * 8);

  f32x4 acc_o[2][8] = {};
  float den[2][4] = {};

  const bf16* Kg = kb + (long)kvh * HDIM;
  const bf16* Vg = vT + (long)(kvh * HDIM) * SQ;

  for (int j = 0; j <= qt; ++j) {
    const bool diag = (j == qt);
    PH_BAR();

    #pragma unroll
    for (int i = 0; i < 8; ++i) {
      const int rb = w * 32 + i * 4;
      const int r  = rb + g4;
      GLD(Kg + (long)(j * 128 + r) * 512 + ((l15 ^ (r & 7)) * 8), Ks + rb * 128);
    }
    #pragma unroll
    for (int i = 0; i < 8; ++i) {
      const int rb = w * 32 + i * 4;
      const int r  = rb + g4;
      GLD(Vg + (long)r * SQ + j * 128 + ((l15 ^ (r & 7)) * 8), Vs + rb * 128);
    }
    asm volatile("s_waitcnt vmcnt(8)" ::: "memory");
    PH_BAR();

    f32x4 acc_s[2][8] = {};
    #pragma unroll
    for (int ks = 0; ks < 4; ++ks) {
      bf16x8 kf[8];
      #pragma unroll
      for (int n = 0; n < 8; ++n) {
        const int kr = n * 16 + l15;
        kf[n] = *(const bf16x8*)((const char*)Ks + kr * 256 + (((ks * 4 + g4) ^ (kr & 7)) * 16));
      }
      #pragma unroll
      for (int m = 0; m < 2; ++m)
        #pragma unroll
        for (int n = 0; n < 8; ++n)
          acc_s[m][n] = MFMA16(qf[m][ks], kf[n], acc_s[m][n]);
    }

    float rs[2][4] = {};
    #pragma unroll
    for (int m = 0; m < 2; ++m)
      #pragma unroll
      for (int n = 0; n < 8; ++n) {
        const int kc = n * 16 + l15;
        #pragma unroll
        for (int r = 0; r < 4; ++r) {
          const int qlr = w * 32 + m * 16 + g4 * 4 + r;
          float p = __expf(acc_s[m][n][r] * scale);
          if (diag && kc > qlr) p = 1.0f;
          rs[m][r] += p;
          Ps[(w * 32 + m * 16 + g4 * 4 + r) * 136 + kc] = (bf16)p;
        }
      }
    #pragma unroll
    for (int m = 0; m < 2; ++m)
      #pragma unroll
      for (int r = 0; r < 4; ++r) {
        float v = rs[m][r];
        v += __shfl_xor(v, 1); v += __shfl_xor(v, 2);
        v += __shfl_xor(v, 4); v += __shfl_xor(v, 8);
        den[m][r] += v;
      }

    asm volatile("s_waitcnt vmcnt(0) lgkmcnt(0)" ::: "memory");
    PH_BAR();

    #pragma unroll
    for (int ks = 0; ks < 4; ++ks) {
      bf16x8 pa[2], vf[8];
      #pragma unroll
      for (int m = 0; m < 2; ++m)
        pa[m] = *(const bf16x8*)((const char*)Ps + (w * 32 + m * 16 + l15) * 272
                                 + ks * 64 + g4 * 16);
      #pragma unroll
      for (int n = 0; n < 8; ++n) {
        const int dr = n * 16 + l15;
        vf[n] = *(const bf16x8*)((const char*)Vs + dr * 256 + (((ks * 4 + g4) ^ (dr & 7)) * 16));
      }
      #pragma unroll
      for (int m = 0; m < 2; ++m)
        #pragma unroll
        for (int n = 0; n < 8; ++n)
          acc_o[m][n] = MFMA16(pa[m], vf[n], acc_o[m][n]);
    }
  }

  float denf[2][4];
  #pragma unroll
  for (int m = 0; m < 2; ++m)
    #pragma unroll
    for (int r = 0; r < 4; ++r)
      denf[m][r] = den[m][r] + 128.0f * (15 - qt);

  #pragma unroll
  for (int n = 0; n < 8; ++n) {
    const float t = suffPc[((kvh << 4) + qt) * 128 + n * 16 + l15];
    #pragma unroll
    for (int m = 0; m < 2; ++m)
      #pragma unroll
      for (int r = 0; r < 4; ++r) {
        const float y = (acc_o[m][n][r] + t) / denf[m][r];
        yb[(long)(qt * 128 + w * 32 + m * 16 + g4 * 4 + r) * DMODEL
           + h * HDIM + n * 16 + l15] = (bf16)y;
      }
  }
}

// chunk column sums: chunkS[kvh][c][d] = sum_{s in chunk c} V[s][d]
__global__ __launch_bounds__(128)
void vchunksum(const bf16* __restrict__ vT, float* __restrict__ chunkS)
{
  const int kvh = (int)blockIdx.x;
  const int c   = (int)blockIdx.y;
  const int d   = (int)threadIdx.x;
  const bf16* row = vT + (long)(kvh * HDIM + d) * SQ + c * 128;
  float s = 0.f;
  #pragma unroll
  for (int r = 0; r < 16; ++r) {
    bf16x8 v = *(const bf16x8*)(row + r * 8);
    #pragma unroll
    for (int e = 0; e < 8; ++e) s += (float)v[e];
  }
  chunkS[(kvh * 16 + c) * 128 + d] = s;
}

// suffix scan over the 16 chunk sums
__global__ __launch_bounds__(128)
void vsuffscan(const float* __restrict__ chunkS, float* __restrict__ suffPc)
{
  const int kvh = (int)blockIdx.x;
  const int d   = (int)threadIdx.x;
  float a = 0.f;
  for (int c = 15; c >= 0; --c) {
    suffPc[(kvh * 16 + c) * 128 + d] = a;
    a += chunkS[(kvh * 16 + c) * 128 + d];
  }
}

// fp32 [K][N] -> bf16 transpose+convert, up to 3 segments (z-indexed).
__global__ __launch_bounds__(256)
void transpose_cvt3(const float* __restrict__ s0, bf16* __restrict__ d0, int N0, int L0,
                    const float* __restrict__ s1, bf16* __restrict__ d1, int N1, int L1,
                    const float* __restrict__ s2, bf16* __restrict__ d2, int N2, int L2,
                    int K)
{
  const float* src; bf16* dst; int N, L;
  if (blockIdx.z == 0)      { src = s0; dst = d0; N = N0; L = L0; }
  else if (blockIdx.z == 1) { src = s1; dst = d1; N = N1; L = L1; }
  else                      { src = s2; dst = d2; N = N2; L = L2; }
  if (!src) return;
  const int n0 = (int)blockIdx.x * 32; if (n0 >= N) return;
  const int k0 = (int)blockIdx.y * 32;
  __shared__ float t[32][33];
  const int tr = (int)threadIdx.x >> 3;
  const int tc = ((int)threadIdx.x & 7) * 4;
  f32x4 v = *(const f32x4*)(src + (long)(k0 + tr) * N + n0 + tc);
  t[tr][tc] = v[0]; t[tr][tc + 1] = v[1]; t[tr][tc + 2] = v[2]; t[tr][tc + 3] = v[3];
  __syncthreads();
  bf16x4 b = { (bf16)t[tc][tr], (bf16)t[tc + 1][tr], (bf16)t[tc + 2][tr], (bf16)t[tc + 3][tr] };
  *(bf16x4*)(dst + (long)(n0 + tr) * L + k0 + tc) = b;
}

__global__ __launch_bounds__(256)
void cvt_bf16_kernel(const float* __restrict__ in, bf16* __restrict__ out, int nvec)
{
  const int i = (int)(blockIdx.x * 256 + threadIdx.x);
  if (i < nvec) {
    f32x4 v = ((const f32x4*)in)[i];
    bf16x4 b = { (bf16)v[0], (bf16)v[1], (bf16)v[2], (bf16)v[3] };
    ((bf16x4*)out)[i] = b;
  }
}

__global__ __launch_bounds__(256)
void rmsnorm_kernel(bf16* __restrict__ out, const float* __restrict__ in, const float* __restrict__ g)
{
  const int row = (int)blockIdx.x;
  const float* x = in + (long)row * DMODEL;
  bf16* o = out + (long)row * DMODEL;
  const int tid = (int)threadIdx.x;
  f32x4 v0 = *(const f32x4*)(x + tid * 4);
  f32x4 v1 = *(const f32x4*)(x + tid * 4 + 1024);
  float ss = v0[0]*v0[0] + v0[1]*v0[1] + v0[2]*v0[2] + v0[3]*v0[3]
           + v1[0]*v1[0] + v1[1]*v1[1] + v1[2]*v1[2] + v1[3]*v1[3];
  #pragma unroll
  for (int o_ = 32; o_; o_ >>= 1) ss += __shfl_xor(ss, o_);
  __shared__ float sm[4];
  if ((tid & 63) == 0) sm[tid >> 6] = ss;
  __syncthreads();
  ss = sm[0] + sm[1] + sm[2] + sm[3];
  const float r = 1.0f / sqrtf(ss * (1.0f / DMODEL) + EPSV);
  f32x4 g0 = *(const f32x4*)(g + tid * 4);
  f32x4 g1 = *(const f32x4*)(g + tid * 4 + 1024);
  bf16x4 o0, o1;
  #pragma unroll
  for (int j = 0; j < 4; ++j) { o0[j] = (bf16)(v0[j] * r * g0[j]); o1[j] = (bf16)(v1[j] * r * g1[j]); }
  *(bf16x4*)(o + tid * 4) = o0;
  *(bf16x4*)(o + tid * 4 + 1024) = o1;
}

__global__ void rope_tables(float* cosT, float* sinT)
{
  const int s = (int)blockIdx.x;
  const int i = (int)threadIdx.x;
  const double inv = pow(10000.0, -(double)i / 64.0);
  const double f = (double)s * inv;
  cosT[s * 64 + i] = (float)cos(f);
  sinT[s * 64 + i] = (float)sin(f);
}

// rope for q (blocks 0..8191) and k (blocks 8192..10239) in one dispatch.
__global__ __launch_bounds__(256)
void rope_both(bf16* __restrict__ qb, bf16* __restrict__ kb,
               const float* __restrict__ cosT, const float* __restrict__ sinT)
{
  const int blk = (int)blockIdx.x;
  bf16* buf; int nh, stride, t;
  if (blk < 8192) { buf = qb; nh = NHEAD; stride = DMODEL; t = blk * 256 + (int)threadIdx.x; }
  else            { buf = kb; nh = NKV;   stride = 512;    t = (blk - 8192) * 256 + (int)threadIdx.x; }
  const int per = nh * 64;
  const int s = t / per;
  const int r = t - s * per;
  const int h = r >> 6;
  const int i = r & 63;
  bf16* b = buf + (long)s * stride + h * HDIM;
  const float c  = cosT[s * 64 + i];
  const float sn = sinT[s * 64 + i];
  const float x1 = (float)b[i];
  const float x2 = (float)b[64 + i];
  b[i]      = (bf16)(x1 * c - x2 * sn);
  b[64 + i] = (bf16)(x2 * c + x1 * sn);
}

__global__ __launch_bounds__(256)
void embed_gather(f32x4* x, const f32x4* embed, const int* idx)
{
  const int t = (int)(blockIdx.x * 256 + threadIdx.x);
  const int s = t >> 9;
  const int c = t & 511;
  x[t] = embed[(long)idx[s] * 512 + c];
}

extern "C" void kernel_launch(void* const* d_in, const int* in_sizes, int n_in,
                              void* d_out, int out_size, void* d_ws, size_t ws_size,
                              hipStream_t stream)
{
  (void)in_sizes; (void)n_in; (void)out_size;
  const int*   idx   = (const int*)  d_in[0];
  const float* embed = (const float*)d_in[1];
  const float* wq    = (const float*)d_in[2];
  const float* wk    = (const float*)d_in[3];
  const float* wv    = (const float*)d_in[4];
  const float* wo    = (const float*)d_in[5];
  const float* ln1g  = (const float*)d_in[6];
  const float* ln2g  = (const float*)d_in[7];
  const float* wgate = (const float*)d_in[8];
  const float* wup   = (const float*)d_in[9];
  const float* wdown = (const float*)d_in[10];
  const float* fing  = (const float*)d_in[11];
  const float* lmh   = (const float*)d_in[12];
  float* out = (float*)d_out;

  char* wp = (char*)d_ws;
  auto alloc = [&](size_t bytes) { char* p = wp; wp += (bytes + 255) & ~(size_t)255; return p; };
  float* cosT   = (float*)alloc((size_t)SQ * 64 * 4);
  float* sinT   = (float*)alloc((size_t)SQ * 64 * 4);
  float* suffPc = (float*)alloc((size_t)NKV * 16 * 128 * 4);
  float* chunkS = (float*)alloc((size_t)NKV * 16 * 128 * 4);
  float* x      = (float*)alloc((size_t)SQ * DMODEL * 4);
  bf16*  h      = (bf16*) alloc((size_t)SQ * DMODEL * 2);
  bf16*  qb     = (bf16*) alloc((size_t)SQ * DMODEL * 2);
  bf16*  kb     = (bf16*) alloc((size_t)SQ * 512 * 2);
  bf16*  vT     = (bf16*) alloc((size_t)512 * SQ * 2);
  bf16*  ffb    = (bf16*) alloc((size_t)SQ * FFDIM * 2);
  size_t used  = (size_t)(wp - (char*)d_ws);
  bf16*  wbuf  = (bf16*)wp;                 // weight scratch (gate+up interleaved: 46 MB)
  size_t avail = ws_size - used;

  bf16* yb = qb;                            // flash writes y over q (same rows per block)
  const float scale = 0.08838834764831845f;

  rope_tables<<<SQ, 64, 0, stream>>>(cosT, sinT);
  embed_gather<<<(SQ * 512) / 256, 256, 0, stream>>>((f32x4*)x, (const f32x4*)embed, idx);

  for (int l = 0; l < NLAYER; ++l) {
    const float* lwq = wq    + (long)l * DMODEL * DMODEL;
    const float* lwk = wk    + (long)l * DMODEL * 512;
    const float* lwv = wv    + (long)l * DMODEL * 512;
    const float* lwo = wo    + (long)l * DMODEL * DMODEL;
    const float* lwg = wgate + (long)l * DMODEL * FFDIM;
    const float* lwu = wup   + (long)l * DMODEL * FFDIM;
    const float* lwd = wdown + (long)l * FFDIM * DMODEL;

    rmsnorm_kernel<<<SQ, 256, 0, stream>>>(h, x, ln1g + l * DMODEL);

    // fused QKV weight cvt: [wq^T | wk^T | wv^T] -> wbuf (3072 x 2048)
    transpose_cvt3<<<dim3(64, 64, 3), 256, 0, stream>>>(
        lwq, wbuf, DMODEL, DMODEL,
        lwk, wbuf + (long)2048 * DMODEL, 512, DMODEL,
        lwv, wbuf + (long)2560 * DMODEL, 512, DMODEL, DMODEL);
    gemm128<EP_QKV, 2><<<dim3(16, 24), 256, 0, stream>>>(
        h, wbuf, qb, nullptr, kb, vT, DMODEL, DMODEL, DMODEL, 0);

    vchunksum<<<dim3(NKV, 16), 128, 0, stream>>>(vT, chunkS);
    vsuffscan<<<NKV, 128, 0, stream>>>(chunkS, suffPc);
    rope_both<<<8192 + 2048, 256, 0, stream>>>(qb, kb, cosT, sinT);

    flash_attn<<<dim3(16, NHEAD), 256, 0, stream>>>(qb, kb, vT, suffPc, yb, scale);

    transpose_cvt3<<<dim3(64, 64, 1), 256, 0, stream>>>(
        lwo, wbuf, DMODEL, DMODEL,
        nullptr, nullptr, 0, 0, nullptr, nullptr, 0, 0, DMODEL);
    gemm128<EP_ADD, 3><<<dim3(16, 16), 256, 0, stream>>>(
        yb, wbuf, x, x, nullptr, nullptr, DMODEL, DMODEL, DMODEL, DMODEL);

    rmsnorm_kernel<<<SQ, 256, 0, stream>>>(h, x, ln2g + l * DMODEL);

    // gate+up interleaved: even rows = wg^T, odd rows = wu^T (11264 x 2048)
    transpose_cvt3<<<dim3(176, 64, 2), 256, 0, stream>>>(
        lwg, wbuf, FFDIM, 2 * DMODEL,
        lwu, wbuf + DMODEL, FFDIM, 2 * DMODEL,
        nullptr, nullptr, 0, 0, DMODEL);
    // GLU on gemm128: grid (16, 88) = 1408 blocks @ 2/CU (tail-efficient)
    gemm128<EP_GLU, 2><<<dim3(16, 88), 256, 0, stream>>>(
        h, wbuf, ffb, nullptr, nullptr, nullptr, DMODEL, DMODEL, DMODEL, FFDIM);

    // down: A = ffb [2048][5632]
    transpose_cvt3<<<dim3(64, 176, 1), 256, 0, stream>>>(
        lwd, wbuf, DMODEL, FFDIM,
        nullptr, nullptr, 0, 0, nullptr, nullptr, 0, 0, FFDIM);
    gemm128<EP_ADD, 3><<<dim3(16, 16), 256, 0, stream>>>(
        ffb, wbuf, x, x, nullptr, nullptr, FFDIM, FFDIM, FFDIM, DMODEL);
  }

  rmsnorm_kernel<<<SQ, 256, 0, stream>>>(h, x, fing);

  long chunkRows = (long)(avail / ((size_t)DMODEL * 2)) & ~255L;
  if (chunkRows > VOCAB) chunkRows = VOCAB;
  for (long c0 = 0; c0 < VOCAB; c0 += chunkRows) {
    const long rows = (VOCAB - c0 < chunkRows) ? (VOCAB - c0) : chunkRows;
    const int  nvec = (int)(rows * DMODEL / 4);
    cvt_bf16_kernel<<<(nvec + 255) / 256, 256, 0, stream>>>(lmh + c0 * DMODEL, wbuf, nvec);
    gemm256<EP_STOREF><<<dim3(8, (int)(rows / 256)), 512, 0, stream>>>(
        h, wbuf, out + c0, nullptr, DMODEL, DMODEL, DMODEL, VOCAB);
  }
}